// Round 3
// baseline (1915.971 us; speedup 1.0000x reference)
//
#include <hip/hip_runtime.h>
#include <math.h>

#define IN_DIM 256
#define OUT_DIM 128
#define NH 8
#define HD 16
#define GH 16
#define TBL 4096

typedef __attribute__((ext_vector_type(8))) short short8;
typedef __attribute__((ext_vector_type(4))) float floatx4;

// ---------------- bf16 split helpers (RNE) ----------------
__device__ __forceinline__ unsigned short f2bf(float f) {
    union { float f; unsigned u; } v; v.f = f;
    unsigned r = v.u + 0x7fffu + ((v.u >> 16) & 1u);
    return (unsigned short)(r >> 16);
}
__device__ __forceinline__ float bf2f(unsigned short h) {
    union { unsigned u; float f; } v; v.u = ((unsigned)h) << 16;
    return v.f;
}
__device__ __forceinline__ void split1(float f, unsigned short& h, unsigned short& l) {
    h = f2bf(f);
    l = f2bf(f - bf2f(h));
}

// split fp32 array into bf16 hi + bf16 residual lo (float4-vectorized)
__global__ void split_x_kernel(const float* __restrict__ in, unsigned short* __restrict__ hi,
                               unsigned short* __restrict__ lo, int n4) {
    int i = blockIdx.x * 256 + threadIdx.x;
    if (i >= n4) return;
    float4 f = ((const float4*)in)[i];
    ushort4 h, l;
    split1(f.x, h.x, l.x); split1(f.y, h.y, l.y);
    split1(f.z, h.z, l.z); split1(f.w, h.w, l.w);
    ((ushort4*)hi)[i] = h;
    ((ushort4*)lo)[i] = l;
}

// split the three qkv weight matrices (each OUT_DIM*IN_DIM) into hi/lo planes
__global__ void split_w_kernel(const float* __restrict__ Wq, const float* __restrict__ Wk,
                               const float* __restrict__ Wv,
                               unsigned short* __restrict__ hi, unsigned short* __restrict__ lo) {
    int m = blockIdx.y;
    const float* W = (m == 0) ? Wq : (m == 1) ? Wk : Wv;
    int i = blockIdx.x * 256 + threadIdx.x;          // float4 index within matrix
    if (i >= (OUT_DIM * IN_DIM) / 4) return;
    float4 f = ((const float4*)W)[i];
    ushort4 h, l;
    split1(f.x, h.x, l.x); split1(f.y, h.y, l.y);
    split1(f.z, h.z, l.z); split1(f.w, h.w, l.w);
    size_t base = (size_t)m * (OUT_DIM * IN_DIM) / 4;
    ((ushort4*)hi)[base + i] = h;
    ((ushort4*)lo)[base + i] = l;
}

// ---------------- geo bias table: bias(dist) per head, 4096-point lerp table ----------------
__global__ void geo_table_kernel(const float* __restrict__ Wg1, const float* __restrict__ bg1,
                                 const float* __restrict__ Wg2, const float* __restrict__ bg2,
                                 float* __restrict__ tbl) {
    int i = blockIdx.x * blockDim.x + threadIdx.x;
    if (i >= TBL) return;
    float d = (float)i * (6.0f / (float)(TBL - 1));
    float rbf[GH];
#pragma unroll
    for (int j = 0; j < GH; ++j) {
        float c = 0.4f * (float)j;
        float t = d - c;
        rbf[j] = __expf(-t * t);
    }
    float hid[GH];
#pragma unroll
    for (int j = 0; j < GH; ++j) {
        float acc = bg1[j];
#pragma unroll
        for (int kk = 0; kk < GH; ++kk) acc += rbf[kk] * Wg1[j * GH + kk];
        hid[j] = fmaxf(acc, 0.0f);
    }
#pragma unroll
    for (int h = 0; h < NH; ++h) {
        float acc = bg2[h];
#pragma unroll
        for (int j = 0; j < GH; ++j) acc += hid[j] * Wg2[h * GH + j];
        tbl[i * NH + h] = acc;
    }
}

// ---------------- qkv via split-bf16 MFMA ----------------
// block: 64 rows x 128 cols, 4 waves (each wave: 16 rows x 128 cols), K=256 in chunks of 32.
// C = xh*Wh + xl*Wh + xh*Wl  (xl*Wl term ~2^-18, dropped) -> fp32-class accuracy.
// LDS row stride = 40 shorts (80 B = 5 x 16B chunks, odd multiple of 16B) -> frag reads
// walk all 8 bank-groups over 8 rows: 2-way max aliasing = free on CDNA4 (m136).
__global__ __launch_bounds__(256) void qkv_mfma_kernel(
    const unsigned short* __restrict__ xh, const unsigned short* __restrict__ xl,
    const unsigned short* __restrict__ wh, const unsigned short* __restrict__ wl,
    const float* __restrict__ bq, const float* __restrict__ bk, const float* __restrict__ bv,
    float* __restrict__ q, float* __restrict__ k, float* __restrict__ v, int Nn) {
    const int n0 = blockIdx.x * 64;
    const int wsel = blockIdx.y;
    const unsigned short* W_h = wh + (size_t)wsel * (OUT_DIM * IN_DIM);
    const unsigned short* W_l = wl + (size_t)wsel * (OUT_DIM * IN_DIM);
    const float* bias = (wsel == 0) ? bq : (wsel == 1) ? bk : bv;
    float* outp = (wsel == 0) ? q : (wsel == 1) ? k : v;

    __shared__ unsigned short xh_s[64 * 40];
    __shared__ unsigned short xl_s[64 * 40];
    __shared__ unsigned short wh_s[128 * 40];
    __shared__ unsigned short wl_s[128 * 40];

    const int tid = threadIdx.x;
    const int w = tid >> 6;          // wave 0..3 -> rows w*16..w*16+15
    const int lane = tid & 63;
    const int ml = lane & 15;        // A row / B col / D col
    const int quad = lane >> 4;      // k-block selector; D rows quad*4..quad*4+3

    const int rows_valid = min(64, Nn - n0);

    floatx4 acc[8];
#pragma unroll
    for (int ct = 0; ct < 8; ++ct) acc[ct] = (floatx4){0.f, 0.f, 0.f, 0.f};

    const short8 zero8 = {0, 0, 0, 0, 0, 0, 0, 0};

    for (int kc = 0; kc < IN_DIM; kc += 32) {
        // stage x tile [64][32] hi+lo
        {
            int r = tid >> 2, c = tid & 3;
            short8 vh = zero8, vl = zero8;
            if (r < rows_valid) {
                size_t g = (size_t)(n0 + r) * IN_DIM + kc + c * 8;
                vh = *(const short8*)(xh + g);
                vl = *(const short8*)(xl + g);
            }
            *(short8*)(xh_s + r * 40 + c * 8) = vh;
            *(short8*)(xl_s + r * 40 + c * 8) = vl;
        }
        // stage W tile [128][32] hi+lo
#pragma unroll
        for (int l = 0; l < 2; ++l) {
            int idx = tid + l * 256;
            int r = idx >> 2, c = idx & 3;
            size_t g = (size_t)r * IN_DIM + kc + c * 8;
            *(short8*)(wh_s + r * 40 + c * 8) = *(const short8*)(W_h + g);
            *(short8*)(wl_s + r * 40 + c * 8) = *(const short8*)(W_l + g);
        }
        __syncthreads();

        short8 ah = *(const short8*)(xh_s + (w * 16 + ml) * 40 + quad * 8);
        short8 al = *(const short8*)(xl_s + (w * 16 + ml) * 40 + quad * 8);
#pragma unroll
        for (int ct = 0; ct < 8; ++ct) {
            short8 bh = *(const short8*)(wh_s + (ct * 16 + ml) * 40 + quad * 8);
            short8 bl = *(const short8*)(wl_s + (ct * 16 + ml) * 40 + quad * 8);
            acc[ct] = __builtin_amdgcn_mfma_f32_16x16x32_bf16(ah, bh, acc[ct], 0, 0, 0);
            acc[ct] = __builtin_amdgcn_mfma_f32_16x16x32_bf16(al, bh, acc[ct], 0, 0, 0);
            acc[ct] = __builtin_amdgcn_mfma_f32_16x16x32_bf16(ah, bl, acc[ct], 0, 0, 0);
        }
        __syncthreads();
    }

    // epilogue: D[row=quad*4+r][col=ct*16+ml]
#pragma unroll
    for (int ct = 0; ct < 8; ++ct) {
        float bj = bias[ct * 16 + ml];
#pragma unroll
        for (int r = 0; r < 4; ++r) {
            int grow = n0 + w * 16 + quad * 4 + r;
            if (grow < Nn) outp[(size_t)grow * 128 + ct * 16 + ml] = acc[ct][r] + bj;
        }
    }
}

// ---------------- fp32 register-tiled GEMM (kept for the final Wo GEMM) ----------------
template <int K>
static __device__ __forceinline__ void gemm_tile(const float* __restrict__ X,
                                                 const float* __restrict__ W,
                                                 const float* __restrict__ b,
                                                 float* __restrict__ out,
                                                 int n0, int Nn) {
    __shared__ float xs[64 * 32];
    __shared__ float wsm[128 * 32];
    const int tid = threadIdx.x;
    const int tx = tid & 15;
    const int ty = tid >> 4;
    float acc[4][8];
#pragma unroll
    for (int i = 0; i < 4; ++i)
#pragma unroll
        for (int j = 0; j < 8; ++j) acc[i][j] = 0.0f;

    const int rows_valid = min(64, Nn - n0);

    for (int kc = 0; kc < K; kc += 32) {
#pragma unroll
        for (int l = 0; l < 2; ++l) {
            int fl = tid + l * 256;
            int r = fl >> 3, c4 = fl & 7;
            float4 val = make_float4(0.f, 0.f, 0.f, 0.f);
            if (r < rows_valid) val = *(const float4*)(X + (size_t)(n0 + r) * K + kc + c4 * 4);
            int slot = c4 ^ ((r >> 3) & 7);
            *(float4*)(xs + r * 32 + slot * 4) = val;
        }
#pragma unroll
        for (int l = 0; l < 4; ++l) {
            int fl = tid + l * 256;
            int r = fl >> 3, c4 = fl & 7;
            float4 val = *(const float4*)(W + (size_t)r * K + kc + c4 * 4);
            int slot = c4 ^ ((r >> 3) & 7);
            *(float4*)(wsm + r * 32 + slot * 4) = val;
        }
        __syncthreads();
#pragma unroll
        for (int k4 = 0; k4 < 8; ++k4) {
            float4 xa[4], wb[8];
#pragma unroll
            for (int i = 0; i < 4; ++i) {
                int r = ty * 4 + i;
                int slot = k4 ^ ((r >> 3) & 7);
                xa[i] = *(const float4*)(xs + r * 32 + slot * 4);
            }
#pragma unroll
            for (int j = 0; j < 8; ++j) {
                int r = tx * 8 + j;
                int slot = k4 ^ ((r >> 3) & 7);
                wb[j] = *(const float4*)(wsm + r * 32 + slot * 4);
            }
#pragma unroll
            for (int i = 0; i < 4; ++i)
#pragma unroll
                for (int j = 0; j < 8; ++j) {
                    acc[i][j] += xa[i].x * wb[j].x;
                    acc[i][j] += xa[i].y * wb[j].y;
                    acc[i][j] += xa[i].z * wb[j].z;
                    acc[i][j] += xa[i].w * wb[j].w;
                }
        }
        __syncthreads();
    }

    float bj[8];
#pragma unroll
    for (int j = 0; j < 8; ++j) bj[j] = b[tx * 8 + j];
#pragma unroll
    for (int i = 0; i < 4; ++i) {
        int r = ty * 4 + i;
        if (r < rows_valid) {
            float4 o0 = make_float4(acc[i][0] + bj[0], acc[i][1] + bj[1],
                                    acc[i][2] + bj[2], acc[i][3] + bj[3]);
            float4 o1 = make_float4(acc[i][4] + bj[4], acc[i][5] + bj[5],
                                    acc[i][6] + bj[6], acc[i][7] + bj[7]);
            float* op = out + (size_t)(n0 + r) * 128 + tx * 8;
            *(float4*)op = o0;
            *(float4*)(op + 4) = o1;
        }
    }
}

__global__ __launch_bounds__(256) void out_gemm_kernel(const float* __restrict__ in,
                                                       const float* __restrict__ Wo, const float* __restrict__ bo,
                                                       float* __restrict__ out, int Nn) {
    gemm_tile<OUT_DIM>(in, Wo, bo, out, blockIdx.x * 64, Nn);
}

// ---------------- CSR build ----------------
__global__ void deg_kernel(const int* __restrict__ ei, int* __restrict__ deg, int E_) {
    int e = blockIdx.x * 256 + threadIdx.x;
    if (e < E_) atomicAdd(&deg[ei[e]], 1);
}

__global__ __launch_bounds__(1024) void scan_kernel(const int* __restrict__ deg,
                                                    int* __restrict__ rowstart,
                                                    int* __restrict__ cursor, int n) {
    __shared__ int sm[1024];
    int t = threadIdx.x;
    int chunk = (n + 1023) / 1024;
    int b0 = t * chunk;
    int b1 = min(b0 + chunk, n);
    int lsum = 0;
    for (int i = b0; i < b1; ++i) lsum += deg[i];
    sm[t] = lsum;
    __syncthreads();
    for (int off = 1; off < 1024; off <<= 1) {
        int other = (t >= off) ? sm[t - off] : 0;
        __syncthreads();
        sm[t] += other;
        __syncthreads();
    }
    int run = sm[t] - lsum;
    for (int i = b0; i < b1; ++i) {
        rowstart[i] = run;
        cursor[i] = run;
        run += deg[i];
    }
    if (t == 1023) rowstart[n] = sm[1023];
}

// ---------------- edge pass ----------------
__global__ __launch_bounds__(256) void edge_kernel(const int* __restrict__ ei,
                                                   const float* __restrict__ edist,
                                                   const float* __restrict__ q,
                                                   const float* __restrict__ k,
                                                   const float* __restrict__ tbl,
                                                   int* __restrict__ cursor,
                                                   float* __restrict__ attn,
                                                   int* __restrict__ ccol, int E_) {
    int tid = threadIdx.x;
    int g = tid >> 3, h = tid & 7;
    int e = blockIdx.x * 32 + g;
    if (e >= E_) return;
    int row = ei[e];
    int col = ei[E_ + e];
    float dist = edist[e];

    float u = dist * ((float)(TBL - 1) / 6.0f);
    u = fminf(fmaxf(u, 0.0f), (float)(TBL - 1));
    int i0 = (int)u;
    if (i0 > TBL - 2) i0 = TBL - 2;
    float fr = u - (float)i0;
    float t0 = tbl[i0 * NH + h];
    float t1 = tbl[(i0 + 1) * NH + h];
    float bias = t0 + fr * (t1 - t0);

    const float4* qp = (const float4*)(q + (size_t)row * 128 + h * 16);
    const float4* kp = (const float4*)(k + (size_t)col * 128 + h * 16);
    float dot = 0.0f;
#pragma unroll
    for (int i = 0; i < 4; ++i) {
        float4 a = qp[i];
        float4 bb = kp[i];
        dot += a.x * bb.x + a.y * bb.y + a.z * bb.z + a.w * bb.w;
    }
    float attn_v = dot * 0.25f + bias;

    int pos = 0;
    if (h == 0) pos = atomicAdd(&cursor[row], 1);
    int lane = tid & 63;
    pos = __shfl(pos, lane & ~7, 64);

    attn[(size_t)pos * 8 + h] = attn_v;
    if (h == 0) ccol[pos] = col;
}

// ---------------- node pass: softmax (m,s) -> in-place weight rewrite -> aggregation ----------------
__global__ __launch_bounds__(256) void node_kernel(float* __restrict__ attn,
                                                   const int* __restrict__ ccol,
                                                   const float* __restrict__ v,
                                                   const int* __restrict__ rowstart,
                                                   float* __restrict__ outacc, int Nn) {
    int lane = threadIdx.x & 63;
    int n = blockIdx.x * 4 + (threadIdx.x >> 6);
    if (n >= Nn) return;
    int start = rowstart[n];
    int end = rowstart[n + 1];

    float m[NH], s[NH];
#pragma unroll
    for (int h = 0; h < NH; ++h) { m[h] = -1e30f; s[h] = 0.0f; }

    for (int i = start + lane; i < end; i += 64) {
        float4 a0 = *(const float4*)(attn + (size_t)i * 8);
        float4 a1 = *(const float4*)(attn + (size_t)i * 8 + 4);
        float av[8] = {a0.x, a0.y, a0.z, a0.w, a1.x, a1.y, a1.z, a1.w};
#pragma unroll
        for (int h = 0; h < NH; ++h) {
            float nm = fmaxf(m[h], av[h]);
            s[h] = s[h] * __expf(m[h] - nm) + __expf(av[h] - nm);
            m[h] = nm;
        }
    }
#pragma unroll
    for (int off = 1; off < 64; off <<= 1) {
#pragma unroll
        for (int h = 0; h < NH; ++h) {
            float om = __shfl_xor(m[h], off);
            float os = __shfl_xor(s[h], off);
            float nm = fmaxf(m[h], om);
            s[h] = s[h] * __expf(m[h] - nm) + os * __expf(om - nm);
            m[h] = nm;
        }
    }
    float inv[NH];
#pragma unroll
    for (int h = 0; h < NH; ++h) inv[h] = 1.0f / (s[h] + 1e-12f);

    // rewrite attn -> normalized weights (8 wave-exps per 64 edges instead of 128)
    for (int i = start + lane; i < end; i += 64) {
        float4 a0 = *(const float4*)(attn + (size_t)i * 8);
        float4 a1 = *(const float4*)(attn + (size_t)i * 8 + 4);
        a0.x = __expf(a0.x - m[0]) * inv[0];
        a0.y = __expf(a0.y - m[1]) * inv[1];
        a0.z = __expf(a0.z - m[2]) * inv[2];
        a0.w = __expf(a0.w - m[3]) * inv[3];
        a1.x = __expf(a1.x - m[4]) * inv[4];
        a1.y = __expf(a1.y - m[5]) * inv[5];
        a1.z = __expf(a1.z - m[6]) * inv[6];
        a1.w = __expf(a1.w - m[7]) * inv[7];
        *(float4*)(attn + (size_t)i * 8) = a0;
        *(float4*)(attn + (size_t)i * 8 + 4) = a1;
    }
    __threadfence();  // make own-wave stores visible to own-wave cross-lane loads

    int h0 = lane >> 4;
    float acc0 = 0.0f, acc1 = 0.0f;
    for (int i = start; i < end; ++i) {
        int col = ccol[i];
        float w0 = attn[(size_t)i * 8 + h0];
        float w1 = attn[(size_t)i * 8 + 4 + h0];
        const float* vp = v + (size_t)col * 128;
        acc0 += w0 * vp[lane];
        acc1 += w1 * vp[64 + lane];
    }
    float* op = outacc + (size_t)n * 128;
    op[lane] = acc0;
    op[64 + lane] = acc1;
}

extern "C" void kernel_launch(void* const* d_in, const int* in_sizes, int n_in,
                              void* d_out, int out_size, void* d_ws, size_t ws_size,
                              hipStream_t stream) {
    const float* x   = (const float*)d_in[0];
    const int* ei    = (const int*)d_in[1];
    const float* edist = (const float*)d_in[2];
    const float* Wq = (const float*)d_in[3];  const float* bq = (const float*)d_in[4];
    const float* Wk = (const float*)d_in[5];  const float* bk = (const float*)d_in[6];
    const float* Wv = (const float*)d_in[7];  const float* bv = (const float*)d_in[8];
    const float* Wo = (const float*)d_in[9];  const float* bo = (const float*)d_in[10];
    const float* Wg1 = (const float*)d_in[11]; const float* bg1 = (const float*)d_in[12];
    const float* Wg2 = (const float*)d_in[13]; const float* bg2 = (const float*)d_in[14];
    const int Nn = in_sizes[0] / IN_DIM;
    const int Ee = in_sizes[2];
    float* out = (float*)d_out;

    char* ws = (char*)d_ws;
    size_t off = 0;
    auto alloc = [&](size_t bytes) -> char* {
        char* p = ws + off;
        off += (bytes + 255) & ~(size_t)255;
        return p;
    };
    float* q    = (float*)alloc((size_t)Nn * 128 * 4);
    float* kbuf = (float*)alloc((size_t)Nn * 128 * 4);
    float* vbuf = (float*)alloc((size_t)Nn * 128 * 4);
    float* attn = (float*)alloc((size_t)Ee * 8 * 4);   // also aliased as xl during qkv
    float* geot = (float*)alloc((size_t)TBL * 8 * 4);
    int* ccol     = (int*)alloc((size_t)Ee * 4);
    int* deg      = (int*)alloc((size_t)Nn * 4);
    int* rowstart = (int*)alloc((size_t)(Nn + 1) * 4);
    int* cursor   = (int*)alloc((size_t)Nn * 4);
    unsigned short* wh_all = (unsigned short*)alloc((size_t)3 * OUT_DIM * IN_DIM * 2);
    unsigned short* wl_all = (unsigned short*)alloc((size_t)3 * OUT_DIM * IN_DIM * 2);
    float* outacc = q;  // q dead after edge_kernel

    // x split buffers: xh aliases d_out (final GEMM rewrites it), xl aliases attn
    // (attn is written only by edge_kernel, after qkv_mfma completes). Both 25.6 MB.
    unsigned short* xh = (unsigned short*)d_out;
    unsigned short* xl = (unsigned short*)attn;

    hipMemsetAsync(deg, 0, (size_t)Nn * 4, stream);

    int n4x = Nn * IN_DIM / 4;
    split_x_kernel<<<(n4x + 255) / 256, 256, 0, stream>>>(x, xh, xl, n4x);
    split_w_kernel<<<dim3((OUT_DIM * IN_DIM / 4 + 255) / 256, 3), 256, 0, stream>>>(Wq, Wk, Wv, wh_all, wl_all);

    geo_table_kernel<<<(TBL + 255) / 256, 256, 0, stream>>>(Wg1, bg1, Wg2, bg2, geot);

    dim3 gq((Nn + 63) / 64, 3);
    qkv_mfma_kernel<<<gq, 256, 0, stream>>>(xh, xl, wh_all, wl_all, bq, bk, bv, q, kbuf, vbuf, Nn);

    deg_kernel<<<(Ee + 255) / 256, 256, 0, stream>>>(ei, deg, Ee);
    scan_kernel<<<1, 1024, 0, stream>>>(deg, rowstart, cursor, Nn);

    edge_kernel<<<(Ee + 31) / 32, 256, 0, stream>>>(ei, edist, q, kbuf, geot, cursor, attn, ccol, Ee);

    node_kernel<<<(Nn + 3) / 4, 256, 0, stream>>>(attn, ccol, vbuf, rowstart, outacc, Nn);

    out_gemm_kernel<<<(Nn + 63) / 64, 256, 0, stream>>>(outacc, Wo, bo, out, Nn);
}

// Round 4
// 613.302 us; speedup vs baseline: 3.1240x; 3.1240x over previous
//
#include <hip/hip_runtime.h>
#include <math.h>

#define IN_DIM 256
#define OUT_DIM 128
#define NH 8
#define HD 16
#define GH 16
#define TBL 4096

typedef __attribute__((ext_vector_type(8))) short short8;
typedef __attribute__((ext_vector_type(4))) float floatx4;

// ---------------- bf16 split helpers (RNE) ----------------
__device__ __forceinline__ unsigned short f2bf(float f) {
    union { float f; unsigned u; } v; v.f = f;
    unsigned r = v.u + 0x7fffu + ((v.u >> 16) & 1u);
    return (unsigned short)(r >> 16);
}
__device__ __forceinline__ float bf2f(unsigned short h) {
    union { unsigned u; float f; } v; v.u = ((unsigned)h) << 16;
    return v.f;
}
__device__ __forceinline__ void split1(float f, unsigned short& h, unsigned short& l) {
    h = f2bf(f);
    l = f2bf(f - bf2f(h));
}

// split fp32 array into bf16 hi + bf16 residual lo (float4-vectorized)
__global__ void split_x_kernel(const float* __restrict__ in, unsigned short* __restrict__ hi,
                               unsigned short* __restrict__ lo, int n4) {
    int i = blockIdx.x * 256 + threadIdx.x;
    if (i >= n4) return;
    float4 f = ((const float4*)in)[i];
    ushort4 h, l;
    split1(f.x, h.x, l.x); split1(f.y, h.y, l.y);
    split1(f.z, h.z, l.z); split1(f.w, h.w, l.w);
    ((ushort4*)hi)[i] = h;
    ((ushort4*)lo)[i] = l;
}

// split the three qkv weight matrices (each OUT_DIM*IN_DIM) into hi/lo planes
__global__ void split_w_kernel(const float* __restrict__ Wq, const float* __restrict__ Wk,
                               const float* __restrict__ Wv,
                               unsigned short* __restrict__ hi, unsigned short* __restrict__ lo) {
    int m = blockIdx.y;
    const float* W = (m == 0) ? Wq : (m == 1) ? Wk : Wv;
    int i = blockIdx.x * 256 + threadIdx.x;          // float4 index within matrix
    if (i >= (OUT_DIM * IN_DIM) / 4) return;
    float4 f = ((const float4*)W)[i];
    ushort4 h, l;
    split1(f.x, h.x, l.x); split1(f.y, h.y, l.y);
    split1(f.z, h.z, l.z); split1(f.w, h.w, l.w);
    size_t base = (size_t)m * (OUT_DIM * IN_DIM) / 4;
    ((ushort4*)hi)[base + i] = h;
    ((ushort4*)lo)[base + i] = l;
}

// ---------------- geo bias table: bias(dist) per head, 4096-point lerp table ----------------
__global__ void geo_table_kernel(const float* __restrict__ Wg1, const float* __restrict__ bg1,
                                 const float* __restrict__ Wg2, const float* __restrict__ bg2,
                                 float* __restrict__ tbl) {
    int i = blockIdx.x * blockDim.x + threadIdx.x;
    if (i >= TBL) return;
    float d = (float)i * (6.0f / (float)(TBL - 1));
    float rbf[GH];
#pragma unroll
    for (int j = 0; j < GH; ++j) {
        float c = 0.4f * (float)j;
        float t = d - c;
        rbf[j] = __expf(-t * t);
    }
    float hid[GH];
#pragma unroll
    for (int j = 0; j < GH; ++j) {
        float acc = bg1[j];
#pragma unroll
        for (int kk = 0; kk < GH; ++kk) acc += rbf[kk] * Wg1[j * GH + kk];
        hid[j] = fmaxf(acc, 0.0f);
    }
#pragma unroll
    for (int h = 0; h < NH; ++h) {
        float acc = bg2[h];
#pragma unroll
        for (int j = 0; j < GH; ++j) acc += hid[j] * Wg2[h * GH + j];
        tbl[i * NH + h] = acc;
    }
}

// ---------------- qkv via split-bf16 MFMA ----------------
// block: 64 rows x 128 cols, 4 waves (each wave: 16 rows x 128 cols), K=256 in chunks of 32.
// C = xh*Wh + xl*Wh + xh*Wl  (xl*Wl term ~2^-18, dropped) -> fp32-class accuracy.
__global__ __launch_bounds__(256) void qkv_mfma_kernel(
    const unsigned short* __restrict__ xh, const unsigned short* __restrict__ xl,
    const unsigned short* __restrict__ wh, const unsigned short* __restrict__ wl,
    const float* __restrict__ bq, const float* __restrict__ bk, const float* __restrict__ bv,
    float* __restrict__ q, float* __restrict__ k, float* __restrict__ v, int Nn) {
    const int n0 = blockIdx.x * 64;
    const int wsel = blockIdx.y;
    const unsigned short* W_h = wh + (size_t)wsel * (OUT_DIM * IN_DIM);
    const unsigned short* W_l = wl + (size_t)wsel * (OUT_DIM * IN_DIM);
    const float* bias = (wsel == 0) ? bq : (wsel == 1) ? bk : bv;
    float* outp = (wsel == 0) ? q : (wsel == 1) ? k : v;

    __shared__ unsigned short xh_s[64 * 40];
    __shared__ unsigned short xl_s[64 * 40];
    __shared__ unsigned short wh_s[128 * 40];
    __shared__ unsigned short wl_s[128 * 40];

    const int tid = threadIdx.x;
    const int w = tid >> 6;          // wave 0..3 -> rows w*16..w*16+15
    const int lane = tid & 63;
    const int ml = lane & 15;        // A row / B col / D col
    const int quad = lane >> 4;      // k-block selector; D rows quad*4..quad*4+3

    const int rows_valid = min(64, Nn - n0);

    floatx4 acc[8];
#pragma unroll
    for (int ct = 0; ct < 8; ++ct) acc[ct] = (floatx4){0.f, 0.f, 0.f, 0.f};

    const short8 zero8 = {0, 0, 0, 0, 0, 0, 0, 0};

    for (int kc = 0; kc < IN_DIM; kc += 32) {
        // stage x tile [64][32] hi+lo
        {
            int r = tid >> 2, c = tid & 3;
            short8 vh = zero8, vl = zero8;
            if (r < rows_valid) {
                size_t g = (size_t)(n0 + r) * IN_DIM + kc + c * 8;
                vh = *(const short8*)(xh + g);
                vl = *(const short8*)(xl + g);
            }
            *(short8*)(xh_s + r * 40 + c * 8) = vh;
            *(short8*)(xl_s + r * 40 + c * 8) = vl;
        }
        // stage W tile [128][32] hi+lo
#pragma unroll
        for (int l = 0; l < 2; ++l) {
            int idx = tid + l * 256;
            int r = idx >> 2, c = idx & 3;
            size_t g = (size_t)r * IN_DIM + kc + c * 8;
            *(short8*)(wh_s + r * 40 + c * 8) = *(const short8*)(W_h + g);
            *(short8*)(wl_s + r * 40 + c * 8) = *(const short8*)(W_l + g);
        }
        __syncthreads();

        short8 ah = *(const short8*)(xh_s + (w * 16 + ml) * 40 + quad * 8);
        short8 al = *(const short8*)(xl_s + (w * 16 + ml) * 40 + quad * 8);
#pragma unroll
        for (int ct = 0; ct < 8; ++ct) {
            short8 bh = *(const short8*)(wh_s + (ct * 16 + ml) * 40 + quad * 8);
            short8 bl = *(const short8*)(wl_s + (ct * 16 + ml) * 40 + quad * 8);
            acc[ct] = __builtin_amdgcn_mfma_f32_16x16x32_bf16(ah, bh, acc[ct], 0, 0, 0);
            acc[ct] = __builtin_amdgcn_mfma_f32_16x16x32_bf16(al, bh, acc[ct], 0, 0, 0);
            acc[ct] = __builtin_amdgcn_mfma_f32_16x16x32_bf16(ah, bl, acc[ct], 0, 0, 0);
        }
        __syncthreads();
    }

    // epilogue: D[row=quad*4+r][col=ct*16+ml]
#pragma unroll
    for (int ct = 0; ct < 8; ++ct) {
        float bj = bias[ct * 16 + ml];
#pragma unroll
        for (int r = 0; r < 4; ++r) {
            int grow = n0 + w * 16 + quad * 4 + r;
            if (grow < Nn) outp[(size_t)grow * 128 + ct * 16 + ml] = acc[ct][r] + bj;
        }
    }
}

// ---------------- fp32 register-tiled GEMM (kept for the final Wo GEMM) ----------------
template <int K>
static __device__ __forceinline__ void gemm_tile(const float* __restrict__ X,
                                                 const float* __restrict__ W,
                                                 const float* __restrict__ b,
                                                 float* __restrict__ out,
                                                 int n0, int Nn) {
    __shared__ float xs[64 * 32];
    __shared__ float wsm[128 * 32];
    const int tid = threadIdx.x;
    const int tx = tid & 15;
    const int ty = tid >> 4;
    float acc[4][8];
#pragma unroll
    for (int i = 0; i < 4; ++i)
#pragma unroll
        for (int j = 0; j < 8; ++j) acc[i][j] = 0.0f;

    const int rows_valid = min(64, Nn - n0);

    for (int kc = 0; kc < K; kc += 32) {
#pragma unroll
        for (int l = 0; l < 2; ++l) {
            int fl = tid + l * 256;
            int r = fl >> 3, c4 = fl & 7;
            float4 val = make_float4(0.f, 0.f, 0.f, 0.f);
            if (r < rows_valid) val = *(const float4*)(X + (size_t)(n0 + r) * K + kc + c4 * 4);
            int slot = c4 ^ ((r >> 3) & 7);
            *(float4*)(xs + r * 32 + slot * 4) = val;
        }
#pragma unroll
        for (int l = 0; l < 4; ++l) {
            int fl = tid + l * 256;
            int r = fl >> 3, c4 = fl & 7;
            float4 val = *(const float4*)(W + (size_t)r * K + kc + c4 * 4);
            int slot = c4 ^ ((r >> 3) & 7);
            *(float4*)(wsm + r * 32 + slot * 4) = val;
        }
        __syncthreads();
#pragma unroll
        for (int k4 = 0; k4 < 8; ++k4) {
            float4 xa[4], wb[8];
#pragma unroll
            for (int i = 0; i < 4; ++i) {
                int r = ty * 4 + i;
                int slot = k4 ^ ((r >> 3) & 7);
                xa[i] = *(const float4*)(xs + r * 32 + slot * 4);
            }
#pragma unroll
            for (int j = 0; j < 8; ++j) {
                int r = tx * 8 + j;
                int slot = k4 ^ ((r >> 3) & 7);
                wb[j] = *(const float4*)(wsm + r * 32 + slot * 4);
            }
#pragma unroll
            for (int i = 0; i < 4; ++i)
#pragma unroll
                for (int j = 0; j < 8; ++j) {
                    acc[i][j] += xa[i].x * wb[j].x;
                    acc[i][j] += xa[i].y * wb[j].y;
                    acc[i][j] += xa[i].z * wb[j].z;
                    acc[i][j] += xa[i].w * wb[j].w;
                }
        }
        __syncthreads();
    }

    float bj[8];
#pragma unroll
    for (int j = 0; j < 8; ++j) bj[j] = b[tx * 8 + j];
#pragma unroll
    for (int i = 0; i < 4; ++i) {
        int r = ty * 4 + i;
        if (r < rows_valid) {
            float4 o0 = make_float4(acc[i][0] + bj[0], acc[i][1] + bj[1],
                                    acc[i][2] + bj[2], acc[i][3] + bj[3]);
            float4 o1 = make_float4(acc[i][4] + bj[4], acc[i][5] + bj[5],
                                    acc[i][6] + bj[6], acc[i][7] + bj[7]);
            float* op = out + (size_t)(n0 + r) * 128 + tx * 8;
            *(float4*)op = o0;
            *(float4*)(op + 4) = o1;
        }
    }
}

__global__ __launch_bounds__(256) void out_gemm_kernel(const float* __restrict__ in,
                                                       const float* __restrict__ Wo, const float* __restrict__ bo,
                                                       float* __restrict__ out, int Nn) {
    gemm_tile<OUT_DIM>(in, Wo, bo, out, blockIdx.x * 64, Nn);
}

// ---------------- CSR build ----------------
__global__ void deg_kernel(const int* __restrict__ ei, int* __restrict__ deg, int E_) {
    int e = blockIdx.x * 256 + threadIdx.x;
    if (e < E_) atomicAdd(&deg[ei[e]], 1);
}

__global__ __launch_bounds__(1024) void scan_kernel(const int* __restrict__ deg,
                                                    int* __restrict__ rowstart,
                                                    int* __restrict__ cursor, int n) {
    __shared__ int sm[1024];
    int t = threadIdx.x;
    int chunk = (n + 1023) / 1024;
    int b0 = t * chunk;
    int b1 = min(b0 + chunk, n);
    int lsum = 0;
    for (int i = b0; i < b1; ++i) lsum += deg[i];
    sm[t] = lsum;
    __syncthreads();
    for (int off = 1; off < 1024; off <<= 1) {
        int other = (t >= off) ? sm[t - off] : 0;
        __syncthreads();
        sm[t] += other;
        __syncthreads();
    }
    int run = sm[t] - lsum;
    for (int i = b0; i < b1; ++i) {
        rowstart[i] = run;
        cursor[i] = run;
        run += deg[i];
    }
    if (t == 1023) rowstart[n] = sm[1023];
}

// ---------------- edge pass ----------------
__global__ __launch_bounds__(256) void edge_kernel(const int* __restrict__ ei,
                                                   const float* __restrict__ edist,
                                                   const float* __restrict__ q,
                                                   const float* __restrict__ k,
                                                   const float* __restrict__ tbl,
                                                   int* __restrict__ cursor,
                                                   float* __restrict__ attn,
                                                   int* __restrict__ ccol, int E_) {
    int tid = threadIdx.x;
    int g = tid >> 3, h = tid & 7;
    int e = blockIdx.x * 32 + g;
    if (e >= E_) return;
    int row = ei[e];
    int col = ei[E_ + e];
    float dist = edist[e];

    float u = dist * ((float)(TBL - 1) / 6.0f);
    u = fminf(fmaxf(u, 0.0f), (float)(TBL - 1));
    int i0 = (int)u;
    if (i0 > TBL - 2) i0 = TBL - 2;
    float fr = u - (float)i0;
    float t0 = tbl[i0 * NH + h];
    float t1 = tbl[(i0 + 1) * NH + h];
    float bias = t0 + fr * (t1 - t0);

    const float4* qp = (const float4*)(q + (size_t)row * 128 + h * 16);
    const float4* kp = (const float4*)(k + (size_t)col * 128 + h * 16);
    float dot = 0.0f;
#pragma unroll
    for (int i = 0; i < 4; ++i) {
        float4 a = qp[i];
        float4 bb = kp[i];
        dot += a.x * bb.x + a.y * bb.y + a.z * bb.z + a.w * bb.w;
    }
    float attn_v = dot * 0.25f + bias;

    int pos = 0;
    if (h == 0) pos = atomicAdd(&cursor[row], 1);
    int lane = tid & 63;
    pos = __shfl(pos, lane & ~7, 64);

    attn[(size_t)pos * 8 + h] = attn_v;
    if (h == 0) ccol[pos] = col;
}

// ---------------- node pass: exact segment softmax + v aggregation (R2 structure) ----------------
// NOTE R3 post-mortem: the in-place weight-rewrite + __threadfence variant was 6x slower
// (1395us, VALUBusy 5.9%) -- the device fence serializes and invalidates L1 per wave.
// Recomputing 2 expf/edge in the aggregation loop is essentially free.
__global__ __launch_bounds__(256) void node_kernel(const float* __restrict__ attn,
                                                   const int* __restrict__ ccol,
                                                   const float* __restrict__ v,
                                                   const int* __restrict__ rowstart,
                                                   float* __restrict__ outacc, int Nn) {
    int lane = threadIdx.x & 63;
    int n = blockIdx.x * 4 + (threadIdx.x >> 6);
    if (n >= Nn) return;
    int start = rowstart[n];
    int end = rowstart[n + 1];

    float m[NH], s[NH];
#pragma unroll
    for (int h = 0; h < NH; ++h) { m[h] = -1e30f; s[h] = 0.0f; }

    for (int i = start + lane; i < end; i += 64) {
        float4 a0 = *(const float4*)(attn + (size_t)i * 8);
        float4 a1 = *(const float4*)(attn + (size_t)i * 8 + 4);
        float av[8] = {a0.x, a0.y, a0.z, a0.w, a1.x, a1.y, a1.z, a1.w};
#pragma unroll
        for (int h = 0; h < NH; ++h) {
            float nm = fmaxf(m[h], av[h]);
            s[h] = s[h] * __expf(m[h] - nm) + __expf(av[h] - nm);
            m[h] = nm;
        }
    }
#pragma unroll
    for (int off = 1; off < 64; off <<= 1) {
#pragma unroll
        for (int h = 0; h < NH; ++h) {
            float om = __shfl_xor(m[h], off);
            float os = __shfl_xor(s[h], off);
            float nm = fmaxf(m[h], om);
            s[h] = s[h] * __expf(m[h] - nm) + os * __expf(om - nm);
            m[h] = nm;
        }
    }

    int h0 = lane >> 4;  // lane covers features f=lane (head h0) and f=lane+64 (head h0+4)
    float m0 = (h0 == 0) ? m[0] : (h0 == 1) ? m[1] : (h0 == 2) ? m[2] : m[3];
    float s0 = (h0 == 0) ? s[0] : (h0 == 1) ? s[1] : (h0 == 2) ? s[2] : s[3];
    float m1 = (h0 == 0) ? m[4] : (h0 == 1) ? m[5] : (h0 == 2) ? m[6] : m[7];
    float s1 = (h0 == 0) ? s[4] : (h0 == 1) ? s[5] : (h0 == 2) ? s[6] : s[7];
    float is0 = 1.0f / (s0 + 1e-12f);
    float is1 = 1.0f / (s1 + 1e-12f);

    float acc0 = 0.0f, acc1 = 0.0f;
    for (int i = start; i < end; ++i) {
        int col = ccol[i];
        float a0 = attn[(size_t)i * 8 + h0];
        float a1 = attn[(size_t)i * 8 + 4 + h0];
        float w0 = __expf(a0 - m0) * is0;
        float w1 = __expf(a1 - m1) * is1;
        const float* vp = v + (size_t)col * 128;
        acc0 += w0 * vp[lane];
        acc1 += w1 * vp[64 + lane];
    }
    float* op = outacc + (size_t)n * 128;
    op[lane] = acc0;
    op[64 + lane] = acc1;
}

extern "C" void kernel_launch(void* const* d_in, const int* in_sizes, int n_in,
                              void* d_out, int out_size, void* d_ws, size_t ws_size,
                              hipStream_t stream) {
    const float* x   = (const float*)d_in[0];
    const int* ei    = (const int*)d_in[1];
    const float* edist = (const float*)d_in[2];
    const float* Wq = (const float*)d_in[3];  const float* bq = (const float*)d_in[4];
    const float* Wk = (const float*)d_in[5];  const float* bk = (const float*)d_in[6];
    const float* Wv = (const float*)d_in[7];  const float* bv = (const float*)d_in[8];
    const float* Wo = (const float*)d_in[9];  const float* bo = (const float*)d_in[10];
    const float* Wg1 = (const float*)d_in[11]; const float* bg1 = (const float*)d_in[12];
    const float* Wg2 = (const float*)d_in[13]; const float* bg2 = (const float*)d_in[14];
    const int Nn = in_sizes[0] / IN_DIM;
    const int Ee = in_sizes[2];
    float* out = (float*)d_out;

    char* ws = (char*)d_ws;
    size_t off = 0;
    auto alloc = [&](size_t bytes) -> char* {
        char* p = ws + off;
        off += (bytes + 255) & ~(size_t)255;
        return p;
    };
    float* q    = (float*)alloc((size_t)Nn * 128 * 4);
    float* kbuf = (float*)alloc((size_t)Nn * 128 * 4);
    float* vbuf = (float*)alloc((size_t)Nn * 128 * 4);
    float* attn = (float*)alloc((size_t)Ee * 8 * 4);   // also aliased as xl during qkv
    float* geot = (float*)alloc((size_t)TBL * 8 * 4);
    int* ccol     = (int*)alloc((size_t)Ee * 4);
    int* deg      = (int*)alloc((size_t)Nn * 4);
    int* rowstart = (int*)alloc((size_t)(Nn + 1) * 4);
    int* cursor   = (int*)alloc((size_t)Nn * 4);
    unsigned short* wh_all = (unsigned short*)alloc((size_t)3 * OUT_DIM * IN_DIM * 2);
    unsigned short* wl_all = (unsigned short*)alloc((size_t)3 * OUT_DIM * IN_DIM * 2);
    float* outacc = q;  // q dead after edge_kernel

    // x split buffers: xh aliases d_out (final GEMM rewrites it), xl aliases attn
    // (attn is written only by edge_kernel, after qkv_mfma completes). Both 25.6 MB.
    unsigned short* xh = (unsigned short*)d_out;
    unsigned short* xl = (unsigned short*)attn;

    hipMemsetAsync(deg, 0, (size_t)Nn * 4, stream);

    int n4x = Nn * IN_DIM / 4;
    split_x_kernel<<<(n4x + 255) / 256, 256, 0, stream>>>(x, xh, xl, n4x);
    split_w_kernel<<<dim3((OUT_DIM * IN_DIM / 4 + 255) / 256, 3), 256, 0, stream>>>(Wq, Wk, Wv, wh_all, wl_all);

    geo_table_kernel<<<(TBL + 255) / 256, 256, 0, stream>>>(Wg1, bg1, Wg2, bg2, geot);

    dim3 gq((Nn + 63) / 64, 3);
    qkv_mfma_kernel<<<gq, 256, 0, stream>>>(xh, xl, wh_all, wl_all, bq, bk, bv, q, kbuf, vbuf, Nn);

    deg_kernel<<<(Ee + 255) / 256, 256, 0, stream>>>(ei, deg, Ee);
    scan_kernel<<<1, 1024, 0, stream>>>(deg, rowstart, cursor, Nn);

    edge_kernel<<<(Ee + 31) / 32, 256, 0, stream>>>(ei, edist, q, kbuf, geot, cursor, attn, ccol, Ee);

    node_kernel<<<(Nn + 3) / 4, 256, 0, stream>>>(attn, ccol, vbuf, rowstart, outacc, Nn);

    out_gemm_kernel<<<(Nn + 63) / 64, 256, 0, stream>>>(outacc, Wo, bo, out, Nn);
}

// Round 5
// 551.737 us; speedup vs baseline: 3.4726x; 1.1116x over previous
//
#include <hip/hip_runtime.h>
#include <math.h>

#define IN_DIM 256
#define OUT_DIM 128
#define NH 8
#define HD 16
#define GH 16
#define TBL 1024

typedef __attribute__((ext_vector_type(8))) short short8;
typedef __attribute__((ext_vector_type(4))) float floatx4;

// ---------------- bf16 split helpers (RNE) ----------------
__device__ __forceinline__ unsigned short f2bf(float f) {
    union { float f; unsigned u; } v; v.f = f;
    unsigned r = v.u + 0x7fffu + ((v.u >> 16) & 1u);
    return (unsigned short)(r >> 16);
}
__device__ __forceinline__ float bf2f(unsigned short h) {
    union { unsigned u; float f; } v; v.u = ((unsigned)h) << 16;
    return v.f;
}
__device__ __forceinline__ void split1(float f, unsigned short& h, unsigned short& l) {
    h = f2bf(f);
    l = f2bf(f - bf2f(h));
}

__global__ void split_x_kernel(const float* __restrict__ in, unsigned short* __restrict__ hi,
                               unsigned short* __restrict__ lo, int n4) {
    int i = blockIdx.x * 256 + threadIdx.x;
    if (i >= n4) return;
    float4 f = ((const float4*)in)[i];
    ushort4 h, l;
    split1(f.x, h.x, l.x); split1(f.y, h.y, l.y);
    split1(f.z, h.z, l.z); split1(f.w, h.w, l.w);
    ((ushort4*)hi)[i] = h;
    ((ushort4*)lo)[i] = l;
}

__global__ void split_w_kernel(const float* __restrict__ Wq, const float* __restrict__ Wk,
                               const float* __restrict__ Wv,
                               unsigned short* __restrict__ hi, unsigned short* __restrict__ lo) {
    int m = blockIdx.y;
    const float* W = (m == 0) ? Wq : (m == 1) ? Wk : Wv;
    int i = blockIdx.x * 256 + threadIdx.x;
    if (i >= (OUT_DIM * IN_DIM) / 4) return;
    float4 f = ((const float4*)W)[i];
    ushort4 h, l;
    split1(f.x, h.x, l.x); split1(f.y, h.y, l.y);
    split1(f.z, h.z, l.z); split1(f.w, h.w, l.w);
    size_t base = (size_t)m * (OUT_DIM * IN_DIM) / 4;
    ((ushort4*)hi)[base + i] = h;
    ((ushort4*)lo)[base + i] = l;
}

// ---------------- geo bias table ----------------
__global__ void geo_table_kernel(const float* __restrict__ Wg1, const float* __restrict__ bg1,
                                 const float* __restrict__ Wg2, const float* __restrict__ bg2,
                                 float* __restrict__ tbl) {
    int i = blockIdx.x * blockDim.x + threadIdx.x;
    if (i >= TBL) return;
    float d = (float)i * (6.0f / (float)(TBL - 1));
    float rbf[GH];
#pragma unroll
    for (int j = 0; j < GH; ++j) {
        float c = 0.4f * (float)j;
        float t = d - c;
        rbf[j] = __expf(-t * t);
    }
    float hid[GH];
#pragma unroll
    for (int j = 0; j < GH; ++j) {
        float acc = bg1[j];
#pragma unroll
        for (int kk = 0; kk < GH; ++kk) acc += rbf[kk] * Wg1[j * GH + kk];
        hid[j] = fmaxf(acc, 0.0f);
    }
#pragma unroll
    for (int h = 0; h < NH; ++h) {
        float acc = bg2[h];
#pragma unroll
        for (int j = 0; j < GH; ++j) acc += hid[j] * Wg2[h * GH + j];
        tbl[i * NH + h] = acc;
    }
}

// ---------------- qkv via split-bf16 MFMA (unchanged from R4) ----------------
__global__ __launch_bounds__(256) void qkv_mfma_kernel(
    const unsigned short* __restrict__ xh, const unsigned short* __restrict__ xl,
    const unsigned short* __restrict__ wh, const unsigned short* __restrict__ wl,
    const float* __restrict__ bq, const float* __restrict__ bk, const float* __restrict__ bv,
    float* __restrict__ q, float* __restrict__ k, float* __restrict__ v, int Nn) {
    const int n0 = blockIdx.x * 64;
    const int wsel = blockIdx.y;
    const unsigned short* W_h = wh + (size_t)wsel * (OUT_DIM * IN_DIM);
    const unsigned short* W_l = wl + (size_t)wsel * (OUT_DIM * IN_DIM);
    const float* bias = (wsel == 0) ? bq : (wsel == 1) ? bk : bv;
    float* outp = (wsel == 0) ? q : (wsel == 1) ? k : v;

    __shared__ unsigned short xh_s[64 * 40];
    __shared__ unsigned short xl_s[64 * 40];
    __shared__ unsigned short wh_s[128 * 40];
    __shared__ unsigned short wl_s[128 * 40];

    const int tid = threadIdx.x;
    const int w = tid >> 6;
    const int lane = tid & 63;
    const int ml = lane & 15;
    const int quad = lane >> 4;

    const int rows_valid = min(64, Nn - n0);

    floatx4 acc[8];
#pragma unroll
    for (int ct = 0; ct < 8; ++ct) acc[ct] = (floatx4){0.f, 0.f, 0.f, 0.f};

    const short8 zero8 = {0, 0, 0, 0, 0, 0, 0, 0};

    for (int kc = 0; kc < IN_DIM; kc += 32) {
        {
            int r = tid >> 2, c = tid & 3;
            short8 vh = zero8, vl = zero8;
            if (r < rows_valid) {
                size_t g = (size_t)(n0 + r) * IN_DIM + kc + c * 8;
                vh = *(const short8*)(xh + g);
                vl = *(const short8*)(xl + g);
            }
            *(short8*)(xh_s + r * 40 + c * 8) = vh;
            *(short8*)(xl_s + r * 40 + c * 8) = vl;
        }
#pragma unroll
        for (int l = 0; l < 2; ++l) {
            int idx = tid + l * 256;
            int r = idx >> 2, c = idx & 3;
            size_t g = (size_t)r * IN_DIM + kc + c * 8;
            *(short8*)(wh_s + r * 40 + c * 8) = *(const short8*)(W_h + g);
            *(short8*)(wl_s + r * 40 + c * 8) = *(const short8*)(W_l + g);
        }
        __syncthreads();

        short8 ah = *(const short8*)(xh_s + (w * 16 + ml) * 40 + quad * 8);
        short8 al = *(const short8*)(xl_s + (w * 16 + ml) * 40 + quad * 8);
#pragma unroll
        for (int ct = 0; ct < 8; ++ct) {
            short8 bh = *(const short8*)(wh_s + (ct * 16 + ml) * 40 + quad * 8);
            short8 bl = *(const short8*)(wl_s + (ct * 16 + ml) * 40 + quad * 8);
            acc[ct] = __builtin_amdgcn_mfma_f32_16x16x32_bf16(ah, bh, acc[ct], 0, 0, 0);
            acc[ct] = __builtin_amdgcn_mfma_f32_16x16x32_bf16(al, bh, acc[ct], 0, 0, 0);
            acc[ct] = __builtin_amdgcn_mfma_f32_16x16x32_bf16(ah, bl, acc[ct], 0, 0, 0);
        }
        __syncthreads();
    }

#pragma unroll
    for (int ct = 0; ct < 8; ++ct) {
        float bj = bias[ct * 16 + ml];
#pragma unroll
        for (int r = 0; r < 4; ++r) {
            int grow = n0 + w * 16 + quad * 4 + r;
            if (grow < Nn) outp[(size_t)grow * 128 + ct * 16 + ml] = acc[ct][r] + bj;
        }
    }
}

// ---------------- fp32 register-tiled GEMM (final Wo GEMM) ----------------
template <int K>
static __device__ __forceinline__ void gemm_tile(const float* __restrict__ X,
                                                 const float* __restrict__ W,
                                                 const float* __restrict__ b,
                                                 float* __restrict__ out,
                                                 int n0, int Nn) {
    __shared__ float xs[64 * 32];
    __shared__ float wsm[128 * 32];
    const int tid = threadIdx.x;
    const int tx = tid & 15;
    const int ty = tid >> 4;
    float acc[4][8];
#pragma unroll
    for (int i = 0; i < 4; ++i)
#pragma unroll
        for (int j = 0; j < 8; ++j) acc[i][j] = 0.0f;

    const int rows_valid = min(64, Nn - n0);

    for (int kc = 0; kc < K; kc += 32) {
#pragma unroll
        for (int l = 0; l < 2; ++l) {
            int fl = tid + l * 256;
            int r = fl >> 3, c4 = fl & 7;
            float4 val = make_float4(0.f, 0.f, 0.f, 0.f);
            if (r < rows_valid) val = *(const float4*)(X + (size_t)(n0 + r) * K + kc + c4 * 4);
            int slot = c4 ^ ((r >> 3) & 7);
            *(float4*)(xs + r * 32 + slot * 4) = val;
        }
#pragma unroll
        for (int l = 0; l < 4; ++l) {
            int fl = tid + l * 256;
            int r = fl >> 3, c4 = fl & 7;
            float4 val = *(const float4*)(W + (size_t)r * K + kc + c4 * 4);
            int slot = c4 ^ ((r >> 3) & 7);
            *(float4*)(wsm + r * 32 + slot * 4) = val;
        }
        __syncthreads();
#pragma unroll
        for (int k4 = 0; k4 < 8; ++k4) {
            float4 xa[4], wb[8];
#pragma unroll
            for (int i = 0; i < 4; ++i) {
                int r = ty * 4 + i;
                int slot = k4 ^ ((r >> 3) & 7);
                xa[i] = *(const float4*)(xs + r * 32 + slot * 4);
            }
#pragma unroll
            for (int j = 0; j < 8; ++j) {
                int r = tx * 8 + j;
                int slot = k4 ^ ((r >> 3) & 7);
                wb[j] = *(const float4*)(wsm + r * 32 + slot * 4);
            }
#pragma unroll
            for (int i = 0; i < 4; ++i)
#pragma unroll
                for (int j = 0; j < 8; ++j) {
                    acc[i][j] += xa[i].x * wb[j].x;
                    acc[i][j] += xa[i].y * wb[j].y;
                    acc[i][j] += xa[i].z * wb[j].z;
                    acc[i][j] += xa[i].w * wb[j].w;
                }
        }
        __syncthreads();
    }

    float bj[8];
#pragma unroll
    for (int j = 0; j < 8; ++j) bj[j] = b[tx * 8 + j];
#pragma unroll
    for (int i = 0; i < 4; ++i) {
        int r = ty * 4 + i;
        if (r < rows_valid) {
            float4 o0 = make_float4(acc[i][0] + bj[0], acc[i][1] + bj[1],
                                    acc[i][2] + bj[2], acc[i][3] + bj[3]);
            float4 o1 = make_float4(acc[i][4] + bj[4], acc[i][5] + bj[5],
                                    acc[i][6] + bj[6], acc[i][7] + bj[7]);
            float* op = out + (size_t)(n0 + r) * 128 + tx * 8;
            *(float4*)op = o0;
            *(float4*)(op + 4) = o1;
        }
    }
}

__global__ __launch_bounds__(256) void out_gemm_kernel(const float* __restrict__ in,
                                                       const float* __restrict__ Wo, const float* __restrict__ bo,
                                                       float* __restrict__ out, int Nn) {
    gemm_tile<OUT_DIM>(in, Wo, bo, out, blockIdx.x * 64, Nn);
}

// ---------------- CSR build ----------------
__global__ void deg_kernel(const int* __restrict__ ei, int* __restrict__ deg, int E_) {
    int e = blockIdx.x * 256 + threadIdx.x;
    if (e < E_) atomicAdd(&deg[ei[e]], 1);
}

__global__ __launch_bounds__(1024) void scan_kernel(const int* __restrict__ deg,
                                                    int* __restrict__ rowstart,
                                                    int* __restrict__ cursor, int n) {
    __shared__ int sm[1024];
    int t = threadIdx.x;
    int chunk = (n + 1023) / 1024;
    int b0 = t * chunk;
    int b1 = min(b0 + chunk, n);
    int lsum = 0;
    for (int i = b0; i < b1; ++i) lsum += deg[i];
    sm[t] = lsum;
    __syncthreads();
    for (int off = 1; off < 1024; off <<= 1) {
        int other = (t >= off) ? sm[t - off] : 0;
        __syncthreads();
        sm[t] += other;
        __syncthreads();
    }
    int run = sm[t] - lsum;
    for (int i = b0; i < b1; ++i) {
        rowstart[i] = run;
        cursor[i] = run;
        run += deg[i];
    }
    if (t == 1023) rowstart[n] = sm[1023];
}

// ---------------- scatter: ccol + cdist into CSR order (20 B/edge, no row gathers) ----------------
__global__ void scatter_kernel(const int* __restrict__ ei, const float* __restrict__ edist,
                               int* __restrict__ cursor, int* __restrict__ ccol,
                               float* __restrict__ cdist, int E_) {
    int e = blockIdx.x * 256 + threadIdx.x;
    if (e >= E_) return;
    int row = ei[e];
    int pos = atomicAdd(&cursor[row], 1);
    ccol[pos] = ei[E_ + e];
    cdist[pos] = edist[e];
}

// ---------------- fused flash-style edge+node pass ----------------
// One wave per destination node. Lane L holds features f=2L,2L+1 (head h=L>>3).
// Per edge: gather k[col], v[col] (float2/lane, coalesced 512B across wave),
// per-head dot via 3 shfl_xor in 8-lane groups, geo-bias table lerp (one
// cacheline/edge), online-softmax (m,l,o) update. q[row] read ONCE per node
// (wave-uniform) instead of per edge -- kills the 410MB q-gather of R4's edge
// pass and the entire separate node pass + attn intermediate.
__global__ __launch_bounds__(256) void fused_node_kernel(
    const float* __restrict__ q, const float* __restrict__ k, const float* __restrict__ v,
    const int* __restrict__ ccol, const float* __restrict__ cdist,
    const float* __restrict__ tbl, const int* __restrict__ rowstart,
    float* __restrict__ outacc, int Nn) {
    int lane = threadIdx.x & 63;
    int n = blockIdx.x * 4 + (threadIdx.x >> 6);
    if (n >= Nn) return;
    int start = rowstart[n];
    int end = rowstart[n + 1];
    int h = lane >> 3;

    float2 q2 = *(const float2*)(q + (size_t)n * 128 + lane * 2);

    float m = -1e30f, l = 0.0f;
    float ox = 0.0f, oy = 0.0f;

    int ncol = 0; float ndist = 0.0f;
    if (start < end) { ncol = ccol[start]; ndist = cdist[start]; }

    for (int i = start; i < end; ++i) {
        int col = ncol;
        float dist = ndist;
        if (i + 1 < end) { ncol = ccol[i + 1]; ndist = cdist[i + 1]; }

        float2 k2 = *(const float2*)(k + (size_t)col * 128 + lane * 2);
        float2 v2 = *(const float2*)(v + (size_t)col * 128 + lane * 2);

        float d = q2.x * k2.x + q2.y * k2.y;
        d += __shfl_xor(d, 1);
        d += __shfl_xor(d, 2);
        d += __shfl_xor(d, 4);

        float u = dist * ((float)(TBL - 1) / 6.0f);
        u = fminf(fmaxf(u, 0.0f), (float)(TBL - 1));
        int i0 = (int)u;
        if (i0 > TBL - 2) i0 = TBL - 2;
        float fr = u - (float)i0;
        float t0 = tbl[i0 * NH + h];
        float t1 = tbl[(i0 + 1) * NH + h];
        float logit = d * 0.25f + t0 + fr * (t1 - t0);

        float nm = fmaxf(m, logit);
        float resc = __expf(m - nm);
        float p = __expf(logit - nm);
        l = l * resc + p;
        ox = ox * resc + p * v2.x;
        oy = oy * resc + p * v2.y;
        m = nm;
    }

    float inv = 1.0f / (l + 1e-12f);
    float2 o2 = make_float2(ox * inv, oy * inv);
    *(float2*)(outacc + (size_t)n * 128 + lane * 2) = o2;
}

extern "C" void kernel_launch(void* const* d_in, const int* in_sizes, int n_in,
                              void* d_out, int out_size, void* d_ws, size_t ws_size,
                              hipStream_t stream) {
    const float* x   = (const float*)d_in[0];
    const int* ei    = (const int*)d_in[1];
    const float* edist = (const float*)d_in[2];
    const float* Wq = (const float*)d_in[3];  const float* bq = (const float*)d_in[4];
    const float* Wk = (const float*)d_in[5];  const float* bk = (const float*)d_in[6];
    const float* Wv = (const float*)d_in[7];  const float* bv = (const float*)d_in[8];
    const float* Wo = (const float*)d_in[9];  const float* bo = (const float*)d_in[10];
    const float* Wg1 = (const float*)d_in[11]; const float* bg1 = (const float*)d_in[12];
    const float* Wg2 = (const float*)d_in[13]; const float* bg2 = (const float*)d_in[14];
    const int Nn = in_sizes[0] / IN_DIM;
    const int Ee = in_sizes[2];
    float* out = (float*)d_out;

    char* ws = (char*)d_ws;
    size_t off = 0;
    auto alloc = [&](size_t bytes) -> char* {
        char* p = ws + off;
        off += (bytes + 255) & ~(size_t)255;
        return p;
    };
    float* q    = (float*)alloc((size_t)Nn * 128 * 4);
    float* kbuf = (float*)alloc((size_t)Nn * 128 * 4);
    float* vbuf = (float*)alloc((size_t)Nn * 128 * 4);
    // 25.6 MB block: xl (bf16 residual of x) during qkv_mfma; ccol+cdist after.
    char* xlblock = alloc((size_t)Nn * IN_DIM * 2);
    float* geot = (float*)alloc((size_t)TBL * 8 * 4);
    int* deg      = (int*)alloc((size_t)Nn * 4);
    int* rowstart = (int*)alloc((size_t)(Nn + 1) * 4);
    int* cursor   = (int*)alloc((size_t)Nn * 4);
    unsigned short* wh_all = (unsigned short*)alloc((size_t)3 * OUT_DIM * IN_DIM * 2);
    unsigned short* wl_all = (unsigned short*)alloc((size_t)3 * OUT_DIM * IN_DIM * 2);

    unsigned short* xh = (unsigned short*)d_out;       // rewritten by final GEMM
    unsigned short* xl = (unsigned short*)xlblock;
    int* ccol    = (int*)xlblock;                       // live after qkv_mfma
    float* cdist = (float*)(xlblock + (size_t)Ee * 4);
    float* outacc = q;  // each wave reads q-row n before writing out-row n

    hipMemsetAsync(deg, 0, (size_t)Nn * 4, stream);

    int n4x = Nn * IN_DIM / 4;
    split_x_kernel<<<(n4x + 255) / 256, 256, 0, stream>>>(x, xh, xl, n4x);
    split_w_kernel<<<dim3((OUT_DIM * IN_DIM / 4 + 255) / 256, 3), 256, 0, stream>>>(Wq, Wk, Wv, wh_all, wl_all);

    geo_table_kernel<<<(TBL + 255) / 256, 256, 0, stream>>>(Wg1, bg1, Wg2, bg2, geot);

    dim3 gq((Nn + 63) / 64, 3);
    qkv_mfma_kernel<<<gq, 256, 0, stream>>>(xh, xl, wh_all, wl_all, bq, bk, bv, q, kbuf, vbuf, Nn);

    deg_kernel<<<(Ee + 255) / 256, 256, 0, stream>>>(ei, deg, Ee);
    scan_kernel<<<1, 1024, 0, stream>>>(deg, rowstart, cursor, Nn);

    scatter_kernel<<<(Ee + 255) / 256, 256, 0, stream>>>(ei, edist, cursor, ccol, cdist, Ee);

    fused_node_kernel<<<(Nn + 3) / 4, 256, 0, stream>>>(q, kbuf, vbuf, ccol, cdist, geot, rowstart, outacc, Nn);

    out_gemm_kernel<<<(Nn + 63) / 64, 256, 0, stream>>>(outacc, Wo, bo, out, Nn);
}

// Round 6
// 499.613 us; speedup vs baseline: 3.8349x; 1.1043x over previous
//
#include <hip/hip_runtime.h>
#include <math.h>

#define IN_DIM 256
#define OUT_DIM 128
#define NH 8
#define HD 16
#define GH 16
#define TBL 1024

typedef __attribute__((ext_vector_type(8))) short short8;
typedef __attribute__((ext_vector_type(4))) float floatx4;

// ---------------- bf16 helpers (RNE) ----------------
__device__ __forceinline__ unsigned short f2bf(float f) {
    union { float f; unsigned u; } v; v.f = f;
    unsigned r = v.u + 0x7fffu + ((v.u >> 16) & 1u);
    return (unsigned short)(r >> 16);
}
__device__ __forceinline__ float bf2f(unsigned short h) {
    union { unsigned u; float f; } v; v.u = ((unsigned)h) << 16;
    return v.f;
}
__device__ __forceinline__ void split1(float f, unsigned short& h, unsigned short& l) {
    h = f2bf(f);
    l = f2bf(f - bf2f(h));
}

__global__ void split_x_kernel(const float* __restrict__ in, unsigned short* __restrict__ hi,
                               unsigned short* __restrict__ lo, int n4) {
    int i = blockIdx.x * 256 + threadIdx.x;
    if (i >= n4) return;
    float4 f = ((const float4*)in)[i];
    ushort4 h, l;
    split1(f.x, h.x, l.x); split1(f.y, h.y, l.y);
    split1(f.z, h.z, l.z); split1(f.w, h.w, l.w);
    ((ushort4*)hi)[i] = h;
    ((ushort4*)lo)[i] = l;
}

// split Wq/Wk/Wv into bf16 hi/lo planes (y=0..2) and build the geo bias table (y=3)
__global__ void prep_w_geo_kernel(const float* __restrict__ Wq, const float* __restrict__ Wk,
                                  const float* __restrict__ Wv,
                                  unsigned short* __restrict__ hi, unsigned short* __restrict__ lo,
                                  const float* __restrict__ Wg1, const float* __restrict__ bg1,
                                  const float* __restrict__ Wg2, const float* __restrict__ bg2,
                                  float* __restrict__ tbl) {
    int m = blockIdx.y;
    if (m < 3) {
        const float* W = (m == 0) ? Wq : (m == 1) ? Wk : Wv;
        int i = blockIdx.x * 256 + threadIdx.x;
        if (i >= (OUT_DIM * IN_DIM) / 4) return;
        float4 f = ((const float4*)W)[i];
        ushort4 h, l;
        split1(f.x, h.x, l.x); split1(f.y, h.y, l.y);
        split1(f.z, h.z, l.z); split1(f.w, h.w, l.w);
        size_t base = (size_t)m * (OUT_DIM * IN_DIM) / 4;
        ((ushort4*)hi)[base + i] = h;
        ((ushort4*)lo)[base + i] = l;
        return;
    }
    // geo bias table
    int i = blockIdx.x * 256 + threadIdx.x;
    if (i >= TBL) return;
    float d = (float)i * (6.0f / (float)(TBL - 1));
    float rbf[GH];
#pragma unroll
    for (int j = 0; j < GH; ++j) {
        float c = 0.4f * (float)j;
        float t = d - c;
        rbf[j] = __expf(-t * t);
    }
    float hid[GH];
#pragma unroll
    for (int j = 0; j < GH; ++j) {
        float acc = bg1[j];
#pragma unroll
        for (int kk = 0; kk < GH; ++kk) acc += rbf[kk] * Wg1[j * GH + kk];
        hid[j] = fmaxf(acc, 0.0f);
    }
#pragma unroll
    for (int h = 0; h < NH; ++h) {
        float acc = bg2[h];
#pragma unroll
        for (int j = 0; j < GH; ++j) acc += hid[j] * Wg2[h * GH + j];
        tbl[i * NH + h] = acc;
    }
}

// ---------------- qkv via split-bf16 MFMA; q stored fp32, k/v stored bf16 ----------------
__global__ __launch_bounds__(256) void qkv_mfma_kernel(
    const unsigned short* __restrict__ xh, const unsigned short* __restrict__ xl,
    const unsigned short* __restrict__ wh, const unsigned short* __restrict__ wl,
    const float* __restrict__ bq, const float* __restrict__ bk, const float* __restrict__ bv,
    float* __restrict__ q, unsigned short* __restrict__ kb, unsigned short* __restrict__ vb,
    int Nn) {
    const int n0 = blockIdx.x * 64;
    const int wsel = blockIdx.y;
    const unsigned short* W_h = wh + (size_t)wsel * (OUT_DIM * IN_DIM);
    const unsigned short* W_l = wl + (size_t)wsel * (OUT_DIM * IN_DIM);
    const float* bias = (wsel == 0) ? bq : (wsel == 1) ? bk : bv;

    __shared__ unsigned short xh_s[64 * 40];
    __shared__ unsigned short xl_s[64 * 40];
    __shared__ unsigned short wh_s[128 * 40];
    __shared__ unsigned short wl_s[128 * 40];

    const int tid = threadIdx.x;
    const int w = tid >> 6;
    const int lane = tid & 63;
    const int ml = lane & 15;
    const int quad = lane >> 4;

    const int rows_valid = min(64, Nn - n0);

    floatx4 acc[8];
#pragma unroll
    for (int ct = 0; ct < 8; ++ct) acc[ct] = (floatx4){0.f, 0.f, 0.f, 0.f};

    const short8 zero8 = {0, 0, 0, 0, 0, 0, 0, 0};

    for (int kc = 0; kc < IN_DIM; kc += 32) {
        {
            int r = tid >> 2, c = tid & 3;
            short8 vh = zero8, vl = zero8;
            if (r < rows_valid) {
                size_t g = (size_t)(n0 + r) * IN_DIM + kc + c * 8;
                vh = *(const short8*)(xh + g);
                vl = *(const short8*)(xl + g);
            }
            *(short8*)(xh_s + r * 40 + c * 8) = vh;
            *(short8*)(xl_s + r * 40 + c * 8) = vl;
        }
#pragma unroll
        for (int l = 0; l < 2; ++l) {
            int idx = tid + l * 256;
            int r = idx >> 2, c = idx & 3;
            size_t g = (size_t)r * IN_DIM + kc + c * 8;
            *(short8*)(wh_s + r * 40 + c * 8) = *(const short8*)(W_h + g);
            *(short8*)(wl_s + r * 40 + c * 8) = *(const short8*)(W_l + g);
        }
        __syncthreads();

        short8 ah = *(const short8*)(xh_s + (w * 16 + ml) * 40 + quad * 8);
        short8 al = *(const short8*)(xl_s + (w * 16 + ml) * 40 + quad * 8);
#pragma unroll
        for (int ct = 0; ct < 8; ++ct) {
            short8 bh = *(const short8*)(wh_s + (ct * 16 + ml) * 40 + quad * 8);
            short8 bl = *(const short8*)(wl_s + (ct * 16 + ml) * 40 + quad * 8);
            acc[ct] = __builtin_amdgcn_mfma_f32_16x16x32_bf16(ah, bh, acc[ct], 0, 0, 0);
            acc[ct] = __builtin_amdgcn_mfma_f32_16x16x32_bf16(al, bh, acc[ct], 0, 0, 0);
            acc[ct] = __builtin_amdgcn_mfma_f32_16x16x32_bf16(ah, bl, acc[ct], 0, 0, 0);
        }
        __syncthreads();
    }

    if (wsel == 0) {
#pragma unroll
        for (int ct = 0; ct < 8; ++ct) {
            float bj = bias[ct * 16 + ml];
#pragma unroll
            for (int r = 0; r < 4; ++r) {
                int grow = n0 + w * 16 + quad * 4 + r;
                if (grow < Nn) q[(size_t)grow * 128 + ct * 16 + ml] = acc[ct][r] + bj;
            }
        }
    } else {
        unsigned short* ob = (wsel == 1) ? kb : vb;
#pragma unroll
        for (int ct = 0; ct < 8; ++ct) {
            float bj = bias[ct * 16 + ml];
#pragma unroll
            for (int r = 0; r < 4; ++r) {
                int grow = n0 + w * 16 + quad * 4 + r;
                if (grow < Nn) ob[(size_t)grow * 128 + ct * 16 + ml] = f2bf(acc[ct][r] + bj);
            }
        }
    }
}

// ---------------- fp32 register-tiled GEMM (final Wo GEMM) ----------------
template <int K>
static __device__ __forceinline__ void gemm_tile(const float* __restrict__ X,
                                                 const float* __restrict__ W,
                                                 const float* __restrict__ b,
                                                 float* __restrict__ out,
                                                 int n0, int Nn) {
    __shared__ float xs[64 * 32];
    __shared__ float wsm[128 * 32];
    const int tid = threadIdx.x;
    const int tx = tid & 15;
    const int ty = tid >> 4;
    float acc[4][8];
#pragma unroll
    for (int i = 0; i < 4; ++i)
#pragma unroll
        for (int j = 0; j < 8; ++j) acc[i][j] = 0.0f;

    const int rows_valid = min(64, Nn - n0);

    for (int kc = 0; kc < K; kc += 32) {
#pragma unroll
        for (int l = 0; l < 2; ++l) {
            int fl = tid + l * 256;
            int r = fl >> 3, c4 = fl & 7;
            float4 val = make_float4(0.f, 0.f, 0.f, 0.f);
            if (r < rows_valid) val = *(const float4*)(X + (size_t)(n0 + r) * K + kc + c4 * 4);
            int slot = c4 ^ ((r >> 3) & 7);
            *(float4*)(xs + r * 32 + slot * 4) = val;
        }
#pragma unroll
        for (int l = 0; l < 4; ++l) {
            int fl = tid + l * 256;
            int r = fl >> 3, c4 = fl & 7;
            float4 val = *(const float4*)(W + (size_t)r * K + kc + c4 * 4);
            int slot = c4 ^ ((r >> 3) & 7);
            *(float4*)(wsm + r * 32 + slot * 4) = val;
        }
        __syncthreads();
#pragma unroll
        for (int k4 = 0; k4 < 8; ++k4) {
            float4 xa[4], wb[8];
#pragma unroll
            for (int i = 0; i < 4; ++i) {
                int r = ty * 4 + i;
                int slot = k4 ^ ((r >> 3) & 7);
                xa[i] = *(const float4*)(xs + r * 32 + slot * 4);
            }
#pragma unroll
            for (int j = 0; j < 8; ++j) {
                int r = tx * 8 + j;
                int slot = k4 ^ ((r >> 3) & 7);
                wb[j] = *(const float4*)(wsm + r * 32 + slot * 4);
            }
#pragma unroll
            for (int i = 0; i < 4; ++i)
#pragma unroll
                for (int j = 0; j < 8; ++j) {
                    acc[i][j] += xa[i].x * wb[j].x;
                    acc[i][j] += xa[i].y * wb[j].y;
                    acc[i][j] += xa[i].z * wb[j].z;
                    acc[i][j] += xa[i].w * wb[j].w;
                }
        }
        __syncthreads();
    }

    float bj[8];
#pragma unroll
    for (int j = 0; j < 8; ++j) bj[j] = b[tx * 8 + j];
#pragma unroll
    for (int i = 0; i < 4; ++i) {
        int r = ty * 4 + i;
        if (r < rows_valid) {
            float4 o0 = make_float4(acc[i][0] + bj[0], acc[i][1] + bj[1],
                                    acc[i][2] + bj[2], acc[i][3] + bj[3]);
            float4 o1 = make_float4(acc[i][4] + bj[4], acc[i][5] + bj[5],
                                    acc[i][6] + bj[6], acc[i][7] + bj[7]);
            float* op = out + (size_t)(n0 + r) * 128 + tx * 8;
            *(float4*)op = o0;
            *(float4*)(op + 4) = o1;
        }
    }
}

__global__ __launch_bounds__(256) void out_gemm_kernel(const float* __restrict__ in,
                                                       const float* __restrict__ Wo, const float* __restrict__ bo,
                                                       float* __restrict__ out, int Nn) {
    gemm_tile<OUT_DIM>(in, Wo, bo, out, blockIdx.x * 64, Nn);
}

// ---------------- CSR build ----------------
__global__ void deg_kernel(const int* __restrict__ ei, int* __restrict__ deg, int E_) {
    int e = blockIdx.x * 256 + threadIdx.x;
    if (e < E_) atomicAdd(&deg[ei[e]], 1);
}

__global__ __launch_bounds__(1024) void scan_kernel(const int* __restrict__ deg,
                                                    int* __restrict__ rowstart,
                                                    int* __restrict__ cursor, int n) {
    __shared__ int sm[1024];
    int t = threadIdx.x;
    int chunk = (n + 1023) / 1024;
    int b0 = t * chunk;
    int b1 = min(b0 + chunk, n);
    int lsum = 0;
    for (int i = b0; i < b1; ++i) lsum += deg[i];
    sm[t] = lsum;
    __syncthreads();
    for (int off = 1; off < 1024; off <<= 1) {
        int other = (t >= off) ? sm[t - off] : 0;
        __syncthreads();
        sm[t] += other;
        __syncthreads();
    }
    int run = sm[t] - lsum;
    for (int i = b0; i < b1; ++i) {
        rowstart[i] = run;
        cursor[i] = run;
        run += deg[i];
    }
    if (t == 1023) rowstart[n] = sm[1023];
}

// ---------------- scatter: {col, dist} packed int2 into CSR order (one 8B write/edge) ----------------
__global__ void scatter_kernel(const int* __restrict__ ei, const float* __restrict__ edist,
                               int* __restrict__ cursor, int2* __restrict__ cpack, int E_) {
    int e = blockIdx.x * 256 + threadIdx.x;
    if (e >= E_) return;
    int row = ei[e];
    int pos = atomicAdd(&cursor[row], 1);
    cpack[pos] = make_int2(ei[E_ + e], __float_as_int(edist[e]));
}

// ---------------- fused flash-style edge+node pass (bf16 k/v gathers) ----------------
// One wave per destination node. Lane L holds features f=2L,2L+1 (head h=L>>3).
// Per edge: one int2 (col,dist), one u32 of bf16 k-pair, one u32 of bf16 v-pair
// per lane (512B/edge across the wave -- half of R5's fp32 1KB). Per-head dot
// via 3 shfl_xor in 8-lane groups; geo-bias table lerp; online softmax.
__global__ __launch_bounds__(256) void fused_node_kernel(
    const float* __restrict__ q, const unsigned short* __restrict__ kb,
    const unsigned short* __restrict__ vb, const int2* __restrict__ cpack,
    const float* __restrict__ tbl, const int* __restrict__ rowstart,
    float* __restrict__ outacc, int Nn) {
    int lane = threadIdx.x & 63;
    int n = blockIdx.x * 4 + (threadIdx.x >> 6);
    if (n >= Nn) return;
    int start = rowstart[n];
    int end = rowstart[n + 1];
    int h = lane >> 3;

    float2 q2 = *(const float2*)(q + (size_t)n * 128 + lane * 2);

    float m = -1e30f, l = 0.0f;
    float ox = 0.0f, oy = 0.0f;

    int2 np = make_int2(0, 0);
    if (start < end) np = cpack[start];

    for (int i = start; i < end; ++i) {
        int col = np.x;
        float dist = __int_as_float(np.y);
        if (i + 1 < end) np = cpack[i + 1];

        unsigned ku = *(const unsigned*)(kb + (size_t)col * 128 + lane * 2);
        unsigned vu = *(const unsigned*)(vb + (size_t)col * 128 + lane * 2);
        float kx = __uint_as_float(ku << 16);
        float ky = __uint_as_float(ku & 0xffff0000u);
        float vx = __uint_as_float(vu << 16);
        float vy = __uint_as_float(vu & 0xffff0000u);

        float d = q2.x * kx + q2.y * ky;
        d += __shfl_xor(d, 1);
        d += __shfl_xor(d, 2);
        d += __shfl_xor(d, 4);

        float u = dist * ((float)(TBL - 1) / 6.0f);
        u = fminf(fmaxf(u, 0.0f), (float)(TBL - 1));
        int i0 = (int)u;
        if (i0 > TBL - 2) i0 = TBL - 2;
        float fr = u - (float)i0;
        float t0 = tbl[i0 * NH + h];
        float t1 = tbl[(i0 + 1) * NH + h];
        float logit = d * 0.25f + t0 + fr * (t1 - t0);

        float nm = fmaxf(m, logit);
        float resc = __expf(m - nm);
        float p = __expf(logit - nm);
        l = l * resc + p;
        ox = ox * resc + p * vx;
        oy = oy * resc + p * vy;
        m = nm;
    }

    float inv = 1.0f / (l + 1e-12f);
    *(float2*)(outacc + (size_t)n * 128 + lane * 2) = make_float2(ox * inv, oy * inv);
}

extern "C" void kernel_launch(void* const* d_in, const int* in_sizes, int n_in,
                              void* d_out, int out_size, void* d_ws, size_t ws_size,
                              hipStream_t stream) {
    const float* x   = (const float*)d_in[0];
    const int* ei    = (const int*)d_in[1];
    const float* edist = (const float*)d_in[2];
    const float* Wq = (const float*)d_in[3];  const float* bq = (const float*)d_in[4];
    const float* Wk = (const float*)d_in[5];  const float* bk = (const float*)d_in[6];
    const float* Wv = (const float*)d_in[7];  const float* bv = (const float*)d_in[8];
    const float* Wo = (const float*)d_in[9];  const float* bo = (const float*)d_in[10];
    const float* Wg1 = (const float*)d_in[11]; const float* bg1 = (const float*)d_in[12];
    const float* Wg2 = (const float*)d_in[13]; const float* bg2 = (const float*)d_in[14];
    const int Nn = in_sizes[0] / IN_DIM;
    const int Ee = in_sizes[2];
    float* out = (float*)d_out;

    char* ws = (char*)d_ws;
    size_t off = 0;
    auto alloc = [&](size_t bytes) -> char* {
        char* p = ws + off;
        off += (bytes + 255) & ~(size_t)255;
        return p;
    };
    float* q  = (float*)alloc((size_t)Nn * 128 * 4);
    unsigned short* kbuf = (unsigned short*)alloc((size_t)Nn * 128 * 2);
    unsigned short* vbuf = (unsigned short*)alloc((size_t)Nn * 128 * 2);
    // 25.6 MB block: xl (bf16 residual of x) during qkv_mfma; cpack (6.4 MB) after.
    char* xlblock = alloc((size_t)Nn * IN_DIM * 2);
    float* geot = (float*)alloc((size_t)TBL * 8 * 4);
    int* deg      = (int*)alloc((size_t)Nn * 4);
    int* rowstart = (int*)alloc((size_t)(Nn + 1) * 4);
    int* cursor   = (int*)alloc((size_t)Nn * 4);
    unsigned short* wh_all = (unsigned short*)alloc((size_t)3 * OUT_DIM * IN_DIM * 2);
    unsigned short* wl_all = (unsigned short*)alloc((size_t)3 * OUT_DIM * IN_DIM * 2);

    unsigned short* xh = (unsigned short*)d_out;       // rewritten by final GEMM
    unsigned short* xl = (unsigned short*)xlblock;
    int2* cpack = (int2*)xlblock;                       // live after qkv_mfma
    float* outacc = q;  // wave reads q-row n before writing out-row n; no cross-row use of q

    hipMemsetAsync(deg, 0, (size_t)Nn * 4, stream);

    int n4x = Nn * IN_DIM / 4;
    split_x_kernel<<<(n4x + 255) / 256, 256, 0, stream>>>(x, xh, xl, n4x);
    prep_w_geo_kernel<<<dim3((OUT_DIM * IN_DIM / 4 + 255) / 256, 4), 256, 0, stream>>>(
        Wq, Wk, Wv, wh_all, wl_all, Wg1, bg1, Wg2, bg2, geot);

    dim3 gq((Nn + 63) / 64, 3);
    qkv_mfma_kernel<<<gq, 256, 0, stream>>>(xh, xl, wh_all, wl_all, bq, bk, bv, q, kbuf, vbuf, Nn);

    deg_kernel<<<(Ee + 255) / 256, 256, 0, stream>>>(ei, deg, Ee);
    scan_kernel<<<1, 1024, 0, stream>>>(deg, rowstart, cursor, Nn);

    scatter_kernel<<<(Ee + 255) / 256, 256, 0, stream>>>(ei, edist, cursor, cpack, Ee);

    fused_node_kernel<<<(Nn + 3) / 4, 256, 0, stream>>>(q, kbuf, vbuf, cpack, geot, rowstart, outacc, Nn);

    out_gemm_kernel<<<(Nn + 63) / 64, 256, 0, stream>>>(outacc, Wo, bo, out, Nn);
}

// Round 7
// 398.822 us; speedup vs baseline: 4.8041x; 1.2527x over previous
//
#include <hip/hip_runtime.h>
#include <math.h>

#define IN_DIM 256
#define OUT_DIM 128
#define NH 8
#define HD 16
#define GH 16
#define TBL 1024

typedef __attribute__((ext_vector_type(8))) short short8;
typedef __attribute__((ext_vector_type(4))) float floatx4;

// ---------------- bf16 helpers (RNE) ----------------
__device__ __forceinline__ unsigned short f2bf(float f) {
    union { float f; unsigned u; } v; v.f = f;
    unsigned r = v.u + 0x7fffu + ((v.u >> 16) & 1u);
    return (unsigned short)(r >> 16);
}
__device__ __forceinline__ float bf2f(unsigned short h) {
    union { unsigned u; float f; } v; v.u = ((unsigned)h) << 16;
    return v.f;
}
__device__ __forceinline__ void split1(float f, unsigned short& h, unsigned short& l) {
    h = f2bf(f);
    l = f2bf(f - bf2f(h));
}

__global__ void split_x_kernel(const float* __restrict__ in, unsigned short* __restrict__ hi,
                               unsigned short* __restrict__ lo, int n4) {
    int i = blockIdx.x * 256 + threadIdx.x;
    if (i >= n4) return;
    float4 f = ((const float4*)in)[i];
    ushort4 h, l;
    split1(f.x, h.x, l.x); split1(f.y, h.y, l.y);
    split1(f.z, h.z, l.z); split1(f.w, h.w, l.w);
    ((ushort4*)hi)[i] = h;
    ((ushort4*)lo)[i] = l;
}

// split Wq/Wk/Wv into bf16 hi/lo planes (y=0..2) and build the geo bias table (y=3)
__global__ void prep_w_geo_kernel(const float* __restrict__ Wq, const float* __restrict__ Wk,
                                  const float* __restrict__ Wv,
                                  unsigned short* __restrict__ hi, unsigned short* __restrict__ lo,
                                  const float* __restrict__ Wg1, const float* __restrict__ bg1,
                                  const float* __restrict__ Wg2, const float* __restrict__ bg2,
                                  float* __restrict__ tbl) {
    int m = blockIdx.y;
    if (m < 3) {
        const float* W = (m == 0) ? Wq : (m == 1) ? Wk : Wv;
        int i = blockIdx.x * 256 + threadIdx.x;
        if (i >= (OUT_DIM * IN_DIM) / 4) return;
        float4 f = ((const float4*)W)[i];
        ushort4 h, l;
        split1(f.x, h.x, l.x); split1(f.y, h.y, l.y);
        split1(f.z, h.z, l.z); split1(f.w, h.w, l.w);
        size_t base = (size_t)m * (OUT_DIM * IN_DIM) / 4;
        ((ushort4*)hi)[base + i] = h;
        ((ushort4*)lo)[base + i] = l;
        return;
    }
    // geo bias table
    int i = blockIdx.x * 256 + threadIdx.x;
    if (i >= TBL) return;
    float d = (float)i * (6.0f / (float)(TBL - 1));
    float rbf[GH];
#pragma unroll
    for (int j = 0; j < GH; ++j) {
        float c = 0.4f * (float)j;
        float t = d - c;
        rbf[j] = __expf(-t * t);
    }
    float hid[GH];
#pragma unroll
    for (int j = 0; j < GH; ++j) {
        float acc = bg1[j];
#pragma unroll
        for (int kk = 0; kk < GH; ++kk) acc += rbf[kk] * Wg1[j * GH + kk];
        hid[j] = fmaxf(acc, 0.0f);
    }
#pragma unroll
    for (int h = 0; h < NH; ++h) {
        float acc = bg2[h];
#pragma unroll
        for (int j = 0; j < GH; ++j) acc += hid[j] * Wg2[h * GH + j];
        tbl[i * NH + h] = acc;
    }
}

// ---------------- qkv via split-bf16 MFMA; q stored fp32, k/v stored bf16 ----------------
__global__ __launch_bounds__(256) void qkv_mfma_kernel(
    const unsigned short* __restrict__ xh, const unsigned short* __restrict__ xl,
    const unsigned short* __restrict__ wh, const unsigned short* __restrict__ wl,
    const float* __restrict__ bq, const float* __restrict__ bk, const float* __restrict__ bv,
    float* __restrict__ q, unsigned short* __restrict__ kb, unsigned short* __restrict__ vb,
    int Nn) {
    const int n0 = blockIdx.x * 64;
    const int wsel = blockIdx.y;
    const unsigned short* W_h = wh + (size_t)wsel * (OUT_DIM * IN_DIM);
    const unsigned short* W_l = wl + (size_t)wsel * (OUT_DIM * IN_DIM);
    const float* bias = (wsel == 0) ? bq : (wsel == 1) ? bk : bv;

    __shared__ unsigned short xh_s[64 * 40];
    __shared__ unsigned short xl_s[64 * 40];
    __shared__ unsigned short wh_s[128 * 40];
    __shared__ unsigned short wl_s[128 * 40];

    const int tid = threadIdx.x;
    const int w = tid >> 6;
    const int lane = tid & 63;
    const int ml = lane & 15;
    const int quad = lane >> 4;

    const int rows_valid = min(64, Nn - n0);

    floatx4 acc[8];
#pragma unroll
    for (int ct = 0; ct < 8; ++ct) acc[ct] = (floatx4){0.f, 0.f, 0.f, 0.f};

    const short8 zero8 = {0, 0, 0, 0, 0, 0, 0, 0};

    for (int kc = 0; kc < IN_DIM; kc += 32) {
        {
            int r = tid >> 2, c = tid & 3;
            short8 vh = zero8, vl = zero8;
            if (r < rows_valid) {
                size_t g = (size_t)(n0 + r) * IN_DIM + kc + c * 8;
                vh = *(const short8*)(xh + g);
                vl = *(const short8*)(xl + g);
            }
            *(short8*)(xh_s + r * 40 + c * 8) = vh;
            *(short8*)(xl_s + r * 40 + c * 8) = vl;
        }
#pragma unroll
        for (int l = 0; l < 2; ++l) {
            int idx = tid + l * 256;
            int r = idx >> 2, c = idx & 3;
            size_t g = (size_t)r * IN_DIM + kc + c * 8;
            *(short8*)(wh_s + r * 40 + c * 8) = *(const short8*)(W_h + g);
            *(short8*)(wl_s + r * 40 + c * 8) = *(const short8*)(W_l + g);
        }
        __syncthreads();

        short8 ah = *(const short8*)(xh_s + (w * 16 + ml) * 40 + quad * 8);
        short8 al = *(const short8*)(xl_s + (w * 16 + ml) * 40 + quad * 8);
#pragma unroll
        for (int ct = 0; ct < 8; ++ct) {
            short8 bh = *(const short8*)(wh_s + (ct * 16 + ml) * 40 + quad * 8);
            short8 bl = *(const short8*)(wl_s + (ct * 16 + ml) * 40 + quad * 8);
            acc[ct] = __builtin_amdgcn_mfma_f32_16x16x32_bf16(ah, bh, acc[ct], 0, 0, 0);
            acc[ct] = __builtin_amdgcn_mfma_f32_16x16x32_bf16(al, bh, acc[ct], 0, 0, 0);
            acc[ct] = __builtin_amdgcn_mfma_f32_16x16x32_bf16(ah, bl, acc[ct], 0, 0, 0);
        }
        __syncthreads();
    }

    if (wsel == 0) {
#pragma unroll
        for (int ct = 0; ct < 8; ++ct) {
            float bj = bias[ct * 16 + ml];
#pragma unroll
            for (int r = 0; r < 4; ++r) {
                int grow = n0 + w * 16 + quad * 4 + r;
                if (grow < Nn) q[(size_t)grow * 128 + ct * 16 + ml] = acc[ct][r] + bj;
            }
        }
    } else {
        unsigned short* ob = (wsel == 1) ? kb : vb;
#pragma unroll
        for (int ct = 0; ct < 8; ++ct) {
            float bj = bias[ct * 16 + ml];
#pragma unroll
            for (int r = 0; r < 4; ++r) {
                int grow = n0 + w * 16 + quad * 4 + r;
                if (grow < Nn) ob[(size_t)grow * 128 + ct * 16 + ml] = f2bf(acc[ct][r] + bj);
            }
        }
    }
}

// ---------------- fp32 register-tiled GEMM (final Wo GEMM) ----------------
template <int K>
static __device__ __forceinline__ void gemm_tile(const float* __restrict__ X,
                                                 const float* __restrict__ W,
                                                 const float* __restrict__ b,
                                                 float* __restrict__ out,
                                                 int n0, int Nn) {
    __shared__ float xs[64 * 32];
    __shared__ float wsm[128 * 32];
    const int tid = threadIdx.x;
    const int tx = tid & 15;
    const int ty = tid >> 4;
    float acc[4][8];
#pragma unroll
    for (int i = 0; i < 4; ++i)
#pragma unroll
        for (int j = 0; j < 8; ++j) acc[i][j] = 0.0f;

    const int rows_valid = min(64, Nn - n0);

    for (int kc = 0; kc < K; kc += 32) {
#pragma unroll
        for (int l = 0; l < 2; ++l) {
            int fl = tid + l * 256;
            int r = fl >> 3, c4 = fl & 7;
            float4 val = make_float4(0.f, 0.f, 0.f, 0.f);
            if (r < rows_valid) val = *(const float4*)(X + (size_t)(n0 + r) * K + kc + c4 * 4);
            int slot = c4 ^ ((r >> 3) & 7);
            *(float4*)(xs + r * 32 + slot * 4) = val;
        }
#pragma unroll
        for (int l = 0; l < 4; ++l) {
            int fl = tid + l * 256;
            int r = fl >> 3, c4 = fl & 7;
            float4 val = *(const float4*)(W + (size_t)r * K + kc + c4 * 4);
            int slot = c4 ^ ((r >> 3) & 7);
            *(float4*)(wsm + r * 32 + slot * 4) = val;
        }
        __syncthreads();
#pragma unroll
        for (int k4 = 0; k4 < 8; ++k4) {
            float4 xa[4], wb[8];
#pragma unroll
            for (int i = 0; i < 4; ++i) {
                int r = ty * 4 + i;
                int slot = k4 ^ ((r >> 3) & 7);
                xa[i] = *(const float4*)(xs + r * 32 + slot * 4);
            }
#pragma unroll
            for (int j = 0; j < 8; ++j) {
                int r = tx * 8 + j;
                int slot = k4 ^ ((r >> 3) & 7);
                wb[j] = *(const float4*)(wsm + r * 32 + slot * 4);
            }
#pragma unroll
            for (int i = 0; i < 4; ++i)
#pragma unroll
                for (int j = 0; j < 8; ++j) {
                    acc[i][j] += xa[i].x * wb[j].x;
                    acc[i][j] += xa[i].y * wb[j].y;
                    acc[i][j] += xa[i].z * wb[j].z;
                    acc[i][j] += xa[i].w * wb[j].w;
                }
        }
        __syncthreads();
    }

    float bj[8];
#pragma unroll
    for (int j = 0; j < 8; ++j) bj[j] = b[tx * 8 + j];
#pragma unroll
    for (int i = 0; i < 4; ++i) {
        int r = ty * 4 + i;
        if (r < rows_valid) {
            float4 o0 = make_float4(acc[i][0] + bj[0], acc[i][1] + bj[1],
                                    acc[i][2] + bj[2], acc[i][3] + bj[3]);
            float4 o1 = make_float4(acc[i][4] + bj[4], acc[i][5] + bj[5],
                                    acc[i][6] + bj[6], acc[i][7] + bj[7]);
            float* op = out + (size_t)(n0 + r) * 128 + tx * 8;
            *(float4*)op = o0;
            *(float4*)(op + 4) = o1;
        }
    }
}

__global__ __launch_bounds__(256) void out_gemm_kernel(const float* __restrict__ in,
                                                       const float* __restrict__ Wo, const float* __restrict__ bo,
                                                       float* __restrict__ out, int Nn) {
    gemm_tile<OUT_DIM>(in, Wo, bo, out, blockIdx.x * 64, Nn);
}

// ---------------- CSR build ----------------
__global__ void deg_kernel(const int* __restrict__ ei, int* __restrict__ deg, int E_) {
    int e = blockIdx.x * 256 + threadIdx.x;
    if (e < E_) atomicAdd(&deg[ei[e]], 1);
}

// 3-phase device-wide exclusive scan over deg[0..n) -> rowstart/cursor.
// R6 post-mortem: single-block scan was 108us (one CU, latency-bound serial walk).
// Phase A: 1024 elems/block, int4 loads, reduce -> part[b].
__global__ __launch_bounds__(256) void scan_partial_kernel(const int* __restrict__ deg,
                                                           int* __restrict__ part, int n) {
    __shared__ int sm[4];
    int t = threadIdx.x;
    int idx4 = blockIdx.x * 1024 + t * 4;
    int s = 0;
    if (idx4 + 3 < n) {
        int4 d = *(const int4*)(deg + idx4);
        s = d.x + d.y + d.z + d.w;
    } else {
#pragma unroll
        for (int j = 0; j < 4; ++j) if (idx4 + j < n) s += deg[idx4 + j];
    }
#pragma unroll
    for (int off = 1; off < 64; off <<= 1) s += __shfl_xor(s, off);
    if ((t & 63) == 0) sm[t >> 6] = s;
    __syncthreads();
    if (t == 0) part[blockIdx.x] = sm[0] + sm[1] + sm[2] + sm[3];
}

// Phase B: one block scans npart (<=256) partials in place to exclusive; writes rowstart[n].
__global__ __launch_bounds__(256) void scan_block_kernel(int* __restrict__ part, int npart,
                                                         int* __restrict__ rowstart, int n) {
    __shared__ int sm[256];
    int t = threadIdx.x;
    int v = (t < npart) ? part[t] : 0;
    sm[t] = v;
    __syncthreads();
    for (int off = 1; off < 256; off <<= 1) {
        int o = (t >= off) ? sm[t - off] : 0;
        __syncthreads();
        sm[t] += o;
        __syncthreads();
    }
    if (t < npart) part[t] = sm[t] - v;       // exclusive block offset
    if (t == 255) rowstart[n] = sm[255];      // grand total
}

// Phase C: block-local exclusive scan + block offset; int4 stores to rowstart & cursor.
__global__ __launch_bounds__(256) void scan_write_kernel(const int* __restrict__ deg,
                                                         const int* __restrict__ part,
                                                         int* __restrict__ rowstart,
                                                         int* __restrict__ cursor, int n) {
    __shared__ int sm[256];
    int t = threadIdx.x;
    int idx4 = blockIdx.x * 1024 + t * 4;
    int d0 = 0, d1 = 0, d2 = 0, d3 = 0;
    if (idx4 + 3 < n) {
        int4 d = *(const int4*)(deg + idx4);
        d0 = d.x; d1 = d.y; d2 = d.z; d3 = d.w;
    } else {
        if (idx4 + 0 < n) d0 = deg[idx4 + 0];
        if (idx4 + 1 < n) d1 = deg[idx4 + 1];
        if (idx4 + 2 < n) d2 = deg[idx4 + 2];
        if (idx4 + 3 < n) d3 = deg[idx4 + 3];
    }
    int s = d0 + d1 + d2 + d3;
    sm[t] = s;
    __syncthreads();
    for (int off = 1; off < 256; off <<= 1) {
        int o = (t >= off) ? sm[t - off] : 0;
        __syncthreads();
        sm[t] += o;
        __syncthreads();
    }
    int run = part[blockIdx.x] + sm[t] - s;   // exclusive prefix of this thread's first elem
    int4 rs;
    rs.x = run;
    rs.y = run + d0;
    rs.z = rs.y + d1;
    rs.w = rs.z + d2;
    if (idx4 + 3 < n) {
        *(int4*)(rowstart + idx4) = rs;
        *(int4*)(cursor + idx4) = rs;
    } else {
        int rv[4] = {rs.x, rs.y, rs.z, rs.w};
#pragma unroll
        for (int j = 0; j < 4; ++j)
            if (idx4 + j < n) { rowstart[idx4 + j] = rv[j]; cursor[idx4 + j] = rv[j]; }
    }
}

// ---------------- scatter: {col, dist} packed int2 into CSR order (one 8B write/edge) ----------------
__global__ void scatter_kernel(const int* __restrict__ ei, const float* __restrict__ edist,
                               int* __restrict__ cursor, int2* __restrict__ cpack, int E_) {
    int e = blockIdx.x * 256 + threadIdx.x;
    if (e >= E_) return;
    int row = ei[e];
    int pos = atomicAdd(&cursor[row], 1);
    cpack[pos] = make_int2(ei[E_ + e], __float_as_int(edist[e]));
}

// ---------------- fused flash-style edge+node pass (bf16 k/v gathers) ----------------
__global__ __launch_bounds__(256) void fused_node_kernel(
    const float* __restrict__ q, const unsigned short* __restrict__ kb,
    const unsigned short* __restrict__ vb, const int2* __restrict__ cpack,
    const float* __restrict__ tbl, const int* __restrict__ rowstart,
    float* __restrict__ outacc, int Nn) {
    int lane = threadIdx.x & 63;
    int n = blockIdx.x * 4 + (threadIdx.x >> 6);
    if (n >= Nn) return;
    int start = rowstart[n];
    int end = rowstart[n + 1];
    int h = lane >> 3;

    float2 q2 = *(const float2*)(q + (size_t)n * 128 + lane * 2);

    float m = -1e30f, l = 0.0f;
    float ox = 0.0f, oy = 0.0f;

    int2 np = make_int2(0, 0);
    if (start < end) np = cpack[start];

    for (int i = start; i < end; ++i) {
        int col = np.x;
        float dist = __int_as_float(np.y);
        if (i + 1 < end) np = cpack[i + 1];

        unsigned ku = *(const unsigned*)(kb + (size_t)col * 128 + lane * 2);
        unsigned vu = *(const unsigned*)(vb + (size_t)col * 128 + lane * 2);
        float kx = __uint_as_float(ku << 16);
        float ky = __uint_as_float(ku & 0xffff0000u);
        float vx = __uint_as_float(vu << 16);
        float vy = __uint_as_float(vu & 0xffff0000u);

        float d = q2.x * kx + q2.y * ky;
        d += __shfl_xor(d, 1);
        d += __shfl_xor(d, 2);
        d += __shfl_xor(d, 4);

        float u = dist * ((float)(TBL - 1) / 6.0f);
        u = fminf(fmaxf(u, 0.0f), (float)(TBL - 1));
        int i0 = (int)u;
        if (i0 > TBL - 2) i0 = TBL - 2;
        float fr = u - (float)i0;
        float t0 = tbl[i0 * NH + h];
        float t1 = tbl[(i0 + 1) * NH + h];
        float logit = d * 0.25f + t0 + fr * (t1 - t0);

        float nm = fmaxf(m, logit);
        float resc = __expf(m - nm);
        float p = __expf(logit - nm);
        l = l * resc + p;
        ox = ox * resc + p * vx;
        oy = oy * resc + p * vy;
        m = nm;
    }

    float inv = 1.0f / (l + 1e-12f);
    *(float2*)(outacc + (size_t)n * 128 + lane * 2) = make_float2(ox * inv, oy * inv);
}

extern "C" void kernel_launch(void* const* d_in, const int* in_sizes, int n_in,
                              void* d_out, int out_size, void* d_ws, size_t ws_size,
                              hipStream_t stream) {
    const float* x   = (const float*)d_in[0];
    const int* ei    = (const int*)d_in[1];
    const float* edist = (const float*)d_in[2];
    const float* Wq = (const float*)d_in[3];  const float* bq = (const float*)d_in[4];
    const float* Wk = (const float*)d_in[5];  const float* bk = (const float*)d_in[6];
    const float* Wv = (const float*)d_in[7];  const float* bv = (const float*)d_in[8];
    const float* Wo = (const float*)d_in[9];  const float* bo = (const float*)d_in[10];
    const float* Wg1 = (const float*)d_in[11]; const float* bg1 = (const float*)d_in[12];
    const float* Wg2 = (const float*)d_in[13]; const float* bg2 = (const float*)d_in[14];
    const int Nn = in_sizes[0] / IN_DIM;
    const int Ee = in_sizes[2];
    float* out = (float*)d_out;

    char* ws = (char*)d_ws;
    size_t off = 0;
    auto alloc = [&](size_t bytes) -> char* {
        char* p = ws + off;
        off += (bytes + 255) & ~(size_t)255;
        return p;
    };
    float* q  = (float*)alloc((size_t)Nn * 128 * 4);
    unsigned short* kbuf = (unsigned short*)alloc((size_t)Nn * 128 * 2);
    unsigned short* vbuf = (unsigned short*)alloc((size_t)Nn * 128 * 2);
    // 25.6 MB block: xl (bf16 residual of x) during qkv_mfma; cpack (6.4 MB) after.
    char* xlblock = alloc((size_t)Nn * IN_DIM * 2);
    float* geot = (float*)alloc((size_t)TBL * 8 * 4);
    int* deg      = (int*)alloc((size_t)Nn * 4);
    int* rowstart = (int*)alloc((size_t)(Nn + 1) * 4);
    int* cursor   = (int*)alloc((size_t)Nn * 4);
    int* part     = (int*)alloc((size_t)256 * 4);
    unsigned short* wh_all = (unsigned short*)alloc((size_t)3 * OUT_DIM * IN_DIM * 2);
    unsigned short* wl_all = (unsigned short*)alloc((size_t)3 * OUT_DIM * IN_DIM * 2);

    unsigned short* xh = (unsigned short*)d_out;       // rewritten by final GEMM
    unsigned short* xl = (unsigned short*)xlblock;
    int2* cpack = (int2*)xlblock;                       // live after qkv_mfma
    float* outacc = q;  // wave reads q-row n before writing out-row n

    hipMemsetAsync(deg, 0, (size_t)Nn * 4, stream);

    int n4x = Nn * IN_DIM / 4;
    split_x_kernel<<<(n4x + 255) / 256, 256, 0, stream>>>(x, xh, xl, n4x);
    prep_w_geo_kernel<<<dim3((OUT_DIM * IN_DIM / 4 + 255) / 256, 4), 256, 0, stream>>>(
        Wq, Wk, Wv, wh_all, wl_all, Wg1, bg1, Wg2, bg2, geot);

    dim3 gq((Nn + 63) / 64, 3);
    qkv_mfma_kernel<<<gq, 256, 0, stream>>>(xh, xl, wh_all, wl_all, bq, bk, bv, q, kbuf, vbuf, Nn);

    deg_kernel<<<(Ee + 255) / 256, 256, 0, stream>>>(ei, deg, Ee);

    int nblk = (Nn + 1023) / 1024;   // <=256 for Nn<=262144
    scan_partial_kernel<<<nblk, 256, 0, stream>>>(deg, part, Nn);
    scan_block_kernel<<<1, 256, 0, stream>>>(part, nblk, rowstart, Nn);
    scan_write_kernel<<<nblk, 256, 0, stream>>>(deg, part, rowstart, cursor, Nn);

    scatter_kernel<<<(Ee + 255) / 256, 256, 0, stream>>>(ei, edist, cursor, cpack, Ee);

    fused_node_kernel<<<(Nn + 3) / 4, 256, 0, stream>>>(q, kbuf, vbuf, cpack, geot, rowstart, outacc, Nn);

    out_gemm_kernel<<<(Nn + 63) / 64, 256, 0, stream>>>(outacc, Wo, bo, out, Nn);
}

// Round 8
// 381.401 us; speedup vs baseline: 5.0235x; 1.0457x over previous
//
#include <hip/hip_runtime.h>
#include <math.h>

#define IN_DIM 256
#define OUT_DIM 128
#define NH 8
#define HD 16
#define GH 16
#define TBL 1024
#define LOG2E 1.44269504f

typedef __attribute__((ext_vector_type(8))) short short8;
typedef __attribute__((ext_vector_type(4))) float floatx4;

// ---------------- bf16 helpers (RNE) ----------------
__device__ __forceinline__ unsigned short f2bf(float f) {
    union { float f; unsigned u; } v; v.f = f;
    unsigned r = v.u + 0x7fffu + ((v.u >> 16) & 1u);
    return (unsigned short)(r >> 16);
}
__device__ __forceinline__ float bf2f(unsigned short h) {
    union { unsigned u; float f; } v; v.u = ((unsigned)h) << 16;
    return v.f;
}
__device__ __forceinline__ void split1(float f, unsigned short& h, unsigned short& l) {
    h = f2bf(f);
    l = f2bf(f - bf2f(h));
}
__device__ __forceinline__ float bflo(unsigned u) { return __uint_as_float(u << 16); }
__device__ __forceinline__ float bfhi(unsigned u) { return __uint_as_float(u & 0xffff0000u); }

__global__ void split_x_kernel(const float* __restrict__ in, unsigned short* __restrict__ hi,
                               unsigned short* __restrict__ lo, int n4) {
    int i = blockIdx.x * 256 + threadIdx.x;
    if (i >= n4) return;
    float4 f = ((const float4*)in)[i];
    ushort4 h, l;
    split1(f.x, h.x, l.x); split1(f.y, h.y, l.y);
    split1(f.z, h.z, l.z); split1(f.w, h.w, l.w);
    ((ushort4*)hi)[i] = h;
    ((ushort4*)lo)[i] = l;
}

// split Wq/Wk/Wv into bf16 hi/lo planes (y=0..2) and build the geo bias table (y=3).
// Table entries are pre-scaled by log2(e) so fused_node can use raw v_exp_f32 (2^x).
__global__ void prep_w_geo_kernel(const float* __restrict__ Wq, const float* __restrict__ Wk,
                                  const float* __restrict__ Wv,
                                  unsigned short* __restrict__ hi, unsigned short* __restrict__ lo,
                                  const float* __restrict__ Wg1, const float* __restrict__ bg1,
                                  const float* __restrict__ Wg2, const float* __restrict__ bg2,
                                  float* __restrict__ tbl) {
    int m = blockIdx.y;
    if (m < 3) {
        const float* W = (m == 0) ? Wq : (m == 1) ? Wk : Wv;
        int i = blockIdx.x * 256 + threadIdx.x;
        if (i >= (OUT_DIM * IN_DIM) / 4) return;
        float4 f = ((const float4*)W)[i];
        ushort4 h, l;
        split1(f.x, h.x, l.x); split1(f.y, h.y, l.y);
        split1(f.z, h.z, l.z); split1(f.w, h.w, l.w);
        size_t base = (size_t)m * (OUT_DIM * IN_DIM) / 4;
        ((ushort4*)hi)[base + i] = h;
        ((ushort4*)lo)[base + i] = l;
        return;
    }
    int i = blockIdx.x * 256 + threadIdx.x;
    if (i >= TBL) return;
    float d = (float)i * (6.0f / (float)(TBL - 1));
    float rbf[GH];
#pragma unroll
    for (int j = 0; j < GH; ++j) {
        float c = 0.4f * (float)j;
        float t = d - c;
        rbf[j] = __expf(-t * t);
    }
    float hid[GH];
#pragma unroll
    for (int j = 0; j < GH; ++j) {
        float acc = bg1[j];
#pragma unroll
        for (int kk = 0; kk < GH; ++kk) acc += rbf[kk] * Wg1[j * GH + kk];
        hid[j] = fmaxf(acc, 0.0f);
    }
#pragma unroll
    for (int h = 0; h < NH; ++h) {
        float acc = bg2[h];
#pragma unroll
        for (int j = 0; j < GH; ++j) acc += hid[j] * Wg2[h * GH + j];
        tbl[i * NH + h] = acc * LOG2E;   // log2-domain bias
    }
}

// ---------------- qkv via split-bf16 MFMA; q stored fp32, k/v stored bf16 ----------------
__global__ __launch_bounds__(256) void qkv_mfma_kernel(
    const unsigned short* __restrict__ xh, const unsigned short* __restrict__ xl,
    const unsigned short* __restrict__ wh, const unsigned short* __restrict__ wl,
    const float* __restrict__ bq, const float* __restrict__ bk, const float* __restrict__ bv,
    float* __restrict__ q, unsigned short* __restrict__ kb, unsigned short* __restrict__ vb,
    int Nn) {
    const int n0 = blockIdx.x * 64;
    const int wsel = blockIdx.y;
    const unsigned short* W_h = wh + (size_t)wsel * (OUT_DIM * IN_DIM);
    const unsigned short* W_l = wl + (size_t)wsel * (OUT_DIM * IN_DIM);
    const float* bias = (wsel == 0) ? bq : (wsel == 1) ? bk : bv;

    __shared__ unsigned short xh_s[64 * 40];
    __shared__ unsigned short xl_s[64 * 40];
    __shared__ unsigned short wh_s[128 * 40];
    __shared__ unsigned short wl_s[128 * 40];

    const int tid = threadIdx.x;
    const int w = tid >> 6;
    const int lane = tid & 63;
    const int ml = lane & 15;
    const int quad = lane >> 4;

    const int rows_valid = min(64, Nn - n0);

    floatx4 acc[8];
#pragma unroll
    for (int ct = 0; ct < 8; ++ct) acc[ct] = (floatx4){0.f, 0.f, 0.f, 0.f};

    const short8 zero8 = {0, 0, 0, 0, 0, 0, 0, 0};

    for (int kc = 0; kc < IN_DIM; kc += 32) {
        {
            int r = tid >> 2, c = tid & 3;
            short8 vh = zero8, vl = zero8;
            if (r < rows_valid) {
                size_t g = (size_t)(n0 + r) * IN_DIM + kc + c * 8;
                vh = *(const short8*)(xh + g);
                vl = *(const short8*)(xl + g);
            }
            *(short8*)(xh_s + r * 40 + c * 8) = vh;
            *(short8*)(xl_s + r * 40 + c * 8) = vl;
        }
#pragma unroll
        for (int l = 0; l < 2; ++l) {
            int idx = tid + l * 256;
            int r = idx >> 2, c = idx & 3;
            size_t g = (size_t)r * IN_DIM + kc + c * 8;
            *(short8*)(wh_s + r * 40 + c * 8) = *(const short8*)(W_h + g);
            *(short8*)(wl_s + r * 40 + c * 8) = *(const short8*)(W_l + g);
        }
        __syncthreads();

        short8 ah = *(const short8*)(xh_s + (w * 16 + ml) * 40 + quad * 8);
        short8 al = *(const short8*)(xl_s + (w * 16 + ml) * 40 + quad * 8);
#pragma unroll
        for (int ct = 0; ct < 8; ++ct) {
            short8 bh = *(const short8*)(wh_s + (ct * 16 + ml) * 40 + quad * 8);
            short8 bl = *(const short8*)(wl_s + (ct * 16 + ml) * 40 + quad * 8);
            acc[ct] = __builtin_amdgcn_mfma_f32_16x16x32_bf16(ah, bh, acc[ct], 0, 0, 0);
            acc[ct] = __builtin_amdgcn_mfma_f32_16x16x32_bf16(al, bh, acc[ct], 0, 0, 0);
            acc[ct] = __builtin_amdgcn_mfma_f32_16x16x32_bf16(ah, bl, acc[ct], 0, 0, 0);
        }
        __syncthreads();
    }

    if (wsel == 0) {
#pragma unroll
        for (int ct = 0; ct < 8; ++ct) {
            float bj = bias[ct * 16 + ml];
#pragma unroll
            for (int r = 0; r < 4; ++r) {
                int grow = n0 + w * 16 + quad * 4 + r;
                if (grow < Nn) q[(size_t)grow * 128 + ct * 16 + ml] = acc[ct][r] + bj;
            }
        }
    } else {
        unsigned short* ob = (wsel == 1) ? kb : vb;
#pragma unroll
        for (int ct = 0; ct < 8; ++ct) {
            float bj = bias[ct * 16 + ml];
#pragma unroll
            for (int r = 0; r < 4; ++r) {
                int grow = n0 + w * 16 + quad * 4 + r;
                if (grow < Nn) ob[(size_t)grow * 128 + ct * 16 + ml] = f2bf(acc[ct][r] + bj);
            }
        }
    }
}

// ---------------- fp32 register-tiled GEMM (final Wo GEMM) ----------------
template <int K>
static __device__ __forceinline__ void gemm_tile(const float* __restrict__ X,
                                                 const float* __restrict__ W,
                                                 const float* __restrict__ b,
                                                 float* __restrict__ out,
                                                 int n0, int Nn) {
    __shared__ float xs[64 * 32];
    __shared__ float wsm[128 * 32];
    const int tid = threadIdx.x;
    const int tx = tid & 15;
    const int ty = tid >> 4;
    float acc[4][8];
#pragma unroll
    for (int i = 0; i < 4; ++i)
#pragma unroll
        for (int j = 0; j < 8; ++j) acc[i][j] = 0.0f;

    const int rows_valid = min(64, Nn - n0);

    for (int kc = 0; kc < K; kc += 32) {
#pragma unroll
        for (int l = 0; l < 2; ++l) {
            int fl = tid + l * 256;
            int r = fl >> 3, c4 = fl & 7;
            float4 val = make_float4(0.f, 0.f, 0.f, 0.f);
            if (r < rows_valid) val = *(const float4*)(X + (size_t)(n0 + r) * K + kc + c4 * 4);
            int slot = c4 ^ ((r >> 3) & 7);
            *(float4*)(xs + r * 32 + slot * 4) = val;
        }
#pragma unroll
        for (int l = 0; l < 4; ++l) {
            int fl = tid + l * 256;
            int r = fl >> 3, c4 = fl & 7;
            float4 val = *(const float4*)(W + (size_t)r * K + kc + c4 * 4);
            int slot = c4 ^ ((r >> 3) & 7);
            *(float4*)(wsm + r * 32 + slot * 4) = val;
        }
        __syncthreads();
#pragma unroll
        for (int k4 = 0; k4 < 8; ++k4) {
            float4 xa[4], wb[8];
#pragma unroll
            for (int i = 0; i < 4; ++i) {
                int r = ty * 4 + i;
                int slot = k4 ^ ((r >> 3) & 7);
                xa[i] = *(const float4*)(xs + r * 32 + slot * 4);
            }
#pragma unroll
            for (int j = 0; j < 8; ++j) {
                int r = tx * 8 + j;
                int slot = k4 ^ ((r >> 3) & 7);
                wb[j] = *(const float4*)(wsm + r * 32 + slot * 4);
            }
#pragma unroll
            for (int i = 0; i < 4; ++i)
#pragma unroll
                for (int j = 0; j < 8; ++j) {
                    acc[i][j] += xa[i].x * wb[j].x;
                    acc[i][j] += xa[i].y * wb[j].y;
                    acc[i][j] += xa[i].z * wb[j].z;
                    acc[i][j] += xa[i].w * wb[j].w;
                }
        }
        __syncthreads();
    }

    float bj[8];
#pragma unroll
    for (int j = 0; j < 8; ++j) bj[j] = b[tx * 8 + j];
#pragma unroll
    for (int i = 0; i < 4; ++i) {
        int r = ty * 4 + i;
        if (r < rows_valid) {
            float4 o0 = make_float4(acc[i][0] + bj[0], acc[i][1] + bj[1],
                                    acc[i][2] + bj[2], acc[i][3] + bj[3]);
            float4 o1 = make_float4(acc[i][4] + bj[4], acc[i][5] + bj[5],
                                    acc[i][6] + bj[6], acc[i][7] + bj[7]);
            float* op = out + (size_t)(n0 + r) * 128 + tx * 8;
            *(float4*)op = o0;
            *(float4*)(op + 4) = o1;
        }
    }
}

__global__ __launch_bounds__(256) void out_gemm_kernel(const float* __restrict__ in,
                                                       const float* __restrict__ Wo, const float* __restrict__ bo,
                                                       float* __restrict__ out, int Nn) {
    gemm_tile<OUT_DIM>(in, Wo, bo, out, blockIdx.x * 64, Nn);
}

// ---------------- CSR build ----------------
__global__ void deg_kernel(const int* __restrict__ ei, int* __restrict__ deg, int E_) {
    int e = blockIdx.x * 256 + threadIdx.x;
    if (e < E_) atomicAdd(&deg[ei[e]], 1);
}

__global__ __launch_bounds__(256) void scan_partial_kernel(const int* __restrict__ deg,
                                                           int* __restrict__ part, int n) {
    __shared__ int sm[4];
    int t = threadIdx.x;
    int idx4 = blockIdx.x * 1024 + t * 4;
    int s = 0;
    if (idx4 + 3 < n) {
        int4 d = *(const int4*)(deg + idx4);
        s = d.x + d.y + d.z + d.w;
    } else {
#pragma unroll
        for (int j = 0; j < 4; ++j) if (idx4 + j < n) s += deg[idx4 + j];
    }
#pragma unroll
    for (int off = 1; off < 64; off <<= 1) s += __shfl_xor(s, off);
    if ((t & 63) == 0) sm[t >> 6] = s;
    __syncthreads();
    if (t == 0) part[blockIdx.x] = sm[0] + sm[1] + sm[2] + sm[3];
}

__global__ __launch_bounds__(256) void scan_block_kernel(int* __restrict__ part, int npart,
                                                         int* __restrict__ rowstart, int n) {
    __shared__ int sm[256];
    int t = threadIdx.x;
    int v = (t < npart) ? part[t] : 0;
    sm[t] = v;
    __syncthreads();
    for (int off = 1; off < 256; off <<= 1) {
        int o = (t >= off) ? sm[t - off] : 0;
        __syncthreads();
        sm[t] += o;
        __syncthreads();
    }
    if (t < npart) part[t] = sm[t] - v;
    if (t == 255) rowstart[n] = sm[255];
}

__global__ __launch_bounds__(256) void scan_write_kernel(const int* __restrict__ deg,
                                                         const int* __restrict__ part,
                                                         int* __restrict__ rowstart,
                                                         int* __restrict__ cursor, int n) {
    __shared__ int sm[256];
    int t = threadIdx.x;
    int idx4 = blockIdx.x * 1024 + t * 4;
    int d0 = 0, d1 = 0, d2 = 0, d3 = 0;
    if (idx4 + 3 < n) {
        int4 d = *(const int4*)(deg + idx4);
        d0 = d.x; d1 = d.y; d2 = d.z; d3 = d.w;
    } else {
        if (idx4 + 0 < n) d0 = deg[idx4 + 0];
        if (idx4 + 1 < n) d1 = deg[idx4 + 1];
        if (idx4 + 2 < n) d2 = deg[idx4 + 2];
        if (idx4 + 3 < n) d3 = deg[idx4 + 3];
    }
    int s = d0 + d1 + d2 + d3;
    sm[t] = s;
    __syncthreads();
    for (int off = 1; off < 256; off <<= 1) {
        int o = (t >= off) ? sm[t - off] : 0;
        __syncthreads();
        sm[t] += o;
        __syncthreads();
    }
    int run = part[blockIdx.x] + sm[t] - s;
    int4 rs;
    rs.x = run;
    rs.y = run + d0;
    rs.z = rs.y + d1;
    rs.w = rs.z + d2;
    if (idx4 + 3 < n) {
        *(int4*)(rowstart + idx4) = rs;
        *(int4*)(cursor + idx4) = rs;
    } else {
        int rv[4] = {rs.x, rs.y, rs.z, rs.w};
#pragma unroll
        for (int j = 0; j < 4; ++j)
            if (idx4 + j < n) { rowstart[idx4 + j] = rv[j]; cursor[idx4 + j] = rv[j]; }
    }
}

// ---------------- scatter: {col, table-coord u} packed int2 into CSR order ----------------
__global__ void scatter_kernel(const int* __restrict__ ei, const float* __restrict__ edist,
                               int* __restrict__ cursor, int2* __restrict__ cpack, int E_) {
    int e = blockIdx.x * 256 + threadIdx.x;
    if (e >= E_) return;
    int row = ei[e];
    int pos = atomicAdd(&cursor[row], 1);
    float u = edist[e] * ((float)(TBL - 1) / 6.0f);
    u = fminf(fmaxf(u, 0.0f), (float)(TBL - 1));
    cpack[pos] = make_int2(ei[E_ + e], __float_as_int(u));
}

// ---------------- fused flash-style edge+node pass, head-per-lane layout ----------------
// One wave per node. Lane L: edge base+(L>>3), head h=L&7, owning all 16 features
// of head h. The 16-dot is in-register (no shfl); lerp/softmax/exp run once per
// (edge,head) instead of 8x (R7's layout: 120 wave-inst/edge measured). 8 edges
// retired per wave-iteration; (m,l,acc) merged across the 8 edge-groups at the end.
__global__ __launch_bounds__(256) void fused_node_kernel(
    const float* __restrict__ q, const unsigned short* __restrict__ kb,
    const unsigned short* __restrict__ vb, const int2* __restrict__ cpack,
    const float* __restrict__ tbl, const int* __restrict__ rowstart,
    float* __restrict__ outacc, int Nn) {
    int lane = threadIdx.x & 63;
    int n = blockIdx.x * 4 + (threadIdx.x >> 6);
    if (n >= Nn) return;
    int g = lane >> 3;       // edge subgroup
    int h = lane & 7;        // head
    int start = rowstart[n];
    int end = rowstart[n + 1];

    // q fragment: 16 fp32 features of head h (wave-uniform row)
    float qf[16];
    {
        const float4* qp = (const float4*)(q + (size_t)n * 128 + h * 16);
#pragma unroll
        for (int j = 0; j < 4; ++j) {
            float4 t = qp[j];
            qf[j * 4 + 0] = t.x; qf[j * 4 + 1] = t.y;
            qf[j * 4 + 2] = t.z; qf[j * 4 + 3] = t.w;
        }
    }

    float m = -1e30f, l = 0.0f;
    float acc[16];
#pragma unroll
    for (int j = 0; j < 16; ++j) acc[j] = 0.0f;

    for (int base = start; base < end; base += 8) {
        int e = base + g;
        bool valid = (e < end);
        int ee = valid ? e : (end - 1);
        int2 np = cpack[ee];
        int col = np.x;

        const uint4* kp = (const uint4*)(kb + (size_t)col * 128 + h * 16);
        uint4 k0 = kp[0], k1 = kp[1];
        const uint4* vp = (const uint4*)(vb + (size_t)col * 128 + h * 16);
        uint4 v0 = vp[0], v1 = vp[1];

        unsigned kk[8] = {k0.x, k0.y, k0.z, k0.w, k1.x, k1.y, k1.z, k1.w};
        float d = 0.0f;
#pragma unroll
        for (int j = 0; j < 8; ++j) {
            d = fmaf(bflo(kk[j]), qf[2 * j], d);
            d = fmaf(bfhi(kk[j]), qf[2 * j + 1], d);
        }

        float u = __int_as_float(np.y);
        int i0 = min((int)u, TBL - 2);
        float fr = u - (float)i0;
        float t0 = tbl[i0 * NH + h];
        float t1 = tbl[i0 * NH + NH + h];
        float logit2 = fmaf(d, 0.25f * LOG2E, fmaf(fr, t1 - t0, t0));  // log2 domain
        if (!valid) logit2 = -1e30f;

        float nm = fmaxf(m, logit2);
        float resc = __builtin_amdgcn_exp2f(m - nm);
        float p = __builtin_amdgcn_exp2f(logit2 - nm);
        l = fmaf(l, resc, p);
        unsigned vv[8] = {v0.x, v0.y, v0.z, v0.w, v1.x, v1.y, v1.z, v1.w};
#pragma unroll
        for (int j = 0; j < 8; ++j) {
            acc[2 * j]     = fmaf(acc[2 * j],     resc, p * bflo(vv[j]));
            acc[2 * j + 1] = fmaf(acc[2 * j + 1], resc, p * bfhi(vv[j]));
        }
        m = nm;
    }

    // merge (m, l, acc) across the 8 edge-groups (lanes differing in bits 3..5)
#pragma unroll
    for (int off = 8; off < 64; off <<= 1) {
        float om = __shfl_xor(m, off);
        float ol = __shfl_xor(l, off);
        float nm = fmaxf(m, om);
        float r0 = __builtin_amdgcn_exp2f(m - nm);
        float r1 = __builtin_amdgcn_exp2f(om - nm);
        l = l * r0 + ol * r1;
#pragma unroll
        for (int j = 0; j < 16; ++j) {
            float oa = __shfl_xor(acc[j], off);
            acc[j] = acc[j] * r0 + oa * r1;
        }
        m = nm;
    }

    if (g == 0) {
        float inv = 1.0f / (l + 1e-12f);
        float4* op = (float4*)(outacc + (size_t)n * 128 + h * 16);
#pragma unroll
        for (int j = 0; j < 4; ++j)
            op[j] = make_float4(acc[j * 4 + 0] * inv, acc[j * 4 + 1] * inv,
                                acc[j * 4 + 2] * inv, acc[j * 4 + 3] * inv);
    }
}

extern "C" void kernel_launch(void* const* d_in, const int* in_sizes, int n_in,
                              void* d_out, int out_size, void* d_ws, size_t ws_size,
                              hipStream_t stream) {
    const float* x   = (const float*)d_in[0];
    const int* ei    = (const int*)d_in[1];
    const float* edist = (const float*)d_in[2];
    const float* Wq = (const float*)d_in[3];  const float* bq = (const float*)d_in[4];
    const float* Wk = (const float*)d_in[5];  const float* bk = (const float*)d_in[6];
    const float* Wv = (const float*)d_in[7];  const float* bv = (const float*)d_in[8];
    const float* Wo = (const float*)d_in[9];  const float* bo = (const float*)d_in[10];
    const float* Wg1 = (const float*)d_in[11]; const float* bg1 = (const float*)d_in[12];
    const float* Wg2 = (const float*)d_in[13]; const float* bg2 = (const float*)d_in[14];
    const int Nn = in_sizes[0] / IN_DIM;
    const int Ee = in_sizes[2];
    float* out = (float*)d_out;

    char* ws = (char*)d_ws;
    size_t off = 0;
    auto alloc = [&](size_t bytes) -> char* {
        char* p = ws + off;
        off += (bytes + 255) & ~(size_t)255;
        return p;
    };
    float* q  = (float*)alloc((size_t)Nn * 128 * 4);
    unsigned short* kbuf = (unsigned short*)alloc((size_t)Nn * 128 * 2);
    unsigned short* vbuf = (unsigned short*)alloc((size_t)Nn * 128 * 2);
    char* xlblock = alloc((size_t)Nn * IN_DIM * 2);
    float* geot = (float*)alloc((size_t)TBL * 8 * 4);
    int* deg      = (int*)alloc((size_t)Nn * 4);
    int* rowstart = (int*)alloc((size_t)(Nn + 1) * 4);
    int* cursor   = (int*)alloc((size_t)Nn * 4);
    int* part     = (int*)alloc((size_t)256 * 4);
    unsigned short* wh_all = (unsigned short*)alloc((size_t)3 * OUT_DIM * IN_DIM * 2);
    unsigned short* wl_all = (unsigned short*)alloc((size_t)3 * OUT_DIM * IN_DIM * 2);

    unsigned short* xh = (unsigned short*)d_out;       // rewritten by final GEMM
    unsigned short* xl = (unsigned short*)xlblock;
    int2* cpack = (int2*)xlblock;                       // live after qkv_mfma
    float* outacc = q;  // wave reads q-row n before writing out-row n

    hipMemsetAsync(deg, 0, (size_t)Nn * 4, stream);

    int n4x = Nn * IN_DIM / 4;
    split_x_kernel<<<(n4x + 255) / 256, 256, 0, stream>>>(x, xh, xl, n4x);
    prep_w_geo_kernel<<<dim3((OUT_DIM * IN_DIM / 4 + 255) / 256, 4), 256, 0, stream>>>(
        Wq, Wk, Wv, wh_all, wl_all, Wg1, bg1, Wg2, bg2, geot);

    dim3 gq((Nn + 63) / 64, 3);
    qkv_mfma_kernel<<<gq, 256, 0, stream>>>(xh, xl, wh_all, wl_all, bq, bk, bv, q, kbuf, vbuf, Nn);

    deg_kernel<<<(Ee + 255) / 256, 256, 0, stream>>>(ei, deg, Ee);

    int nblk = (Nn + 1023) / 1024;
    scan_partial_kernel<<<nblk, 256, 0, stream>>>(deg, part, Nn);
    scan_block_kernel<<<1, 256, 0, stream>>>(part, nblk, rowstart, Nn);
    scan_write_kernel<<<nblk, 256, 0, stream>>>(deg, part, rowstart, cursor, Nn);

    scatter_kernel<<<(Ee + 255) / 256, 256, 0, stream>>>(ei, edist, cursor, cpack, Ee);

    fused_node_kernel<<<(Nn + 3) / 4, 256, 0, stream>>>(q, kbuf, vbuf, cpack, geot, rowstart, outacc, Nn);

    out_gemm_kernel<<<(Nn + 63) / 64, 256, 0, stream>>>(outacc, Wo, bo, out, Nn);
}

// Round 9
// 364.187 us; speedup vs baseline: 5.2610x; 1.0473x over previous
//
#include <hip/hip_runtime.h>
#include <math.h>

#define IN_DIM 256
#define OUT_DIM 128
#define NH 8
#define HD 16
#define GH 16
#define TBL 1024
#define LOG2E 1.44269504f

typedef __attribute__((ext_vector_type(8))) short short8;
typedef __attribute__((ext_vector_type(4))) float floatx4;

// ---------------- bf16 helpers (RNE) ----------------
__device__ __forceinline__ unsigned short f2bf(float f) {
    union { float f; unsigned u; } v; v.f = f;
    unsigned r = v.u + 0x7fffu + ((v.u >> 16) & 1u);
    return (unsigned short)(r >> 16);
}
__device__ __forceinline__ float bf2f(unsigned short h) {
    union { unsigned u; float f; } v; v.u = ((unsigned)h) << 16;
    return v.f;
}
__device__ __forceinline__ void split1(float f, unsigned short& h, unsigned short& l) {
    h = f2bf(f);
    l = f2bf(f - bf2f(h));
}
__device__ __forceinline__ float bflo(unsigned u) { return __uint_as_float(u << 16); }
__device__ __forceinline__ float bfhi(unsigned u) { return __uint_as_float(u & 0xffff0000u); }

__global__ void split_x_kernel(const float* __restrict__ in, unsigned short* __restrict__ hi,
                               unsigned short* __restrict__ lo, int n4) {
    int i = blockIdx.x * 256 + threadIdx.x;
    if (i >= n4) return;
    float4 f = ((const float4*)in)[i];
    ushort4 h, l;
    split1(f.x, h.x, l.x); split1(f.y, h.y, l.y);
    split1(f.z, h.z, l.z); split1(f.w, h.w, l.w);
    ((ushort4*)hi)[i] = h;
    ((ushort4*)lo)[i] = l;
}

// y=0..2: split Wq/Wk/Wv into bf16 hi/lo; y=3: split Wo; y=4: geo bias table (log2-domain).
__global__ void prep_w_geo_kernel(const float* __restrict__ Wq, const float* __restrict__ Wk,
                                  const float* __restrict__ Wv, const float* __restrict__ Wo,
                                  unsigned short* __restrict__ hi, unsigned short* __restrict__ lo,
                                  unsigned short* __restrict__ wo_h, unsigned short* __restrict__ wo_l,
                                  const float* __restrict__ Wg1, const float* __restrict__ bg1,
                                  const float* __restrict__ Wg2, const float* __restrict__ bg2,
                                  float* __restrict__ tbl) {
    int m = blockIdx.y;
    int i = blockIdx.x * 256 + threadIdx.x;
    if (m < 3) {
        const float* W = (m == 0) ? Wq : (m == 1) ? Wk : Wv;
        if (i >= (OUT_DIM * IN_DIM) / 4) return;
        float4 f = ((const float4*)W)[i];
        ushort4 h, l;
        split1(f.x, h.x, l.x); split1(f.y, h.y, l.y);
        split1(f.z, h.z, l.z); split1(f.w, h.w, l.w);
        size_t base = (size_t)m * (OUT_DIM * IN_DIM) / 4;
        ((ushort4*)hi)[base + i] = h;
        ((ushort4*)lo)[base + i] = l;
        return;
    }
    if (m == 3) {
        if (i >= (OUT_DIM * OUT_DIM) / 4) return;
        float4 f = ((const float4*)Wo)[i];
        ushort4 h, l;
        split1(f.x, h.x, l.x); split1(f.y, h.y, l.y);
        split1(f.z, h.z, l.z); split1(f.w, h.w, l.w);
        ((ushort4*)wo_h)[i] = h;
        ((ushort4*)wo_l)[i] = l;
        return;
    }
    if (i >= TBL) return;
    float d = (float)i * (6.0f / (float)(TBL - 1));
    float rbf[GH];
#pragma unroll
    for (int j = 0; j < GH; ++j) {
        float c = 0.4f * (float)j;
        float t = d - c;
        rbf[j] = __expf(-t * t);
    }
    float hid[GH];
#pragma unroll
    for (int j = 0; j < GH; ++j) {
        float acc = bg1[j];
#pragma unroll
        for (int kk = 0; kk < GH; ++kk) acc += rbf[kk] * Wg1[j * GH + kk];
        hid[j] = fmaxf(acc, 0.0f);
    }
#pragma unroll
    for (int h = 0; h < NH; ++h) {
        float acc = bg2[h];
#pragma unroll
        for (int j = 0; j < GH; ++j) acc += hid[j] * Wg2[h * GH + j];
        tbl[i * NH + h] = acc * LOG2E;
    }
}

// ---------------- qkv via split-bf16 MFMA; q stored fp32, k/v stored bf16 ----------------
__global__ __launch_bounds__(256) void qkv_mfma_kernel(
    const unsigned short* __restrict__ xh, const unsigned short* __restrict__ xl,
    const unsigned short* __restrict__ wh, const unsigned short* __restrict__ wl,
    const float* __restrict__ bq, const float* __restrict__ bk, const float* __restrict__ bv,
    float* __restrict__ q, unsigned short* __restrict__ kb, unsigned short* __restrict__ vb,
    int Nn) {
    const int n0 = blockIdx.x * 64;
    const int wsel = blockIdx.y;
    const unsigned short* W_h = wh + (size_t)wsel * (OUT_DIM * IN_DIM);
    const unsigned short* W_l = wl + (size_t)wsel * (OUT_DIM * IN_DIM);
    const float* bias = (wsel == 0) ? bq : (wsel == 1) ? bk : bv;

    __shared__ unsigned short xh_s[64 * 40];
    __shared__ unsigned short xl_s[64 * 40];
    __shared__ unsigned short wh_s[128 * 40];
    __shared__ unsigned short wl_s[128 * 40];

    const int tid = threadIdx.x;
    const int w = tid >> 6;
    const int lane = tid & 63;
    const int ml = lane & 15;
    const int quad = lane >> 4;

    const int rows_valid = min(64, Nn - n0);

    floatx4 acc[8];
#pragma unroll
    for (int ct = 0; ct < 8; ++ct) acc[ct] = (floatx4){0.f, 0.f, 0.f, 0.f};

    const short8 zero8 = {0, 0, 0, 0, 0, 0, 0, 0};

    for (int kc = 0; kc < IN_DIM; kc += 32) {
        {
            int r = tid >> 2, c = tid & 3;
            short8 vh = zero8, vl = zero8;
            if (r < rows_valid) {
                size_t g = (size_t)(n0 + r) * IN_DIM + kc + c * 8;
                vh = *(const short8*)(xh + g);
                vl = *(const short8*)(xl + g);
            }
            *(short8*)(xh_s + r * 40 + c * 8) = vh;
            *(short8*)(xl_s + r * 40 + c * 8) = vl;
        }
#pragma unroll
        for (int l = 0; l < 2; ++l) {
            int idx = tid + l * 256;
            int r = idx >> 2, c = idx & 3;
            size_t g = (size_t)r * IN_DIM + kc + c * 8;
            *(short8*)(wh_s + r * 40 + c * 8) = *(const short8*)(W_h + g);
            *(short8*)(wl_s + r * 40 + c * 8) = *(const short8*)(W_l + g);
        }
        __syncthreads();

        short8 ah = *(const short8*)(xh_s + (w * 16 + ml) * 40 + quad * 8);
        short8 al = *(const short8*)(xl_s + (w * 16 + ml) * 40 + quad * 8);
#pragma unroll
        for (int ct = 0; ct < 8; ++ct) {
            short8 bh = *(const short8*)(wh_s + (ct * 16 + ml) * 40 + quad * 8);
            short8 bl = *(const short8*)(wl_s + (ct * 16 + ml) * 40 + quad * 8);
            acc[ct] = __builtin_amdgcn_mfma_f32_16x16x32_bf16(ah, bh, acc[ct], 0, 0, 0);
            acc[ct] = __builtin_amdgcn_mfma_f32_16x16x32_bf16(al, bh, acc[ct], 0, 0, 0);
            acc[ct] = __builtin_amdgcn_mfma_f32_16x16x32_bf16(ah, bl, acc[ct], 0, 0, 0);
        }
        __syncthreads();
    }

    if (wsel == 0) {
#pragma unroll
        for (int ct = 0; ct < 8; ++ct) {
            float bj = bias[ct * 16 + ml];
#pragma unroll
            for (int r = 0; r < 4; ++r) {
                int grow = n0 + w * 16 + quad * 4 + r;
                if (grow < Nn) q[(size_t)grow * 128 + ct * 16 + ml] = acc[ct][r] + bj;
            }
        }
    } else {
        unsigned short* ob = (wsel == 1) ? kb : vb;
#pragma unroll
        for (int ct = 0; ct < 8; ++ct) {
            float bj = bias[ct * 16 + ml];
#pragma unroll
            for (int r = 0; r < 4; ++r) {
                int grow = n0 + w * 16 + quad * 4 + r;
                if (grow < Nn) ob[(size_t)grow * 128 + ct * 16 + ml] = f2bf(acc[ct][r] + bj);
            }
        }
    }
}

// ---------------- out GEMM via split-bf16 MFMA (K=128): out = o @ Wo^T + bo ----------------
__global__ __launch_bounds__(256) void out_gemm_mfma_kernel(
    const unsigned short* __restrict__ oh, const unsigned short* __restrict__ ol,
    const unsigned short* __restrict__ wo_h, const unsigned short* __restrict__ wo_l,
    const float* __restrict__ bo, float* __restrict__ out, int Nn) {
    const int n0 = blockIdx.x * 64;

    __shared__ unsigned short xh_s[64 * 40];
    __shared__ unsigned short xl_s[64 * 40];
    __shared__ unsigned short wh_s[128 * 40];
    __shared__ unsigned short wl_s[128 * 40];

    const int tid = threadIdx.x;
    const int w = tid >> 6;
    const int lane = tid & 63;
    const int ml = lane & 15;
    const int quad = lane >> 4;

    const int rows_valid = min(64, Nn - n0);

    floatx4 acc[8];
#pragma unroll
    for (int ct = 0; ct < 8; ++ct) acc[ct] = (floatx4){0.f, 0.f, 0.f, 0.f};

    const short8 zero8 = {0, 0, 0, 0, 0, 0, 0, 0};

    for (int kc = 0; kc < OUT_DIM; kc += 32) {
        {
            int r = tid >> 2, c = tid & 3;
            short8 vh = zero8, vl = zero8;
            if (r < rows_valid) {
                size_t g = (size_t)(n0 + r) * OUT_DIM + kc + c * 8;
                vh = *(const short8*)(oh + g);
                vl = *(const short8*)(ol + g);
            }
            *(short8*)(xh_s + r * 40 + c * 8) = vh;
            *(short8*)(xl_s + r * 40 + c * 8) = vl;
        }
#pragma unroll
        for (int l = 0; l < 2; ++l) {
            int idx = tid + l * 256;
            int r = idx >> 2, c = idx & 3;
            size_t g = (size_t)r * OUT_DIM + kc + c * 8;
            *(short8*)(wh_s + r * 40 + c * 8) = *(const short8*)(wo_h + g);
            *(short8*)(wl_s + r * 40 + c * 8) = *(const short8*)(wo_l + g);
        }
        __syncthreads();

        short8 ah = *(const short8*)(xh_s + (w * 16 + ml) * 40 + quad * 8);
        short8 al = *(const short8*)(xl_s + (w * 16 + ml) * 40 + quad * 8);
#pragma unroll
        for (int ct = 0; ct < 8; ++ct) {
            short8 bh = *(const short8*)(wh_s + (ct * 16 + ml) * 40 + quad * 8);
            short8 bl = *(const short8*)(wl_s + (ct * 16 + ml) * 40 + quad * 8);
            acc[ct] = __builtin_amdgcn_mfma_f32_16x16x32_bf16(ah, bh, acc[ct], 0, 0, 0);
            acc[ct] = __builtin_amdgcn_mfma_f32_16x16x32_bf16(al, bh, acc[ct], 0, 0, 0);
            acc[ct] = __builtin_amdgcn_mfma_f32_16x16x32_bf16(ah, bl, acc[ct], 0, 0, 0);
        }
        __syncthreads();
    }

#pragma unroll
    for (int ct = 0; ct < 8; ++ct) {
        float bj = bo[ct * 16 + ml];
#pragma unroll
        for (int r = 0; r < 4; ++r) {
            int grow = n0 + w * 16 + quad * 4 + r;
            if (grow < Nn) out[(size_t)grow * 128 + ct * 16 + ml] = acc[ct][r] + bj;
        }
    }
}

// ---------------- CSR build ----------------
__global__ void deg_kernel(const int* __restrict__ ei, int* __restrict__ deg, int E_) {
    int e = blockIdx.x * 256 + threadIdx.x;
    if (e < E_) atomicAdd(&deg[ei[e]], 1);
}

__global__ __launch_bounds__(256) void scan_partial_kernel(const int* __restrict__ deg,
                                                           int* __restrict__ part, int n) {
    __shared__ int sm[4];
    int t = threadIdx.x;
    int idx4 = blockIdx.x * 1024 + t * 4;
    int s = 0;
    if (idx4 + 3 < n) {
        int4 d = *(const int4*)(deg + idx4);
        s = d.x + d.y + d.z + d.w;
    } else {
#pragma unroll
        for (int j = 0; j < 4; ++j) if (idx4 + j < n) s += deg[idx4 + j];
    }
#pragma unroll
    for (int off = 1; off < 64; off <<= 1) s += __shfl_xor(s, off);
    if ((t & 63) == 0) sm[t >> 6] = s;
    __syncthreads();
    if (t == 0) part[blockIdx.x] = sm[0] + sm[1] + sm[2] + sm[3];
}

__global__ __launch_bounds__(256) void scan_block_kernel(int* __restrict__ part, int npart,
                                                         int* __restrict__ rowstart, int n) {
    __shared__ int sm[256];
    int t = threadIdx.x;
    int v = (t < npart) ? part[t] : 0;
    sm[t] = v;
    __syncthreads();
    for (int off = 1; off < 256; off <<= 1) {
        int o = (t >= off) ? sm[t - off] : 0;
        __syncthreads();
        sm[t] += o;
        __syncthreads();
    }
    if (t < npart) part[t] = sm[t] - v;
    if (t == 255) rowstart[n] = sm[255];
}

__global__ __launch_bounds__(256) void scan_write_kernel(const int* __restrict__ deg,
                                                         const int* __restrict__ part,
                                                         int* __restrict__ rowstart,
                                                         int* __restrict__ cursor, int n) {
    __shared__ int sm[256];
    int t = threadIdx.x;
    int idx4 = blockIdx.x * 1024 + t * 4;
    int d0 = 0, d1 = 0, d2 = 0, d3 = 0;
    if (idx4 + 3 < n) {
        int4 d = *(const int4*)(deg + idx4);
        d0 = d.x; d1 = d.y; d2 = d.z; d3 = d.w;
    } else {
        if (idx4 + 0 < n) d0 = deg[idx4 + 0];
        if (idx4 + 1 < n) d1 = deg[idx4 + 1];
        if (idx4 + 2 < n) d2 = deg[idx4 + 2];
        if (idx4 + 3 < n) d3 = deg[idx4 + 3];
    }
    int s = d0 + d1 + d2 + d3;
    sm[t] = s;
    __syncthreads();
    for (int off = 1; off < 256; off <<= 1) {
        int o = (t >= off) ? sm[t - off] : 0;
        __syncthreads();
        sm[t] += o;
        __syncthreads();
    }
    int run = part[blockIdx.x] + sm[t] - s;
    int4 rs;
    rs.x = run;
    rs.y = run + d0;
    rs.z = rs.y + d1;
    rs.w = rs.z + d2;
    if (idx4 + 3 < n) {
        *(int4*)(rowstart + idx4) = rs;
        *(int4*)(cursor + idx4) = rs;
    } else {
        int rv[4] = {rs.x, rs.y, rs.z, rs.w};
#pragma unroll
        for (int j = 0; j < 4; ++j)
            if (idx4 + j < n) { rowstart[idx4 + j] = rv[j]; cursor[idx4 + j] = rv[j]; }
    }
}

// ---------------- scatter: {col, table-coord u} packed int2 into CSR order ----------------
__global__ void scatter_kernel(const int* __restrict__ ei, const float* __restrict__ edist,
                               int* __restrict__ cursor, int2* __restrict__ cpack, int E_) {
    int e = blockIdx.x * 256 + threadIdx.x;
    if (e >= E_) return;
    int row = ei[e];
    int pos = atomicAdd(&cursor[row], 1);
    float u = edist[e] * ((float)(TBL - 1) / 6.0f);
    u = fminf(fmaxf(u, 0.0f), (float)(TBL - 1));
    cpack[pos] = make_int2(ei[E_ + e], __float_as_int(u));
}

// ---------------- fused flash-style edge+node pass, head-per-lane layout ----------------
// One wave per node. Lane L: edge base+(L>>3), head h=L&7. cpack entries for up to
// 64 edges are preloaded with ONE coalesced lane-strided load and broadcast per
// iteration via shfl -- removes the scattered cpack load (VMEM ~900cyc) from the
// col->k/v dependency chain (R8: latency-bound at 52% VALU / 43% HBM).
// Output written as bf16 hi/lo planes to feed the MFMA out-GEMM.
__global__ __launch_bounds__(256) void fused_node_kernel(
    const float* __restrict__ q, const unsigned short* __restrict__ kb,
    const unsigned short* __restrict__ vb, const int2* __restrict__ cpack,
    const float* __restrict__ tbl, const int* __restrict__ rowstart,
    unsigned short* __restrict__ oh, unsigned short* __restrict__ ol, int Nn) {
    int lane = threadIdx.x & 63;
    int n = blockIdx.x * 4 + (threadIdx.x >> 6);
    if (n >= Nn) return;
    int g = lane >> 3;       // edge subgroup
    int h = lane & 7;        // head
    int start = rowstart[n];
    int end = rowstart[n + 1];

    float qf[16];
    {
        const float4* qp = (const float4*)(q + (size_t)n * 128 + h * 16);
#pragma unroll
        for (int j = 0; j < 4; ++j) {
            float4 t = qp[j];
            qf[j * 4 + 0] = t.x; qf[j * 4 + 1] = t.y;
            qf[j * 4 + 2] = t.z; qf[j * 4 + 3] = t.w;
        }
    }

    float m = -1e30f, l = 0.0f;
    float acc[16];
#pragma unroll
    for (int j = 0; j < 16; ++j) acc[j] = 0.0f;

    for (int c0 = start; c0 < end; c0 += 64) {
        int2 myp = make_int2(0, 0);
        if (c0 + lane < end) myp = cpack[c0 + lane];
        int cnt = min(64, end - c0);

#pragma unroll 2
        for (int t8 = 0; t8 < cnt; t8 += 8) {
            int src = t8 + g;
            bool valid = (src < cnt);
            int col = __shfl(myp.x, src);
            float u = __int_as_float(__shfl(myp.y, src));
            if (!valid) col = 0;

            const uint4* kp = (const uint4*)(kb + (size_t)col * 128 + h * 16);
            uint4 k0 = kp[0], k1 = kp[1];
            const uint4* vp = (const uint4*)(vb + (size_t)col * 128 + h * 16);
            uint4 v0 = vp[0], v1 = vp[1];

            unsigned kk[8] = {k0.x, k0.y, k0.z, k0.w, k1.x, k1.y, k1.z, k1.w};
            float d = 0.0f;
#pragma unroll
            for (int j = 0; j < 8; ++j) {
                d = fmaf(bflo(kk[j]), qf[2 * j], d);
                d = fmaf(bfhi(kk[j]), qf[2 * j + 1], d);
            }

            int i0 = min((int)u, TBL - 2);
            float fr = u - (float)i0;
            float t0 = tbl[i0 * NH + h];
            float t1 = tbl[i0 * NH + NH + h];
            float logit2 = fmaf(d, 0.25f * LOG2E, fmaf(fr, t1 - t0, t0));
            if (!valid) logit2 = -1e30f;

            float nm = fmaxf(m, logit2);
            float resc = __builtin_amdgcn_exp2f(m - nm);
            float p = __builtin_amdgcn_exp2f(logit2 - nm);
            l = fmaf(l, resc, p);
            unsigned vv[8] = {v0.x, v0.y, v0.z, v0.w, v1.x, v1.y, v1.z, v1.w};
#pragma unroll
            for (int j = 0; j < 8; ++j) {
                acc[2 * j]     = fmaf(acc[2 * j],     resc, p * bflo(vv[j]));
                acc[2 * j + 1] = fmaf(acc[2 * j + 1], resc, p * bfhi(vv[j]));
            }
            m = nm;
        }
    }

    // merge (m, l, acc) across the 8 edge-groups
#pragma unroll
    for (int off = 8; off < 64; off <<= 1) {
        float om = __shfl_xor(m, off);
        float ol_ = __shfl_xor(l, off);
        float nm = fmaxf(m, om);
        float r0 = __builtin_amdgcn_exp2f(m - nm);
        float r1 = __builtin_amdgcn_exp2f(om - nm);
        l = l * r0 + ol_ * r1;
#pragma unroll
        for (int j = 0; j < 16; ++j) {
            float oa = __shfl_xor(acc[j], off);
            acc[j] = acc[j] * r0 + oa * r1;
        }
        m = nm;
    }

    if (g == 0) {
        float inv = 1.0f / (l + 1e-12f);
        ushort8_t: ;
        unsigned short hv[16], lv[16];
#pragma unroll
        for (int j = 0; j < 16; ++j) {
            float o = acc[j] * inv;
            split1(o, hv[j], lv[j]);
        }
        *(short8*)(oh + (size_t)n * 128 + h * 16) = *(short8*)hv;
        *(short8*)(oh + (size_t)n * 128 + h * 16 + 8) = *(short8*)(hv + 8);
        *(short8*)(ol + (size_t)n * 128 + h * 16) = *(short8*)lv;
        *(short8*)(ol + (size_t)n * 128 + h * 16 + 8) = *(short8*)(lv + 8);
    }
}

extern "C" void kernel_launch(void* const* d_in, const int* in_sizes, int n_in,
                              void* d_out, int out_size, void* d_ws, size_t ws_size,
                              hipStream_t stream) {
    const float* x   = (const float*)d_in[0];
    const int* ei    = (const int*)d_in[1];
    const float* edist = (const float*)d_in[2];
    const float* Wq = (const float*)d_in[3];  const float* bq = (const float*)d_in[4];
    const float* Wk = (const float*)d_in[5];  const float* bk = (const float*)d_in[6];
    const float* Wv = (const float*)d_in[7];  const float* bv = (const float*)d_in[8];
    const float* Wo = (const float*)d_in[9];  const float* bo = (const float*)d_in[10];
    const float* Wg1 = (const float*)d_in[11]; const float* bg1 = (const float*)d_in[12];
    const float* Wg2 = (const float*)d_in[13]; const float* bg2 = (const float*)d_in[14];
    const int Nn = in_sizes[0] / IN_DIM;
    const int Ee = in_sizes[2];
    float* out = (float*)d_out;

    char* ws = (char*)d_ws;
    size_t off = 0;
    auto alloc = [&](size_t bytes) -> char* {
        char* p = ws + off;
        off += (bytes + 255) & ~(size_t)255;
        return p;
    };
    float* q  = (float*)alloc((size_t)Nn * 128 * 4);
    unsigned short* kbuf = (unsigned short*)alloc((size_t)Nn * 128 * 2);
    unsigned short* vbuf = (unsigned short*)alloc((size_t)Nn * 128 * 2);
    char* xlblock = alloc((size_t)Nn * IN_DIM * 2);
    unsigned short* o_hi = (unsigned short*)alloc((size_t)Nn * 128 * 2);
    unsigned short* o_lo = (unsigned short*)alloc((size_t)Nn * 128 * 2);
    float* geot = (float*)alloc((size_t)TBL * 8 * 4);
    int* deg      = (int*)alloc((size_t)Nn * 4);
    int* rowstart = (int*)alloc((size_t)(Nn + 1) * 4);
    int* cursor   = (int*)alloc((size_t)Nn * 4);
    int* part     = (int*)alloc((size_t)256 * 4);
    unsigned short* wh_all = (unsigned short*)alloc((size_t)3 * OUT_DIM * IN_DIM * 2);
    unsigned short* wl_all = (unsigned short*)alloc((size_t)3 * OUT_DIM * IN_DIM * 2);
    unsigned short* wo_h = (unsigned short*)alloc((size_t)OUT_DIM * OUT_DIM * 2);
    unsigned short* wo_l = (unsigned short*)alloc((size_t)OUT_DIM * OUT_DIM * 2);

    unsigned short* xh = (unsigned short*)d_out;       // rewritten by final GEMM
    unsigned short* xl = (unsigned short*)xlblock;
    int2* cpack = (int2*)xlblock;                       // live after qkv_mfma

    hipMemsetAsync(deg, 0, (size_t)Nn * 4, stream);

    int n4x = Nn * IN_DIM / 4;
    split_x_kernel<<<(n4x + 255) / 256, 256, 0, stream>>>(x, xh, xl, n4x);
    prep_w_geo_kernel<<<dim3((OUT_DIM * IN_DIM / 4 + 255) / 256, 5), 256, 0, stream>>>(
        Wq, Wk, Wv, Wo, wh_all, wl_all, wo_h, wo_l, Wg1, bg1, Wg2, bg2, geot);

    dim3 gq((Nn + 63) / 64, 3);
    qkv_mfma_kernel<<<gq, 256, 0, stream>>>(xh, xl, wh_all, wl_all, bq, bk, bv, q, kbuf, vbuf, Nn);

    deg_kernel<<<(Ee + 255) / 256, 256, 0, stream>>>(ei, deg, Ee);

    int nblk = (Nn + 1023) / 1024;
    scan_partial_kernel<<<nblk, 256, 0, stream>>>(deg, part, Nn);
    scan_block_kernel<<<1, 256, 0, stream>>>(part, nblk, rowstart, Nn);
    scan_write_kernel<<<nblk, 256, 0, stream>>>(deg, part, rowstart, cursor, Nn);

    scatter_kernel<<<(Ee + 255) / 256, 256, 0, stream>>>(ei, edist, cursor, cpack, Ee);

    fused_node_kernel<<<(Nn + 3) / 4, 256, 0, stream>>>(q, kbuf, vbuf, cpack, geot, rowstart, o_hi, o_lo, Nn);

    out_gemm_mfma_kernel<<<(Nn + 63) / 64, 256, 0, stream>>>(o_hi, o_lo, wo_h, wo_l, bo, out, Nn);
}

// Round 10
// 363.558 us; speedup vs baseline: 5.2701x; 1.0017x over previous
//
#include <hip/hip_runtime.h>
#include <math.h>

#define IN_DIM 256
#define OUT_DIM 128
#define NH 8
#define HD 16
#define GH 16
#define TBL 1024
#define LOG2E 1.44269504f

typedef __attribute__((ext_vector_type(8))) short short8;
typedef __attribute__((ext_vector_type(4))) float floatx4;

// ---------------- bf16 helpers (RNE) ----------------
__device__ __forceinline__ unsigned short f2bf(float f) {
    union { float f; unsigned u; } v; v.f = f;
    unsigned r = v.u + 0x7fffu + ((v.u >> 16) & 1u);
    return (unsigned short)(r >> 16);
}
__device__ __forceinline__ float bf2f(unsigned short h) {
    union { unsigned u; float f; } v; v.u = ((unsigned)h) << 16;
    return v.f;
}
__device__ __forceinline__ void split1(float f, unsigned short& h, unsigned short& l) {
    h = f2bf(f);
    l = f2bf(f - bf2f(h));
}
__device__ __forceinline__ float bflo(unsigned u) { return __uint_as_float(u << 16); }
__device__ __forceinline__ float bfhi(unsigned u) { return __uint_as_float(u & 0xffff0000u); }

__global__ void split_x_kernel(const float* __restrict__ in, unsigned short* __restrict__ hi,
                               unsigned short* __restrict__ lo, int n4) {
    int i = blockIdx.x * 256 + threadIdx.x;
    if (i >= n4) return;
    float4 f = ((const float4*)in)[i];
    ushort4 h, l;
    split1(f.x, h.x, l.x); split1(f.y, h.y, l.y);
    split1(f.z, h.z, l.z); split1(f.w, h.w, l.w);
    ((ushort4*)hi)[i] = h;
    ((ushort4*)lo)[i] = l;
}

// y=0..2: split Wq/Wk/Wv into bf16 hi/lo; y=3: split Wo; y=4: geo bias table (log2-domain).
__global__ void prep_w_geo_kernel(const float* __restrict__ Wq, const float* __restrict__ Wk,
                                  const float* __restrict__ Wv, const float* __restrict__ Wo,
                                  unsigned short* __restrict__ hi, unsigned short* __restrict__ lo,
                                  unsigned short* __restrict__ wo_h, unsigned short* __restrict__ wo_l,
                                  const float* __restrict__ Wg1, const float* __restrict__ bg1,
                                  const float* __restrict__ Wg2, const float* __restrict__ bg2,
                                  float* __restrict__ tbl) {
    int m = blockIdx.y;
    int i = blockIdx.x * 256 + threadIdx.x;
    if (m < 3) {
        const float* W = (m == 0) ? Wq : (m == 1) ? Wk : Wv;
        if (i >= (OUT_DIM * IN_DIM) / 4) return;
        float4 f = ((const float4*)W)[i];
        ushort4 h, l;
        split1(f.x, h.x, l.x); split1(f.y, h.y, l.y);
        split1(f.z, h.z, l.z); split1(f.w, h.w, l.w);
        size_t base = (size_t)m * (OUT_DIM * IN_DIM) / 4;
        ((ushort4*)hi)[base + i] = h;
        ((ushort4*)lo)[base + i] = l;
        return;
    }
    if (m == 3) {
        if (i >= (OUT_DIM * OUT_DIM) / 4) return;
        float4 f = ((const float4*)Wo)[i];
        ushort4 h, l;
        split1(f.x, h.x, l.x); split1(f.y, h.y, l.y);
        split1(f.z, h.z, l.z); split1(f.w, h.w, l.w);
        ((ushort4*)wo_h)[i] = h;
        ((ushort4*)wo_l)[i] = l;
        return;
    }
    if (i >= TBL) return;
    float d = (float)i * (6.0f / (float)(TBL - 1));
    float rbf[GH];
#pragma unroll
    for (int j = 0; j < GH; ++j) {
        float c = 0.4f * (float)j;
        float t = d - c;
        rbf[j] = __expf(-t * t);
    }
    float hid[GH];
#pragma unroll
    for (int j = 0; j < GH; ++j) {
        float acc = bg1[j];
#pragma unroll
        for (int kk = 0; kk < GH; ++kk) acc += rbf[kk] * Wg1[j * GH + kk];
        hid[j] = fmaxf(acc, 0.0f);
    }
#pragma unroll
    for (int h = 0; h < NH; ++h) {
        float acc = bg2[h];
#pragma unroll
        for (int j = 0; j < GH; ++j) acc += hid[j] * Wg2[h * GH + j];
        tbl[i * NH + h] = acc * LOG2E;
    }
}

// ---------------- qkv via split-bf16 MFMA; q stored fp32, k/v stored bf16 ----------------
__global__ __launch_bounds__(256) void qkv_mfma_kernel(
    const unsigned short* __restrict__ xh, const unsigned short* __restrict__ xl,
    const unsigned short* __restrict__ wh, const unsigned short* __restrict__ wl,
    const float* __restrict__ bq, const float* __restrict__ bk, const float* __restrict__ bv,
    float* __restrict__ q, unsigned short* __restrict__ kb, unsigned short* __restrict__ vb,
    int Nn) {
    const int n0 = blockIdx.x * 64;
    const int wsel = blockIdx.y;
    const unsigned short* W_h = wh + (size_t)wsel * (OUT_DIM * IN_DIM);
    const unsigned short* W_l = wl + (size_t)wsel * (OUT_DIM * IN_DIM);
    const float* bias = (wsel == 0) ? bq : (wsel == 1) ? bk : bv;

    __shared__ unsigned short xh_s[64 * 40];
    __shared__ unsigned short xl_s[64 * 40];
    __shared__ unsigned short wh_s[128 * 40];
    __shared__ unsigned short wl_s[128 * 40];

    const int tid = threadIdx.x;
    const int w = tid >> 6;
    const int lane = tid & 63;
    const int ml = lane & 15;
    const int quad = lane >> 4;

    const int rows_valid = min(64, Nn - n0);

    floatx4 acc[8];
#pragma unroll
    for (int ct = 0; ct < 8; ++ct) acc[ct] = (floatx4){0.f, 0.f, 0.f, 0.f};

    const short8 zero8 = {0, 0, 0, 0, 0, 0, 0, 0};

    for (int kc = 0; kc < IN_DIM; kc += 32) {
        {
            int r = tid >> 2, c = tid & 3;
            short8 vh = zero8, vl = zero8;
            if (r < rows_valid) {
                size_t g = (size_t)(n0 + r) * IN_DIM + kc + c * 8;
                vh = *(const short8*)(xh + g);
                vl = *(const short8*)(xl + g);
            }
            *(short8*)(xh_s + r * 40 + c * 8) = vh;
            *(short8*)(xl_s + r * 40 + c * 8) = vl;
        }
#pragma unroll
        for (int l = 0; l < 2; ++l) {
            int idx = tid + l * 256;
            int r = idx >> 2, c = idx & 3;
            size_t g = (size_t)r * IN_DIM + kc + c * 8;
            *(short8*)(wh_s + r * 40 + c * 8) = *(const short8*)(W_h + g);
            *(short8*)(wl_s + r * 40 + c * 8) = *(const short8*)(W_l + g);
        }
        __syncthreads();

        short8 ah = *(const short8*)(xh_s + (w * 16 + ml) * 40 + quad * 8);
        short8 al = *(const short8*)(xl_s + (w * 16 + ml) * 40 + quad * 8);
#pragma unroll
        for (int ct = 0; ct < 8; ++ct) {
            short8 bh = *(const short8*)(wh_s + (ct * 16 + ml) * 40 + quad * 8);
            short8 bl = *(const short8*)(wl_s + (ct * 16 + ml) * 40 + quad * 8);
            acc[ct] = __builtin_amdgcn_mfma_f32_16x16x32_bf16(ah, bh, acc[ct], 0, 0, 0);
            acc[ct] = __builtin_amdgcn_mfma_f32_16x16x32_bf16(al, bh, acc[ct], 0, 0, 0);
            acc[ct] = __builtin_amdgcn_mfma_f32_16x16x32_bf16(ah, bl, acc[ct], 0, 0, 0);
        }
        __syncthreads();
    }

    if (wsel == 0) {
#pragma unroll
        for (int ct = 0; ct < 8; ++ct) {
            float bj = bias[ct * 16 + ml];
#pragma unroll
            for (int r = 0; r < 4; ++r) {
                int grow = n0 + w * 16 + quad * 4 + r;
                if (grow < Nn) q[(size_t)grow * 128 + ct * 16 + ml] = acc[ct][r] + bj;
            }
        }
    } else {
        unsigned short* ob = (wsel == 1) ? kb : vb;
#pragma unroll
        for (int ct = 0; ct < 8; ++ct) {
            float bj = bias[ct * 16 + ml];
#pragma unroll
            for (int r = 0; r < 4; ++r) {
                int grow = n0 + w * 16 + quad * 4 + r;
                if (grow < Nn) ob[(size_t)grow * 128 + ct * 16 + ml] = f2bf(acc[ct][r] + bj);
            }
        }
    }
}

// ---------------- out GEMM via split-bf16 MFMA (K=128): out = o @ Wo^T + bo ----------------
__global__ __launch_bounds__(256) void out_gemm_mfma_kernel(
    const unsigned short* __restrict__ oh, const unsigned short* __restrict__ ol,
    const unsigned short* __restrict__ wo_h, const unsigned short* __restrict__ wo_l,
    const float* __restrict__ bo, float* __restrict__ out, int Nn) {
    const int n0 = blockIdx.x * 64;

    __shared__ unsigned short xh_s[64 * 40];
    __shared__ unsigned short xl_s[64 * 40];
    __shared__ unsigned short wh_s[128 * 40];
    __shared__ unsigned short wl_s[128 * 40];

    const int tid = threadIdx.x;
    const int w = tid >> 6;
    const int lane = tid & 63;
    const int ml = lane & 15;
    const int quad = lane >> 4;

    const int rows_valid = min(64, Nn - n0);

    floatx4 acc[8];
#pragma unroll
    for (int ct = 0; ct < 8; ++ct) acc[ct] = (floatx4){0.f, 0.f, 0.f, 0.f};

    const short8 zero8 = {0, 0, 0, 0, 0, 0, 0, 0};

    for (int kc = 0; kc < OUT_DIM; kc += 32) {
        {
            int r = tid >> 2, c = tid & 3;
            short8 vh = zero8, vl = zero8;
            if (r < rows_valid) {
                size_t g = (size_t)(n0 + r) * OUT_DIM + kc + c * 8;
                vh = *(const short8*)(oh + g);
                vl = *(const short8*)(ol + g);
            }
            *(short8*)(xh_s + r * 40 + c * 8) = vh;
            *(short8*)(xl_s + r * 40 + c * 8) = vl;
        }
#pragma unroll
        for (int l = 0; l < 2; ++l) {
            int idx = tid + l * 256;
            int r = idx >> 2, c = idx & 3;
            size_t g = (size_t)r * OUT_DIM + kc + c * 8;
            *(short8*)(wh_s + r * 40 + c * 8) = *(const short8*)(wo_h + g);
            *(short8*)(wl_s + r * 40 + c * 8) = *(const short8*)(wo_l + g);
        }
        __syncthreads();

        short8 ah = *(const short8*)(xh_s + (w * 16 + ml) * 40 + quad * 8);
        short8 al = *(const short8*)(xl_s + (w * 16 + ml) * 40 + quad * 8);
#pragma unroll
        for (int ct = 0; ct < 8; ++ct) {
            short8 bh = *(const short8*)(wh_s + (ct * 16 + ml) * 40 + quad * 8);
            short8 bl = *(const short8*)(wl_s + (ct * 16 + ml) * 40 + quad * 8);
            acc[ct] = __builtin_amdgcn_mfma_f32_16x16x32_bf16(ah, bh, acc[ct], 0, 0, 0);
            acc[ct] = __builtin_amdgcn_mfma_f32_16x16x32_bf16(al, bh, acc[ct], 0, 0, 0);
            acc[ct] = __builtin_amdgcn_mfma_f32_16x16x32_bf16(ah, bl, acc[ct], 0, 0, 0);
        }
        __syncthreads();
    }

#pragma unroll
    for (int ct = 0; ct < 8; ++ct) {
        float bj = bo[ct * 16 + ml];
#pragma unroll
        for (int r = 0; r < 4; ++r) {
            int grow = n0 + w * 16 + quad * 4 + r;
            if (grow < Nn) out[(size_t)grow * 128 + ct * 16 + ml] = acc[ct][r] + bj;
        }
    }
}

// ---------------- CSR build ----------------
__global__ void deg_kernel(const int* __restrict__ ei, int* __restrict__ deg, int E_) {
    int e = blockIdx.x * 256 + threadIdx.x;
    if (e < E_) atomicAdd(&deg[ei[e]], 1);
}

__global__ __launch_bounds__(256) void scan_partial_kernel(const int* __restrict__ deg,
                                                           int* __restrict__ part, int n) {
    __shared__ int sm[4];
    int t = threadIdx.x;
    int idx4 = blockIdx.x * 1024 + t * 4;
    int s = 0;
    if (idx4 + 3 < n) {
        int4 d = *(const int4*)(deg + idx4);
        s = d.x + d.y + d.z + d.w;
    } else {
#pragma unroll
        for (int j = 0; j < 4; ++j) if (idx4 + j < n) s += deg[idx4 + j];
    }
#pragma unroll
    for (int off = 1; off < 64; off <<= 1) s += __shfl_xor(s, off);
    if ((t & 63) == 0) sm[t >> 6] = s;
    __syncthreads();
    if (t == 0) part[blockIdx.x] = sm[0] + sm[1] + sm[2] + sm[3];
}

__global__ __launch_bounds__(256) void scan_block_kernel(int* __restrict__ part, int npart,
                                                         int* __restrict__ rowstart, int n) {
    __shared__ int sm[256];
    int t = threadIdx.x;
    int v = (t < npart) ? part[t] : 0;
    sm[t] = v;
    __syncthreads();
    for (int off = 1; off < 256; off <<= 1) {
        int o = (t >= off) ? sm[t - off] : 0;
        __syncthreads();
        sm[t] += o;
        __syncthreads();
    }
    if (t < npart) part[t] = sm[t] - v;
    if (t == 255) rowstart[n] = sm[255];
}

__global__ __launch_bounds__(256) void scan_write_kernel(const int* __restrict__ deg,
                                                         const int* __restrict__ part,
                                                         int* __restrict__ rowstart,
                                                         int* __restrict__ cursor, int n) {
    __shared__ int sm[256];
    int t = threadIdx.x;
    int idx4 = blockIdx.x * 1024 + t * 4;
    int d0 = 0, d1 = 0, d2 = 0, d3 = 0;
    if (idx4 + 3 < n) {
        int4 d = *(const int4*)(deg + idx4);
        d0 = d.x; d1 = d.y; d2 = d.z; d3 = d.w;
    } else {
        if (idx4 + 0 < n) d0 = deg[idx4 + 0];
        if (idx4 + 1 < n) d1 = deg[idx4 + 1];
        if (idx4 + 2 < n) d2 = deg[idx4 + 2];
        if (idx4 + 3 < n) d3 = deg[idx4 + 3];
    }
    int s = d0 + d1 + d2 + d3;
    sm[t] = s;
    __syncthreads();
    for (int off = 1; off < 256; off <<= 1) {
        int o = (t >= off) ? sm[t - off] : 0;
        __syncthreads();
        sm[t] += o;
        __syncthreads();
    }
    int run = part[blockIdx.x] + sm[t] - s;
    int4 rs;
    rs.x = run;
    rs.y = run + d0;
    rs.z = rs.y + d1;
    rs.w = rs.z + d2;
    if (idx4 + 3 < n) {
        *(int4*)(rowstart + idx4) = rs;
        *(int4*)(cursor + idx4) = rs;
    } else {
        int rv[4] = {rs.x, rs.y, rs.z, rs.w};
#pragma unroll
        for (int j = 0; j < 4; ++j)
            if (idx4 + j < n) { rowstart[idx4 + j] = rv[j]; cursor[idx4 + j] = rv[j]; }
    }
}

// ---------------- scatter: {col, table-coord u} packed int2 into CSR order ----------------
__global__ void scatter_kernel(const int* __restrict__ ei, const float* __restrict__ edist,
                               int* __restrict__ cursor, int2* __restrict__ cpack, int E_) {
    int e = blockIdx.x * 256 + threadIdx.x;
    if (e >= E_) return;
    int row = ei[e];
    int pos = atomicAdd(&cursor[row], 1);
    float u = edist[e] * ((float)(TBL - 1) / 6.0f);
    u = fminf(fmaxf(u, 0.0f), (float)(TBL - 1));
    cpack[pos] = make_int2(ei[E_ + e], __float_as_int(u));
}

// ---------------- fused flash-style edge+node pass, head-per-lane, NO-MAX softmax ----------------
// One wave per node. Lane L: edge base+(L>>3), head h=L&7, owning all 16 features of
// head h. Logits are provably bounded (|d|*0.25*log2e + bias << 80), so the online
// max is dropped entirely: p = exp2(clamp(logit2, 80)); l += p; acc += p*v. This
// removes the serial rescale chain (ILP), the max bookkeeping, and turns the 8-group
// merge into pure sums. R9 post-mortem: cpack preload+shfl regressed (64.3->65.7us,
// VALU 52->67%) -- reverted to direct loads.
__global__ __launch_bounds__(256) void fused_node_kernel(
    const float* __restrict__ q, const unsigned short* __restrict__ kb,
    const unsigned short* __restrict__ vb, const int2* __restrict__ cpack,
    const float* __restrict__ tbl, const int* __restrict__ rowstart,
    unsigned short* __restrict__ oh, unsigned short* __restrict__ ol, int Nn) {
    int lane = threadIdx.x & 63;
    int n = blockIdx.x * 4 + (threadIdx.x >> 6);
    if (n >= Nn) return;
    int g = lane >> 3;       // edge subgroup
    int h = lane & 7;        // head
    int start = rowstart[n];
    int end = rowstart[n + 1];

    float qf[16];
    {
        const float4* qp = (const float4*)(q + (size_t)n * 128 + h * 16);
#pragma unroll
        for (int j = 0; j < 4; ++j) {
            float4 t = qp[j];
            qf[j * 4 + 0] = t.x; qf[j * 4 + 1] = t.y;
            qf[j * 4 + 2] = t.z; qf[j * 4 + 3] = t.w;
        }
    }

    float l = 0.0f;
    float acc[16];
#pragma unroll
    for (int j = 0; j < 16; ++j) acc[j] = 0.0f;

#pragma unroll 2
    for (int base = start; base < end; base += 8) {
        int e = base + g;
        bool valid = (e < end);
        int ee = valid ? e : (end - 1);
        int2 np = cpack[ee];
        int col = np.x;
        float u = __int_as_float(np.y);

        const uint4* kp = (const uint4*)(kb + (size_t)col * 128 + h * 16);
        uint4 k0 = kp[0], k1 = kp[1];
        const uint4* vp = (const uint4*)(vb + (size_t)col * 128 + h * 16);
        uint4 v0 = vp[0], v1 = vp[1];

        unsigned kk[8] = {k0.x, k0.y, k0.z, k0.w, k1.x, k1.y, k1.z, k1.w};
        float d = 0.0f;
#pragma unroll
        for (int j = 0; j < 8; ++j) {
            d = fmaf(bflo(kk[j]), qf[2 * j], d);
            d = fmaf(bfhi(kk[j]), qf[2 * j + 1], d);
        }

        int i0 = min((int)u, TBL - 2);
        float fr = u - (float)i0;
        float t0 = tbl[i0 * NH + h];
        float t1 = tbl[i0 * NH + NH + h];
        float logit2 = fmaf(d, 0.25f * LOG2E, fmaf(fr, t1 - t0, t0));
        logit2 = fminf(logit2, 80.0f);        // overflow guard (real logits << 80)
        if (!valid) logit2 = -1e30f;          // exp2 -> 0
        float p = __builtin_amdgcn_exp2f(logit2);

        l += p;
        unsigned vv[8] = {v0.x, v0.y, v0.z, v0.w, v1.x, v1.y, v1.z, v1.w};
#pragma unroll
        for (int j = 0; j < 8; ++j) {
            acc[2 * j]     = fmaf(p, bflo(vv[j]), acc[2 * j]);
            acc[2 * j + 1] = fmaf(p, bfhi(vv[j]), acc[2 * j + 1]);
        }
    }

    // pure-sum merge across the 8 edge-groups
#pragma unroll
    for (int off = 8; off < 64; off <<= 1) {
        l += __shfl_xor(l, off);
#pragma unroll
        for (int j = 0; j < 16; ++j) acc[j] += __shfl_xor(acc[j], off);
    }

    if (g == 0) {
        float inv = 1.0f / (l + 1e-12f);
        unsigned short hv[16], lv[16];
#pragma unroll
        for (int j = 0; j < 16; ++j) {
            float o = acc[j] * inv;
            split1(o, hv[j], lv[j]);
        }
        *(short8*)(oh + (size_t)n * 128 + h * 16) = *(short8*)hv;
        *(short8*)(oh + (size_t)n * 128 + h * 16 + 8) = *(short8*)(hv + 8);
        *(short8*)(ol + (size_t)n * 128 + h * 16) = *(short8*)lv;
        *(short8*)(ol + (size_t)n * 128 + h * 16 + 8) = *(short8*)(lv + 8);
    }
}

extern "C" void kernel_launch(void* const* d_in, const int* in_sizes, int n_in,
                              void* d_out, int out_size, void* d_ws, size_t ws_size,
                              hipStream_t stream) {
    const float* x   = (const float*)d_in[0];
    const int* ei    = (const int*)d_in[1];
    const float* edist = (const float*)d_in[2];
    const float* Wq = (const float*)d_in[3];  const float* bq = (const float*)d_in[4];
    const float* Wk = (const float*)d_in[5];  const float* bk = (const float*)d_in[6];
    const float* Wv = (const float*)d_in[7];  const float* bv = (const float*)d_in[8];
    const float* Wo = (const float*)d_in[9];  const float* bo = (const float*)d_in[10];
    const float* Wg1 = (const float*)d_in[11]; const float* bg1 = (const float*)d_in[12];
    const float* Wg2 = (const float*)d_in[13]; const float* bg2 = (const float*)d_in[14];
    const int Nn = in_sizes[0] / IN_DIM;
    const int Ee = in_sizes[2];
    float* out = (float*)d_out;

    char* ws = (char*)d_ws;
    size_t off = 0;
    auto alloc = [&](size_t bytes) -> char* {
        char* p = ws + off;
        off += (bytes + 255) & ~(size_t)255;
        return p;
    };
    float* q  = (float*)alloc((size_t)Nn * 128 * 4);
    unsigned short* kbuf = (unsigned short*)alloc((size_t)Nn * 128 * 2);
    unsigned short* vbuf = (unsigned short*)alloc((size_t)Nn * 128 * 2);
    char* xlblock = alloc((size_t)Nn * IN_DIM * 2);
    unsigned short* o_hi = (unsigned short*)alloc((size_t)Nn * 128 * 2);
    unsigned short* o_lo = (unsigned short*)alloc((size_t)Nn * 128 * 2);
    float* geot = (float*)alloc((size_t)TBL * 8 * 4);
    int* deg      = (int*)alloc((size_t)Nn * 4);
    int* rowstart = (int*)alloc((size_t)(Nn + 1) * 4);
    int* cursor   = (int*)alloc((size_t)Nn * 4);
    int* part     = (int*)alloc((size_t)256 * 4);
    unsigned short* wh_all = (unsigned short*)alloc((size_t)3 * OUT_DIM * IN_DIM * 2);
    unsigned short* wl_all = (unsigned short*)alloc((size_t)3 * OUT_DIM * IN_DIM * 2);
    unsigned short* wo_h = (unsigned short*)alloc((size_t)OUT_DIM * OUT_DIM * 2);
    unsigned short* wo_l = (unsigned short*)alloc((size_t)OUT_DIM * OUT_DIM * 2);

    unsigned short* xh = (unsigned short*)d_out;       // rewritten by final GEMM
    unsigned short* xl = (unsigned short*)xlblock;
    int2* cpack = (int2*)xlblock;                       // live after qkv_mfma

    hipMemsetAsync(deg, 0, (size_t)Nn * 4, stream);

    int n4x = Nn * IN_DIM / 4;
    split_x_kernel<<<(n4x + 255) / 256, 256, 0, stream>>>(x, xh, xl, n4x);
    prep_w_geo_kernel<<<dim3((OUT_DIM * IN_DIM / 4 + 255) / 256, 5), 256, 0, stream>>>(
        Wq, Wk, Wv, Wo, wh_all, wl_all, wo_h, wo_l, Wg1, bg1, Wg2, bg2, geot);

    dim3 gq((Nn + 63) / 64, 3);
    qkv_mfma_kernel<<<gq, 256, 0, stream>>>(xh, xl, wh_all, wl_all, bq, bk, bv, q, kbuf, vbuf, Nn);

    deg_kernel<<<(Ee + 255) / 256, 256, 0, stream>>>(ei, deg, Ee);

    int nblk = (Nn + 1023) / 1024;
    scan_partial_kernel<<<nblk, 256, 0, stream>>>(deg, part, Nn);
    scan_block_kernel<<<1, 256, 0, stream>>>(part, nblk, rowstart, Nn);
    scan_write_kernel<<<nblk, 256, 0, stream>>>(deg, part, rowstart, cursor, Nn);

    scatter_kernel<<<(Ee + 255) / 256, 256, 0, stream>>>(ei, edist, cursor, cpack, Ee);

    fused_node_kernel<<<(Nn + 3) / 4, 256, 0, stream>>>(q, kbuf, vbuf, cpack, geot, rowstart, o_hi, o_lo, Nn);

    out_gemm_mfma_kernel<<<(Nn + 63) / 64, 256, 0, stream>>>(o_hi, o_lo, wo_h, wo_l, bo, out, Nn);
}

// Round 11
// 342.651 us; speedup vs baseline: 5.5916x; 1.0610x over previous
//
#include <hip/hip_runtime.h>
#include <math.h>

#define IN_DIM 256
#define OUT_DIM 128
#define NH 8
#define HD 16
#define GH 16
#define TBL 1024
#define LOG2E 1.44269504f

typedef __attribute__((ext_vector_type(8))) short short8;
typedef __attribute__((ext_vector_type(4))) float floatx4;

// ---------------- bf16 helpers (RNE) ----------------
__device__ __forceinline__ unsigned short f2bf(float f) {
    union { float f; unsigned u; } v; v.f = f;
    unsigned r = v.u + 0x7fffu + ((v.u >> 16) & 1u);
    return (unsigned short)(r >> 16);
}
__device__ __forceinline__ float bf2f(unsigned short h) {
    union { unsigned u; float f; } v; v.u = ((unsigned)h) << 16;
    return v.f;
}
__device__ __forceinline__ void split1(float f, unsigned short& h, unsigned short& l) {
    h = f2bf(f);
    l = f2bf(f - bf2f(h));
}
__device__ __forceinline__ float bflo(unsigned u) { return __uint_as_float(u << 16); }
__device__ __forceinline__ float bfhi(unsigned u) { return __uint_as_float(u & 0xffff0000u); }

// ---------------- prep_all: split x, split Wq/Wk/Wv/Wo, geo table, zero deg+part ----------------
// 1D grid, block ranges. All sub-tasks independent. Replaces 3 dispatches (memset,
// split_x, prep_w_geo) -- R10 post-mortem: ~10us/dispatch gap x 11 dispatches is
// first-order; kernel sum is only ~half the wall time.
__global__ __launch_bounds__(256) void prep_all_kernel(
    const float* __restrict__ x, const float* __restrict__ Wq, const float* __restrict__ Wk,
    const float* __restrict__ Wv, const float* __restrict__ Wo,
    unsigned short* __restrict__ xh, unsigned short* __restrict__ xl,
    unsigned short* __restrict__ wh, unsigned short* __restrict__ wl,
    unsigned short* __restrict__ wo_h, unsigned short* __restrict__ wo_l,
    const float* __restrict__ Wg1, const float* __restrict__ bg1,
    const float* __restrict__ Wg2, const float* __restrict__ bg2,
    float* __restrict__ tbl, int* __restrict__ deg, int* __restrict__ part,
    int n4x, int Nn, int nsplit, int nwm, int nwo, int ngeo, int ndegz) {
    int bx = blockIdx.x;
    int t = threadIdx.x;

    if (bx < nsplit) {                       // split x
        int i = bx * 256 + t;
        if (i >= n4x) return;
        float4 f = ((const float4*)x)[i];
        ushort4 h, l;
        split1(f.x, h.x, l.x); split1(f.y, h.y, l.y);
        split1(f.z, h.z, l.z); split1(f.w, h.w, l.w);
        ((ushort4*)xh)[i] = h;
        ((ushort4*)xl)[i] = l;
        return;
    }
    bx -= nsplit;
    if (bx < 3 * nwm) {                      // split Wq/Wk/Wv
        int m = bx / nwm;
        int i = (bx - m * nwm) * 256 + t;
        if (i >= (OUT_DIM * IN_DIM) / 4) return;
        const float* W = (m == 0) ? Wq : (m == 1) ? Wk : Wv;
        float4 f = ((const float4*)W)[i];
        ushort4 h, l;
        split1(f.x, h.x, l.x); split1(f.y, h.y, l.y);
        split1(f.z, h.z, l.z); split1(f.w, h.w, l.w);
        size_t base = (size_t)m * (OUT_DIM * IN_DIM) / 4;
        ((ushort4*)wh)[base + i] = h;
        ((ushort4*)wl)[base + i] = l;
        return;
    }
    bx -= 3 * nwm;
    if (bx < nwo) {                          // split Wo
        int i = bx * 256 + t;
        if (i >= (OUT_DIM * OUT_DIM) / 4) return;
        float4 f = ((const float4*)Wo)[i];
        ushort4 h, l;
        split1(f.x, h.x, l.x); split1(f.y, h.y, l.y);
        split1(f.z, h.z, l.z); split1(f.w, h.w, l.w);
        ((ushort4*)wo_h)[i] = h;
        ((ushort4*)wo_l)[i] = l;
        return;
    }
    bx -= nwo;
    if (bx < ngeo) {                         // geo bias table (log2-domain)
        int i = bx * 256 + t;
        if (i >= TBL) return;
        float d = (float)i * (6.0f / (float)(TBL - 1));
        float rbf[GH];
#pragma unroll
        for (int j = 0; j < GH; ++j) {
            float c = 0.4f * (float)j;
            float tt = d - c;
            rbf[j] = __expf(-tt * tt);
        }
        float hid[GH];
#pragma unroll
        for (int j = 0; j < GH; ++j) {
            float acc = bg1[j];
#pragma unroll
            for (int kk = 0; kk < GH; ++kk) acc += rbf[kk] * Wg1[j * GH + kk];
            hid[j] = fmaxf(acc, 0.0f);
        }
#pragma unroll
        for (int h = 0; h < NH; ++h) {
            float acc = bg2[h];
#pragma unroll
            for (int j = 0; j < GH; ++j) acc += hid[j] * Wg2[h * GH + j];
            tbl[i * NH + h] = acc * LOG2E;
        }
        return;
    }
    bx -= ngeo;
    if (bx < ndegz) {                        // zero deg (int4)
        int idx4 = (bx * 256 + t) * 4;
        if (idx4 + 3 < Nn) {
            *(int4*)(deg + idx4) = make_int4(0, 0, 0, 0);
        } else {
#pragma unroll
            for (int j = 0; j < 4; ++j) if (idx4 + j < Nn) deg[idx4 + j] = 0;
        }
        return;
    }
    // last block: zero part/flags
    if (t < 256) part[t] = 0;
}

// ---------------- qkv (split-bf16 MFMA) + deg count, one dispatch ----------------
// bx < 3*nxb: qkv tile; else: deg atomicAdd block (independent; deg zeroed in prep_all).
__global__ __launch_bounds__(256) void qkv_deg_kernel(
    const unsigned short* __restrict__ xh, const unsigned short* __restrict__ xl,
    const unsigned short* __restrict__ wh, const unsigned short* __restrict__ wl,
    const float* __restrict__ bq, const float* __restrict__ bk, const float* __restrict__ bv,
    float* __restrict__ q, unsigned short* __restrict__ kb, unsigned short* __restrict__ vb,
    const int* __restrict__ ei, int* __restrict__ deg, int Nn, int E_, int nxb) {
    int bx = blockIdx.x;
    if (bx >= 3 * nxb) {                     // deg blocks
        int e = (bx - 3 * nxb) * 256 + threadIdx.x;
        if (e < E_) atomicAdd(&deg[ei[e]], 1);
        return;
    }
    const int wsel = bx / nxb;
    const int n0 = (bx - wsel * nxb) * 64;
    const unsigned short* W_h = wh + (size_t)wsel * (OUT_DIM * IN_DIM);
    const unsigned short* W_l = wl + (size_t)wsel * (OUT_DIM * IN_DIM);
    const float* bias = (wsel == 0) ? bq : (wsel == 1) ? bk : bv;

    __shared__ unsigned short xh_s[64 * 40];
    __shared__ unsigned short xl_s[64 * 40];
    __shared__ unsigned short wh_s[128 * 40];
    __shared__ unsigned short wl_s[128 * 40];

    const int tid = threadIdx.x;
    const int w = tid >> 6;
    const int lane = tid & 63;
    const int ml = lane & 15;
    const int quad = lane >> 4;

    const int rows_valid = min(64, Nn - n0);

    floatx4 acc[8];
#pragma unroll
    for (int ct = 0; ct < 8; ++ct) acc[ct] = (floatx4){0.f, 0.f, 0.f, 0.f};

    const short8 zero8 = {0, 0, 0, 0, 0, 0, 0, 0};

    for (int kc = 0; kc < IN_DIM; kc += 32) {
        {
            int r = tid >> 2, c = tid & 3;
            short8 vh = zero8, vl = zero8;
            if (r < rows_valid) {
                size_t g = (size_t)(n0 + r) * IN_DIM + kc + c * 8;
                vh = *(const short8*)(xh + g);
                vl = *(const short8*)(xl + g);
            }
            *(short8*)(xh_s + r * 40 + c * 8) = vh;
            *(short8*)(xl_s + r * 40 + c * 8) = vl;
        }
#pragma unroll
        for (int l = 0; l < 2; ++l) {
            int idx = tid + l * 256;
            int r = idx >> 2, c = idx & 3;
            size_t g = (size_t)r * IN_DIM + kc + c * 8;
            *(short8*)(wh_s + r * 40 + c * 8) = *(const short8*)(W_h + g);
            *(short8*)(wl_s + r * 40 + c * 8) = *(const short8*)(W_l + g);
        }
        __syncthreads();

        short8 ah = *(const short8*)(xh_s + (w * 16 + ml) * 40 + quad * 8);
        short8 al = *(const short8*)(xl_s + (w * 16 + ml) * 40 + quad * 8);
#pragma unroll
        for (int ct = 0; ct < 8; ++ct) {
            short8 bh = *(const short8*)(wh_s + (ct * 16 + ml) * 40 + quad * 8);
            short8 bl = *(const short8*)(wl_s + (ct * 16 + ml) * 40 + quad * 8);
            acc[ct] = __builtin_amdgcn_mfma_f32_16x16x32_bf16(ah, bh, acc[ct], 0, 0, 0);
            acc[ct] = __builtin_amdgcn_mfma_f32_16x16x32_bf16(al, bh, acc[ct], 0, 0, 0);
            acc[ct] = __builtin_amdgcn_mfma_f32_16x16x32_bf16(ah, bl, acc[ct], 0, 0, 0);
        }
        __syncthreads();
    }

    if (wsel == 0) {
#pragma unroll
        for (int ct = 0; ct < 8; ++ct) {
            float bj = bias[ct * 16 + ml];
#pragma unroll
            for (int r = 0; r < 4; ++r) {
                int grow = n0 + w * 16 + quad * 4 + r;
                if (grow < Nn) q[(size_t)grow * 128 + ct * 16 + ml] = acc[ct][r] + bj;
            }
        }
    } else {
        unsigned short* ob = (wsel == 1) ? kb : vb;
#pragma unroll
        for (int ct = 0; ct < 8; ++ct) {
            float bj = bias[ct * 16 + ml];
#pragma unroll
            for (int r = 0; r < 4; ++r) {
                int grow = n0 + w * 16 + quad * 4 + r;
                if (grow < Nn) ob[(size_t)grow * 128 + ct * 16 + ml] = f2bf(acc[ct][r] + bj);
            }
        }
    }
}

// ---------------- one-dispatch exclusive scan (decoupled lookback, nblk<=256 blocks) ----------------
// All blocks co-resident (nblk=49 << 256 CUs) -> publish/poll cannot deadlock.
// part[] pre-zeroed by prep_all; block b publishes (local_total+1) via atomicExch,
// polls part[0..b-1], then writes rowstart/cursor with int4 stores.
__global__ __launch_bounds__(256) void scan_onepass_kernel(
    const int* __restrict__ deg, int* __restrict__ part,
    int* __restrict__ rowstart, int* __restrict__ cursor, int n, int nblk) {
    __shared__ int sm[256];
    int b = blockIdx.x;
    int t = threadIdx.x;
    int idx4 = b * 1024 + t * 4;
    int d0 = 0, d1 = 0, d2 = 0, d3 = 0;
    if (idx4 + 3 < n) {
        int4 d = *(const int4*)(deg + idx4);
        d0 = d.x; d1 = d.y; d2 = d.z; d3 = d.w;
    } else {
        if (idx4 + 0 < n) d0 = deg[idx4 + 0];
        if (idx4 + 1 < n) d1 = deg[idx4 + 1];
        if (idx4 + 2 < n) d2 = deg[idx4 + 2];
        if (idx4 + 3 < n) d3 = deg[idx4 + 3];
    }
    int s = d0 + d1 + d2 + d3;
    sm[t] = s;
    __syncthreads();
    for (int off = 1; off < 256; off <<= 1) {
        int o = (t >= off) ? sm[t - off] : 0;
        __syncthreads();
        sm[t] += o;
        __syncthreads();
    }
    int myprefix = sm[t] - s;        // exclusive within block
    int total = sm[255];
    __syncthreads();

    if (t == 0) atomicExch(&part[b], total + 1);   // publish (device-scope)

    // parallel poll of predecessors: thread t spins on part[t] for t < b
    int pv = 0;
    if (t < b) {
        while ((pv = atomicAdd(&part[t], 0)) == 0) {}
        pv -= 1;
    }
    sm[t] = (t < b) ? pv : 0;
    __syncthreads();
    for (int off = 128; off > 0; off >>= 1) {
        if (t < off) sm[t] += sm[t + off];
        __syncthreads();
    }
    int offset = sm[0];

    int run = offset + myprefix;
    int4 rs;
    rs.x = run;
    rs.y = run + d0;
    rs.z = rs.y + d1;
    rs.w = rs.z + d2;
    if (idx4 + 3 < n) {
        *(int4*)(rowstart + idx4) = rs;
        *(int4*)(cursor + idx4) = rs;
    } else {
        int rv[4] = {rs.x, rs.y, rs.z, rs.w};
#pragma unroll
        for (int j = 0; j < 4; ++j)
            if (idx4 + j < n) { rowstart[idx4 + j] = rv[j]; cursor[idx4 + j] = rv[j]; }
    }
    if (b == nblk - 1 && t == 255) rowstart[n] = offset + total;
}

// ---------------- scatter: {col, table-coord u} packed int2 into CSR order ----------------
__global__ void scatter_kernel(const int* __restrict__ ei, const float* __restrict__ edist,
                               int* __restrict__ cursor, int2* __restrict__ cpack, int E_) {
    int e = blockIdx.x * 256 + threadIdx.x;
    if (e >= E_) return;
    int row = ei[e];
    int pos = atomicAdd(&cursor[row], 1);
    float u = edist[e] * ((float)(TBL - 1) / 6.0f);
    u = fminf(fmaxf(u, 0.0f), (float)(TBL - 1));
    cpack[pos] = make_int2(ei[E_ + e], __float_as_int(u));
}

// ---------------- fused flash-style edge+node pass (unchanged from R10) ----------------
__global__ __launch_bounds__(256) void fused_node_kernel(
    const float* __restrict__ q, const unsigned short* __restrict__ kb,
    const unsigned short* __restrict__ vb, const int2* __restrict__ cpack,
    const float* __restrict__ tbl, const int* __restrict__ rowstart,
    unsigned short* __restrict__ oh, unsigned short* __restrict__ ol, int Nn) {
    int lane = threadIdx.x & 63;
    int n = blockIdx.x * 4 + (threadIdx.x >> 6);
    if (n >= Nn) return;
    int g = lane >> 3;       // edge subgroup
    int h = lane & 7;        // head
    int start = rowstart[n];
    int end = rowstart[n + 1];

    float qf[16];
    {
        const float4* qp = (const float4*)(q + (size_t)n * 128 + h * 16);
#pragma unroll
        for (int j = 0; j < 4; ++j) {
            float4 t = qp[j];
            qf[j * 4 + 0] = t.x; qf[j * 4 + 1] = t.y;
            qf[j * 4 + 2] = t.z; qf[j * 4 + 3] = t.w;
        }
    }

    float l = 0.0f;
    float acc[16];
#pragma unroll
    for (int j = 0; j < 16; ++j) acc[j] = 0.0f;

#pragma unroll 2
    for (int base = start; base < end; base += 8) {
        int e = base + g;
        bool valid = (e < end);
        int ee = valid ? e : (end - 1);
        int2 np = cpack[ee];
        int col = np.x;
        float u = __int_as_float(np.y);

        const uint4* kp = (const uint4*)(kb + (size_t)col * 128 + h * 16);
        uint4 k0 = kp[0], k1 = kp[1];
        const uint4* vp = (const uint4*)(vb + (size_t)col * 128 + h * 16);
        uint4 v0 = vp[0], v1 = vp[1];

        unsigned kk[8] = {k0.x, k0.y, k0.z, k0.w, k1.x, k1.y, k1.z, k1.w};
        float d = 0.0f;
#pragma unroll
        for (int j = 0; j < 8; ++j) {
            d = fmaf(bflo(kk[j]), qf[2 * j], d);
            d = fmaf(bfhi(kk[j]), qf[2 * j + 1], d);
        }

        int i0 = min((int)u, TBL - 2);
        float fr = u - (float)i0;
        float t0 = tbl[i0 * NH + h];
        float t1 = tbl[i0 * NH + NH + h];
        float logit2 = fmaf(d, 0.25f * LOG2E, fmaf(fr, t1 - t0, t0));
        logit2 = fminf(logit2, 80.0f);        // overflow guard (real logits << 80)
        if (!valid) logit2 = -1e30f;          // exp2 -> 0
        float p = __builtin_amdgcn_exp2f(logit2);

        l += p;
        unsigned vv[8] = {v0.x, v0.y, v0.z, v0.w, v1.x, v1.y, v1.z, v1.w};
#pragma unroll
        for (int j = 0; j < 8; ++j) {
            acc[2 * j]     = fmaf(p, bflo(vv[j]), acc[2 * j]);
            acc[2 * j + 1] = fmaf(p, bfhi(vv[j]), acc[2 * j + 1]);
        }
    }

#pragma unroll
    for (int off = 8; off < 64; off <<= 1) {
        l += __shfl_xor(l, off);
#pragma unroll
        for (int j = 0; j < 16; ++j) acc[j] += __shfl_xor(acc[j], off);
    }

    if (g == 0) {
        float inv = 1.0f / (l + 1e-12f);
        unsigned short hv[16], lv[16];
#pragma unroll
        for (int j = 0; j < 16; ++j) {
            float o = acc[j] * inv;
            split1(o, hv[j], lv[j]);
        }
        *(short8*)(oh + (size_t)n * 128 + h * 16) = *(short8*)hv;
        *(short8*)(oh + (size_t)n * 128 + h * 16 + 8) = *(short8*)(hv + 8);
        *(short8*)(ol + (size_t)n * 128 + h * 16) = *(short8*)lv;
        *(short8*)(ol + (size_t)n * 128 + h * 16 + 8) = *(short8*)(lv + 8);
    }
}

// ---------------- out GEMM via split-bf16 MFMA (K=128) ----------------
__global__ __launch_bounds__(256) void out_gemm_mfma_kernel(
    const unsigned short* __restrict__ oh, const unsigned short* __restrict__ ol,
    const unsigned short* __restrict__ wo_h, const unsigned short* __restrict__ wo_l,
    const float* __restrict__ bo, float* __restrict__ out, int Nn) {
    const int n0 = blockIdx.x * 64;

    __shared__ unsigned short xh_s[64 * 40];
    __shared__ unsigned short xl_s[64 * 40];
    __shared__ unsigned short wh_s[128 * 40];
    __shared__ unsigned short wl_s[128 * 40];

    const int tid = threadIdx.x;
    const int w = tid >> 6;
    const int lane = tid & 63;
    const int ml = lane & 15;
    const int quad = lane >> 4;

    const int rows_valid = min(64, Nn - n0);

    floatx4 acc[8];
#pragma unroll
    for (int ct = 0; ct < 8; ++ct) acc[ct] = (floatx4){0.f, 0.f, 0.f, 0.f};

    const short8 zero8 = {0, 0, 0, 0, 0, 0, 0, 0};

    for (int kc = 0; kc < OUT_DIM; kc += 32) {
        {
            int r = tid >> 2, c = tid & 3;
            short8 vh = zero8, vl = zero8;
            if (r < rows_valid) {
                size_t g = (size_t)(n0 + r) * OUT_DIM + kc + c * 8;
                vh = *(const short8*)(oh + g);
                vl = *(const short8*)(ol + g);
            }
            *(short8*)(xh_s + r * 40 + c * 8) = vh;
            *(short8*)(xl_s + r * 40 + c * 8) = vl;
        }
#pragma unroll
        for (int l = 0; l < 2; ++l) {
            int idx = tid + l * 256;
            int r = idx >> 2, c = idx & 3;
            size_t g = (size_t)r * OUT_DIM + kc + c * 8;
            *(short8*)(wh_s + r * 40 + c * 8) = *(const short8*)(wo_h + g);
            *(short8*)(wl_s + r * 40 + c * 8) = *(const short8*)(wo_l + g);
        }
        __syncthreads();

        short8 ah = *(const short8*)(xh_s + (w * 16 + ml) * 40 + quad * 8);
        short8 al = *(const short8*)(xl_s + (w * 16 + ml) * 40 + quad * 8);
#pragma unroll
        for (int ct = 0; ct < 8; ++ct) {
            short8 bh = *(const short8*)(wh_s + (ct * 16 + ml) * 40 + quad * 8);
            short8 bl = *(const short8*)(wl_s + (ct * 16 + ml) * 40 + quad * 8);
            acc[ct] = __builtin_amdgcn_mfma_f32_16x16x32_bf16(ah, bh, acc[ct], 0, 0, 0);
            acc[ct] = __builtin_amdgcn_mfma_f32_16x16x32_bf16(al, bh, acc[ct], 0, 0, 0);
            acc[ct] = __builtin_amdgcn_mfma_f32_16x16x32_bf16(ah, bl, acc[ct], 0, 0, 0);
        }
        __syncthreads();
    }

#pragma unroll
    for (int ct = 0; ct < 8; ++ct) {
        float bj = bo[ct * 16 + ml];
#pragma unroll
        for (int r = 0; r < 4; ++r) {
            int grow = n0 + w * 16 + quad * 4 + r;
            if (grow < Nn) out[(size_t)grow * 128 + ct * 16 + ml] = acc[ct][r] + bj;
        }
    }
}

extern "C" void kernel_launch(void* const* d_in, const int* in_sizes, int n_in,
                              void* d_out, int out_size, void* d_ws, size_t ws_size,
                              hipStream_t stream) {
    const float* x   = (const float*)d_in[0];
    const int* ei    = (const int*)d_in[1];
    const float* edist = (const float*)d_in[2];
    const float* Wq = (const float*)d_in[3];  const float* bq = (const float*)d_in[4];
    const float* Wk = (const float*)d_in[5];  const float* bk = (const float*)d_in[6];
    const float* Wv = (const float*)d_in[7];  const float* bv = (const float*)d_in[8];
    const float* Wo = (const float*)d_in[9];  const float* bo = (const float*)d_in[10];
    const float* Wg1 = (const float*)d_in[11]; const float* bg1 = (const float*)d_in[12];
    const float* Wg2 = (const float*)d_in[13]; const float* bg2 = (const float*)d_in[14];
    const int Nn = in_sizes[0] / IN_DIM;
    const int Ee = in_sizes[2];
    float* out = (float*)d_out;

    char* ws = (char*)d_ws;
    size_t off = 0;
    auto alloc = [&](size_t bytes) -> char* {
        char* p = ws + off;
        off += (bytes + 255) & ~(size_t)255;
        return p;
    };
    float* q  = (float*)alloc((size_t)Nn * 128 * 4);
    unsigned short* kbuf = (unsigned short*)alloc((size_t)Nn * 128 * 2);
    unsigned short* vbuf = (unsigned short*)alloc((size_t)Nn * 128 * 2);
    char* xlblock = alloc((size_t)Nn * IN_DIM * 2);
    unsigned short* o_hi = (unsigned short*)alloc((size_t)Nn * 128 * 2);
    unsigned short* o_lo = (unsigned short*)alloc((size_t)Nn * 128 * 2);
    float* geot = (float*)alloc((size_t)TBL * 8 * 4);
    int* deg      = (int*)alloc((size_t)Nn * 4);
    int* rowstart = (int*)alloc((size_t)(Nn + 1) * 4);
    int* cursor   = (int*)alloc((size_t)Nn * 4);
    int* part     = (int*)alloc((size_t)256 * 4);
    unsigned short* wh_all = (unsigned short*)alloc((size_t)3 * OUT_DIM * IN_DIM * 2);
    unsigned short* wl_all = (unsigned short*)alloc((size_t)3 * OUT_DIM * IN_DIM * 2);
    unsigned short* wo_h = (unsigned short*)alloc((size_t)OUT_DIM * OUT_DIM * 2);
    unsigned short* wo_l = (unsigned short*)alloc((size_t)OUT_DIM * OUT_DIM * 2);

    unsigned short* xh = (unsigned short*)d_out;       // rewritten by final GEMM
    unsigned short* xl = (unsigned short*)xlblock;
    int2* cpack = (int2*)xlblock;                       // live after qkv

    // --- dispatch 1: prep_all ---
    int n4x = Nn * IN_DIM / 4;
    int nsplit = (n4x + 255) / 256;
    int nwm = ((OUT_DIM * IN_DIM / 4) + 255) / 256;
    int nwo = ((OUT_DIM * OUT_DIM / 4) + 255) / 256;
    int ngeo = (TBL + 255) / 256;
    int ndegz = (Nn + 1023) / 1024;
    int gprep = nsplit + 3 * nwm + nwo + ngeo + ndegz + 1;
    prep_all_kernel<<<gprep, 256, 0, stream>>>(
        x, Wq, Wk, Wv, Wo, xh, xl, wh_all, wl_all, wo_h, wo_l,
        Wg1, bg1, Wg2, bg2, geot, deg, part, n4x, Nn, nsplit, nwm, nwo, ngeo, ndegz);

    // --- dispatch 2: qkv + deg ---
    int nxb = (Nn + 63) / 64;
    int ndegb = (Ee + 255) / 256;
    qkv_deg_kernel<<<3 * nxb + ndegb, 256, 0, stream>>>(
        xh, xl, wh_all, wl_all, bq, bk, bv, q, kbuf, vbuf, ei, deg, Nn, Ee, nxb);

    // --- dispatch 3: one-pass scan ---
    int nblk = (Nn + 1023) / 1024;   // 49 <= 256, all blocks co-resident
    scan_onepass_kernel<<<nblk, 256, 0, stream>>>(deg, part, rowstart, cursor, Nn, nblk);

    // --- dispatch 4: scatter ---
    scatter_kernel<<<(Ee + 255) / 256, 256, 0, stream>>>(ei, edist, cursor, cpack, Ee);

    // --- dispatch 5: fused edge+node ---
    fused_node_kernel<<<(Nn + 3) / 4, 256, 0, stream>>>(q, kbuf, vbuf, cpack, geot, rowstart, o_hi, o_lo, Nn);

    // --- dispatch 6: out GEMM ---
    out_gemm_mfma_kernel<<<(Nn + 63) / 64, 256, 0, stream>>>(o_hi, o_lo, wo_h, wo_l, bo, out, Nn);
}

// Round 12
// 333.588 us; speedup vs baseline: 5.7435x; 1.0272x over previous
//
#include <hip/hip_runtime.h>
#include <math.h>

#define IN_DIM 256
#define OUT_DIM 128
#define NH 8
#define HD 16
#define GH 16
#define TBL 1024
#define LOG2E 1.44269504f

typedef __attribute__((ext_vector_type(8))) short short8;
typedef __attribute__((ext_vector_type(4))) float floatx4;

// ---------------- bf16 helpers (RNE) ----------------
__device__ __forceinline__ unsigned short f2bf(float f) {
    union { float f; unsigned u; } v; v.f = f;
    unsigned r = v.u + 0x7fffu + ((v.u >> 16) & 1u);
    return (unsigned short)(r >> 16);
}
__device__ __forceinline__ float bf2f(unsigned short h) {
    union { unsigned u; float f; } v; v.u = ((unsigned)h) << 16;
    return v.f;
}
__device__ __forceinline__ void split1(float f, unsigned short& h, unsigned short& l) {
    h = f2bf(f);
    l = f2bf(f - bf2f(h));
}
__device__ __forceinline__ float bflo(unsigned u) { return __uint_as_float(u << 16); }
__device__ __forceinline__ float bfhi(unsigned u) { return __uint_as_float(u & 0xffff0000u); }

// ---------------- prep_all: split x, split Wq/Wk/Wv/Wo, geo table, zero deg+part ----------------
__global__ __launch_bounds__(256) void prep_all_kernel(
    const float* __restrict__ x, const float* __restrict__ Wq, const float* __restrict__ Wk,
    const float* __restrict__ Wv, const float* __restrict__ Wo,
    unsigned short* __restrict__ xh, unsigned short* __restrict__ xl,
    unsigned short* __restrict__ wh, unsigned short* __restrict__ wl,
    unsigned short* __restrict__ wo_h, unsigned short* __restrict__ wo_l,
    const float* __restrict__ Wg1, const float* __restrict__ bg1,
    const float* __restrict__ Wg2, const float* __restrict__ bg2,
    float* __restrict__ tbl, int* __restrict__ deg, int* __restrict__ part,
    int n4x, int Nn, int nsplit, int nwm, int nwo, int ngeo, int ndegz) {
    int bx = blockIdx.x;
    int t = threadIdx.x;

    if (bx < nsplit) {                       // split x
        int i = bx * 256 + t;
        if (i >= n4x) return;
        float4 f = ((const float4*)x)[i];
        ushort4 h, l;
        split1(f.x, h.x, l.x); split1(f.y, h.y, l.y);
        split1(f.z, h.z, l.z); split1(f.w, h.w, l.w);
        ((ushort4*)xh)[i] = h;
        ((ushort4*)xl)[i] = l;
        return;
    }
    bx -= nsplit;
    if (bx < 3 * nwm) {                      // split Wq/Wk/Wv
        int m = bx / nwm;
        int i = (bx - m * nwm) * 256 + t;
        if (i >= (OUT_DIM * IN_DIM) / 4) return;
        const float* W = (m == 0) ? Wq : (m == 1) ? Wk : Wv;
        float4 f = ((const float4*)W)[i];
        ushort4 h, l;
        split1(f.x, h.x, l.x); split1(f.y, h.y, l.y);
        split1(f.z, h.z, l.z); split1(f.w, h.w, l.w);
        size_t base = (size_t)m * (OUT_DIM * IN_DIM) / 4;
        ((ushort4*)wh)[base + i] = h;
        ((ushort4*)wl)[base + i] = l;
        return;
    }
    bx -= 3 * nwm;
    if (bx < nwo) {                          // split Wo
        int i = bx * 256 + t;
        if (i >= (OUT_DIM * OUT_DIM) / 4) return;
        float4 f = ((const float4*)Wo)[i];
        ushort4 h, l;
        split1(f.x, h.x, l.x); split1(f.y, h.y, l.y);
        split1(f.z, h.z, l.z); split1(f.w, h.w, l.w);
        ((ushort4*)wo_h)[i] = h;
        ((ushort4*)wo_l)[i] = l;
        return;
    }
    bx -= nwo;
    if (bx < ngeo) {                         // geo bias table (log2-domain)
        int i = bx * 256 + t;
        if (i >= TBL) return;
        float d = (float)i * (6.0f / (float)(TBL - 1));
        float rbf[GH];
#pragma unroll
        for (int j = 0; j < GH; ++j) {
            float c = 0.4f * (float)j;
            float tt = d - c;
            rbf[j] = __expf(-tt * tt);
        }
        float hid[GH];
#pragma unroll
        for (int j = 0; j < GH; ++j) {
            float acc = bg1[j];
#pragma unroll
            for (int kk = 0; kk < GH; ++kk) acc += rbf[kk] * Wg1[j * GH + kk];
            hid[j] = fmaxf(acc, 0.0f);
        }
#pragma unroll
        for (int h = 0; h < NH; ++h) {
            float acc = bg2[h];
#pragma unroll
            for (int j = 0; j < GH; ++j) acc += hid[j] * Wg2[h * GH + j];
            tbl[i * NH + h] = acc * LOG2E;
        }
        return;
    }
    bx -= ngeo;
    if (bx < ndegz) {                        // zero deg (int4)
        int idx4 = (bx * 256 + t) * 4;
        if (idx4 + 3 < Nn) {
            *(int4*)(deg + idx4) = make_int4(0, 0, 0, 0);
        } else {
#pragma unroll
            for (int j = 0; j < 4; ++j) if (idx4 + j < Nn) deg[idx4 + j] = 0;
        }
        return;
    }
    if (t < 256) part[t] = 0;
}

// ---------------- qkv (128x128 tile) + deg count, one dispatch ----------------
// R11 post-mortem: 64x128 tile, 3 error-correction passes everywhere = 343 TF plateau
// (MfmaUtil 13.5%). q/k feed ONLY logits -> 1-pass pure-bf16 is accuracy-safe
// (dlogit ~2e-3); v keeps 3-pass split (its error hits the output linearly).
// 128-row tile doubles MFMA per barrier and halves x re-staging.
__global__ __launch_bounds__(256) void qkv_deg_kernel(
    const unsigned short* __restrict__ xh, const unsigned short* __restrict__ xl,
    const unsigned short* __restrict__ wh, const unsigned short* __restrict__ wl,
    const float* __restrict__ bq, const float* __restrict__ bk, const float* __restrict__ bv,
    float* __restrict__ q, unsigned short* __restrict__ kb, unsigned short* __restrict__ vb,
    const int* __restrict__ ei, int* __restrict__ deg, int Nn, int E_, int nxb) {
    int bx = blockIdx.x;
    if (bx >= 3 * nxb) {                     // deg blocks
        int e = (bx - 3 * nxb) * 256 + threadIdx.x;
        if (e < E_) atomicAdd(&deg[ei[e]], 1);
        return;
    }
    const int wsel = bx / nxb;
    const int n0 = (bx - wsel * nxb) * 128;
    const unsigned short* W_h = wh + (size_t)wsel * (OUT_DIM * IN_DIM);
    const unsigned short* W_l = wl + (size_t)wsel * (OUT_DIM * IN_DIM);
    const float* bias = (wsel == 0) ? bq : (wsel == 1) ? bk : bv;
    const bool vpath = (wsel == 2);

    __shared__ unsigned short xh_s[128 * 40];
    __shared__ unsigned short xl_s[128 * 40];
    __shared__ unsigned short wh_s[128 * 40];
    __shared__ unsigned short wl_s[128 * 40];

    const int tid = threadIdx.x;
    const int w = tid >> 6;
    const int lane = tid & 63;
    const int ml = lane & 15;
    const int quad = lane >> 4;

    const int rows_valid = min(128, Nn - n0);

    floatx4 acc[2][8];
#pragma unroll
    for (int rr = 0; rr < 2; ++rr)
#pragma unroll
        for (int ct = 0; ct < 8; ++ct) acc[rr][ct] = (floatx4){0.f, 0.f, 0.f, 0.f};

    const short8 zero8 = {0, 0, 0, 0, 0, 0, 0, 0};

    for (int kc = 0; kc < IN_DIM; kc += 32) {
#pragma unroll
        for (int l = 0; l < 2; ++l) {
            int flat = tid + l * 256;        // 0..511 -> r 0..127, c 0..3 (8-short chunks)
            int r = flat >> 2, c = flat & 3;
            size_t gx = (size_t)(n0 + r) * IN_DIM + kc + c * 8;
            size_t gw = (size_t)r * IN_DIM + kc + c * 8;
            short8 vh = zero8;
            if (r < rows_valid) vh = *(const short8*)(xh + gx);
            *(short8*)(xh_s + r * 40 + c * 8) = vh;
            *(short8*)(wh_s + r * 40 + c * 8) = *(const short8*)(W_h + gw);
            if (vpath) {
                short8 vl = zero8;
                if (r < rows_valid) vl = *(const short8*)(xl + gx);
                *(short8*)(xl_s + r * 40 + c * 8) = vl;
                *(short8*)(wl_s + r * 40 + c * 8) = *(const short8*)(W_l + gw);
            }
        }
        __syncthreads();

        short8 ah0 = *(const short8*)(xh_s + (w * 32 + ml) * 40 + quad * 8);
        short8 ah1 = *(const short8*)(xh_s + (w * 32 + 16 + ml) * 40 + quad * 8);
        if (!vpath) {
#pragma unroll
            for (int ct = 0; ct < 8; ++ct) {
                short8 bh = *(const short8*)(wh_s + (ct * 16 + ml) * 40 + quad * 8);
                acc[0][ct] = __builtin_amdgcn_mfma_f32_16x16x32_bf16(ah0, bh, acc[0][ct], 0, 0, 0);
                acc[1][ct] = __builtin_amdgcn_mfma_f32_16x16x32_bf16(ah1, bh, acc[1][ct], 0, 0, 0);
            }
        } else {
            short8 al0 = *(const short8*)(xl_s + (w * 32 + ml) * 40 + quad * 8);
            short8 al1 = *(const short8*)(xl_s + (w * 32 + 16 + ml) * 40 + quad * 8);
#pragma unroll
            for (int ct = 0; ct < 8; ++ct) {
                short8 bh = *(const short8*)(wh_s + (ct * 16 + ml) * 40 + quad * 8);
                short8 bl = *(const short8*)(wl_s + (ct * 16 + ml) * 40 + quad * 8);
                acc[0][ct] = __builtin_amdgcn_mfma_f32_16x16x32_bf16(ah0, bh, acc[0][ct], 0, 0, 0);
                acc[0][ct] = __builtin_amdgcn_mfma_f32_16x16x32_bf16(al0, bh, acc[0][ct], 0, 0, 0);
                acc[0][ct] = __builtin_amdgcn_mfma_f32_16x16x32_bf16(ah0, bl, acc[0][ct], 0, 0, 0);
                acc[1][ct] = __builtin_amdgcn_mfma_f32_16x16x32_bf16(ah1, bh, acc[1][ct], 0, 0, 0);
                acc[1][ct] = __builtin_amdgcn_mfma_f32_16x16x32_bf16(al1, bh, acc[1][ct], 0, 0, 0);
                acc[1][ct] = __builtin_amdgcn_mfma_f32_16x16x32_bf16(ah1, bl, acc[1][ct], 0, 0, 0);
            }
        }
        __syncthreads();
    }

    if (wsel == 0) {
#pragma unroll
        for (int rr = 0; rr < 2; ++rr)
#pragma unroll
            for (int ct = 0; ct < 8; ++ct) {
                float bj = bias[ct * 16 + ml];
#pragma unroll
                for (int r = 0; r < 4; ++r) {
                    int grow = n0 + w * 32 + rr * 16 + quad * 4 + r;
                    if (grow < Nn) q[(size_t)grow * 128 + ct * 16 + ml] = acc[rr][ct][r] + bj;
                }
            }
    } else {
        unsigned short* ob = (wsel == 1) ? kb : vb;
#pragma unroll
        for (int rr = 0; rr < 2; ++rr)
#pragma unroll
            for (int ct = 0; ct < 8; ++ct) {
                float bj = bias[ct * 16 + ml];
#pragma unroll
                for (int r = 0; r < 4; ++r) {
                    int grow = n0 + w * 32 + rr * 16 + quad * 4 + r;
                    if (grow < Nn) ob[(size_t)grow * 128 + ct * 16 + ml] = f2bf(acc[rr][ct][r] + bj);
                }
            }
    }
}

// ---------------- one-dispatch exclusive scan (decoupled lookback, nblk<=256 blocks) ----------------
__global__ __launch_bounds__(256) void scan_onepass_kernel(
    const int* __restrict__ deg, int* __restrict__ part,
    int* __restrict__ rowstart, int* __restrict__ cursor, int n, int nblk) {
    __shared__ int sm[256];
    int b = blockIdx.x;
    int t = threadIdx.x;
    int idx4 = b * 1024 + t * 4;
    int d0 = 0, d1 = 0, d2 = 0, d3 = 0;
    if (idx4 + 3 < n) {
        int4 d = *(const int4*)(deg + idx4);
        d0 = d.x; d1 = d.y; d2 = d.z; d3 = d.w;
    } else {
        if (idx4 + 0 < n) d0 = deg[idx4 + 0];
        if (idx4 + 1 < n) d1 = deg[idx4 + 1];
        if (idx4 + 2 < n) d2 = deg[idx4 + 2];
        if (idx4 + 3 < n) d3 = deg[idx4 + 3];
    }
    int s = d0 + d1 + d2 + d3;
    sm[t] = s;
    __syncthreads();
    for (int off = 1; off < 256; off <<= 1) {
        int o = (t >= off) ? sm[t - off] : 0;
        __syncthreads();
        sm[t] += o;
        __syncthreads();
    }
    int myprefix = sm[t] - s;
    int total = sm[255];
    __syncthreads();

    if (t == 0) atomicExch(&part[b], total + 1);

    int pv = 0;
    if (t < b) {
        while ((pv = atomicAdd(&part[t], 0)) == 0) {}
        pv -= 1;
    }
    sm[t] = (t < b) ? pv : 0;
    __syncthreads();
    for (int off = 128; off > 0; off >>= 1) {
        if (t < off) sm[t] += sm[t + off];
        __syncthreads();
    }
    int offset = sm[0];

    int run = offset + myprefix;
    int4 rs;
    rs.x = run;
    rs.y = run + d0;
    rs.z = rs.y + d1;
    rs.w = rs.z + d2;
    if (idx4 + 3 < n) {
        *(int4*)(rowstart + idx4) = rs;
        *(int4*)(cursor + idx4) = rs;
    } else {
        int rv[4] = {rs.x, rs.y, rs.z, rs.w};
#pragma unroll
        for (int j = 0; j < 4; ++j)
            if (idx4 + j < n) { rowstart[idx4 + j] = rv[j]; cursor[idx4 + j] = rv[j]; }
    }
    if (b == nblk - 1 && t == 255) rowstart[n] = offset + total;
}

// ---------------- scatter: {col, table-coord u} packed int2 into CSR order ----------------
__global__ void scatter_kernel(const int* __restrict__ ei, const float* __restrict__ edist,
                               int* __restrict__ cursor, int2* __restrict__ cpack, int E_) {
    int e = blockIdx.x * 256 + threadIdx.x;
    if (e >= E_) return;
    int row = ei[e];
    int pos = atomicAdd(&cursor[row], 1);
    float u = edist[e] * ((float)(TBL - 1) / 6.0f);
    u = fminf(fmaxf(u, 0.0f), (float)(TBL - 1));
    cpack[pos] = make_int2(ei[E_ + e], __float_as_int(u));
}

// ---------------- fused flash-style edge+node pass (unchanged from R10) ----------------
__global__ __launch_bounds__(256) void fused_node_kernel(
    const float* __restrict__ q, const unsigned short* __restrict__ kb,
    const unsigned short* __restrict__ vb, const int2* __restrict__ cpack,
    const float* __restrict__ tbl, const int* __restrict__ rowstart,
    unsigned short* __restrict__ oh, unsigned short* __restrict__ ol, int Nn) {
    int lane = threadIdx.x & 63;
    int n = blockIdx.x * 4 + (threadIdx.x >> 6);
    if (n >= Nn) return;
    int g = lane >> 3;       // edge subgroup
    int h = lane & 7;        // head
    int start = rowstart[n];
    int end = rowstart[n + 1];

    float qf[16];
    {
        const float4* qp = (const float4*)(q + (size_t)n * 128 + h * 16);
#pragma unroll
        for (int j = 0; j < 4; ++j) {
            float4 t = qp[j];
            qf[j * 4 + 0] = t.x; qf[j * 4 + 1] = t.y;
            qf[j * 4 + 2] = t.z; qf[j * 4 + 3] = t.w;
        }
    }

    float l = 0.0f;
    float acc[16];
#pragma unroll
    for (int j = 0; j < 16; ++j) acc[j] = 0.0f;

#pragma unroll 2
    for (int base = start; base < end; base += 8) {
        int e = base + g;
        bool valid = (e < end);
        int ee = valid ? e : (end - 1);
        int2 np = cpack[ee];
        int col = np.x;
        float u = __int_as_float(np.y);

        const uint4* kp = (const uint4*)(kb + (size_t)col * 128 + h * 16);
        uint4 k0 = kp[0], k1 = kp[1];
        const uint4* vp = (const uint4*)(vb + (size_t)col * 128 + h * 16);
        uint4 v0 = vp[0], v1 = vp[1];

        unsigned kk[8] = {k0.x, k0.y, k0.z, k0.w, k1.x, k1.y, k1.z, k1.w};
        float d = 0.0f;
#pragma unroll
        for (int j = 0; j < 8; ++j) {
            d = fmaf(bflo(kk[j]), qf[2 * j], d);
            d = fmaf(bfhi(kk[j]), qf[2 * j + 1], d);
        }

        int i0 = min((int)u, TBL - 2);
        float fr = u - (float)i0;
        float t0 = tbl[i0 * NH + h];
        float t1 = tbl[i0 * NH + NH + h];
        float logit2 = fmaf(d, 0.25f * LOG2E, fmaf(fr, t1 - t0, t0));
        logit2 = fminf(logit2, 80.0f);
        if (!valid) logit2 = -1e30f;
        float p = __builtin_amdgcn_exp2f(logit2);

        l += p;
        unsigned vv[8] = {v0.x, v0.y, v0.z, v0.w, v1.x, v1.y, v1.z, v1.w};
#pragma unroll
        for (int j = 0; j < 8; ++j) {
            acc[2 * j]     = fmaf(p, bflo(vv[j]), acc[2 * j]);
            acc[2 * j + 1] = fmaf(p, bfhi(vv[j]), acc[2 * j + 1]);
        }
    }

#pragma unroll
    for (int off = 8; off < 64; off <<= 1) {
        l += __shfl_xor(l, off);
#pragma unroll
        for (int j = 0; j < 16; ++j) acc[j] += __shfl_xor(acc[j], off);
    }

    if (g == 0) {
        float inv = 1.0f / (l + 1e-12f);
        unsigned short hv[16], lv[16];
#pragma unroll
        for (int j = 0; j < 16; ++j) {
            float o = acc[j] * inv;
            split1(o, hv[j], lv[j]);
        }
        *(short8*)(oh + (size_t)n * 128 + h * 16) = *(short8*)hv;
        *(short8*)(oh + (size_t)n * 128 + h * 16 + 8) = *(short8*)(hv + 8);
        *(short8*)(ol + (size_t)n * 128 + h * 16) = *(short8*)lv;
        *(short8*)(ol + (size_t)n * 128 + h * 16 + 8) = *(short8*)(lv + 8);
    }
}

// ---------------- out GEMM via split-bf16 MFMA (K=128) ----------------
__global__ __launch_bounds__(256) void out_gemm_mfma_kernel(
    const unsigned short* __restrict__ oh, const unsigned short* __restrict__ ol,
    const unsigned short* __restrict__ wo_h, const unsigned short* __restrict__ wo_l,
    const float* __restrict__ bo, float* __restrict__ out, int Nn) {
    const int n0 = blockIdx.x * 64;

    __shared__ unsigned short xh_s[64 * 40];
    __shared__ unsigned short xl_s[64 * 40];
    __shared__ unsigned short wh_s[128 * 40];
    __shared__ unsigned short wl_s[128 * 40];

    const int tid = threadIdx.x;
    const int w = tid >> 6;
    const int lane = tid & 63;
    const int ml = lane & 15;
    const int quad = lane >> 4;

    const int rows_valid = min(64, Nn - n0);

    floatx4 acc[8];
#pragma unroll
    for (int ct = 0; ct < 8; ++ct) acc[ct] = (floatx4){0.f, 0.f, 0.f, 0.f};

    const short8 zero8 = {0, 0, 0, 0, 0, 0, 0, 0};

    for (int kc = 0; kc < OUT_DIM; kc += 32) {
        {
            int r = tid >> 2, c = tid & 3;
            short8 vh = zero8, vl = zero8;
            if (r < rows_valid) {
                size_t g = (size_t)(n0 + r) * OUT_DIM + kc + c * 8;
                vh = *(const short8*)(oh + g);
                vl = *(const short8*)(ol + g);
            }
            *(short8*)(xh_s + r * 40 + c * 8) = vh;
            *(short8*)(xl_s + r * 40 + c * 8) = vl;
        }
#pragma unroll
        for (int l = 0; l < 2; ++l) {
            int idx = tid + l * 256;
            int r = idx >> 2, c = idx & 3;
            size_t g = (size_t)r * OUT_DIM + kc + c * 8;
            *(short8*)(wh_s + r * 40 + c * 8) = *(const short8*)(wo_h + g);
            *(short8*)(wl_s + r * 40 + c * 8) = *(const short8*)(wo_l + g);
        }
        __syncthreads();

        short8 ah = *(const short8*)(xh_s + (w * 16 + ml) * 40 + quad * 8);
        short8 al = *(const short8*)(xl_s + (w * 16 + ml) * 40 + quad * 8);
#pragma unroll
        for (int ct = 0; ct < 8; ++ct) {
            short8 bh = *(const short8*)(wh_s + (ct * 16 + ml) * 40 + quad * 8);
            short8 bl = *(const short8*)(wl_s + (ct * 16 + ml) * 40 + quad * 8);
            acc[ct] = __builtin_amdgcn_mfma_f32_16x16x32_bf16(ah, bh, acc[ct], 0, 0, 0);
            acc[ct] = __builtin_amdgcn_mfma_f32_16x16x32_bf16(al, bh, acc[ct], 0, 0, 0);
            acc[ct] = __builtin_amdgcn_mfma_f32_16x16x32_bf16(ah, bl, acc[ct], 0, 0, 0);
        }
        __syncthreads();
    }

#pragma unroll
    for (int ct = 0; ct < 8; ++ct) {
        float bj = bo[ct * 16 + ml];
#pragma unroll
        for (int r = 0; r < 4; ++r) {
            int grow = n0 + w * 16 + quad * 4 + r;
            if (grow < Nn) out[(size_t)grow * 128 + ct * 16 + ml] = acc[ct][r] + bj;
        }
    }
}

extern "C" void kernel_launch(void* const* d_in, const int* in_sizes, int n_in,
                              void* d_out, int out_size, void* d_ws, size_t ws_size,
                              hipStream_t stream) {
    const float* x   = (const float*)d_in[0];
    const int* ei    = (const int*)d_in[1];
    const float* edist = (const float*)d_in[2];
    const float* Wq = (const float*)d_in[3];  const float* bq = (const float*)d_in[4];
    const float* Wk = (const float*)d_in[5];  const float* bk = (const float*)d_in[6];
    const float* Wv = (const float*)d_in[7];  const float* bv = (const float*)d_in[8];
    const float* Wo = (const float*)d_in[9];  const float* bo = (const float*)d_in[10];
    const float* Wg1 = (const float*)d_in[11]; const float* bg1 = (const float*)d_in[12];
    const float* Wg2 = (const float*)d_in[13]; const float* bg2 = (const float*)d_in[14];
    const int Nn = in_sizes[0] / IN_DIM;
    const int Ee = in_sizes[2];
    float* out = (float*)d_out;

    char* ws = (char*)d_ws;
    size_t off = 0;
    auto alloc = [&](size_t bytes) -> char* {
        char* p = ws + off;
        off += (bytes + 255) & ~(size_t)255;
        return p;
    };
    float* q  = (float*)alloc((size_t)Nn * 128 * 4);
    unsigned short* kbuf = (unsigned short*)alloc((size_t)Nn * 128 * 2);
    unsigned short* vbuf = (unsigned short*)alloc((size_t)Nn * 128 * 2);
    char* xlblock = alloc((size_t)Nn * IN_DIM * 2);
    unsigned short* o_hi = (unsigned short*)alloc((size_t)Nn * 128 * 2);
    unsigned short* o_lo = (unsigned short*)alloc((size_t)Nn * 128 * 2);
    float* geot = (float*)alloc((size_t)TBL * 8 * 4);
    int* deg      = (int*)alloc((size_t)Nn * 4);
    int* rowstart = (int*)alloc((size_t)(Nn + 1) * 4);
    int* cursor   = (int*)alloc((size_t)Nn * 4);
    int* part     = (int*)alloc((size_t)256 * 4);
    unsigned short* wh_all = (unsigned short*)alloc((size_t)3 * OUT_DIM * IN_DIM * 2);
    unsigned short* wl_all = (unsigned short*)alloc((size_t)3 * OUT_DIM * IN_DIM * 2);
    unsigned short* wo_h = (unsigned short*)alloc((size_t)OUT_DIM * OUT_DIM * 2);
    unsigned short* wo_l = (unsigned short*)alloc((size_t)OUT_DIM * OUT_DIM * 2);

    unsigned short* xh = (unsigned short*)d_out;       // rewritten by final GEMM
    unsigned short* xl = (unsigned short*)xlblock;
    int2* cpack = (int2*)xlblock;                       // live after qkv

    // --- dispatch 1: prep_all ---
    int n4x = Nn * IN_DIM / 4;
    int nsplit = (n4x + 255) / 256;
    int nwm = ((OUT_DIM * IN_DIM / 4) + 255) / 256;
    int nwo = ((OUT_DIM * OUT_DIM / 4) + 255) / 256;
    int ngeo = (TBL + 255) / 256;
    int ndegz = (Nn + 1023) / 1024;
    int gprep = nsplit + 3 * nwm + nwo + ngeo + ndegz + 1;
    prep_all_kernel<<<gprep, 256, 0, stream>>>(
        x, Wq, Wk, Wv, Wo, xh, xl, wh_all, wl_all, wo_h, wo_l,
        Wg1, bg1, Wg2, bg2, geot, deg, part, n4x, Nn, nsplit, nwm, nwo, ngeo, ndegz);

    // --- dispatch 2: qkv (128-row tiles) + deg ---
    int nxb = (Nn + 127) / 128;
    int ndegb = (Ee + 255) / 256;
    qkv_deg_kernel<<<3 * nxb + ndegb, 256, 0, stream>>>(
        xh, xl, wh_all, wl_all, bq, bk, bv, q, kbuf, vbuf, ei, deg, Nn, Ee, nxb);

    // --- dispatch 3: one-pass scan ---
    int nblk = (Nn + 1023) / 1024;
    scan_onepass_kernel<<<nblk, 256, 0, stream>>>(deg, part, rowstart, cursor, Nn, nblk);

    // --- dispatch 4: scatter ---
    scatter_kernel<<<(Ee + 255) / 256, 256, 0, stream>>>(ei, edist, cursor, cpack, Ee);

    // --- dispatch 5: fused edge+node ---
    fused_node_kernel<<<(Nn + 3) / 4, 256, 0, stream>>>(q, kbuf, vbuf, cpack, geot, rowstart, o_hi, o_lo, Nn);

    // --- dispatch 6: out GEMM ---
    out_gemm_mfma_kernel<<<(Nn + 63) / 64, 256, 0, stream>>>(o_hi, o_lo, wo_h, wo_l, bo, out, Nn);
}